// Round 4
// baseline (1064.696 us; speedup 1.0000x reference)
//
#include <hip/hip_runtime.h>
#include <hip/hip_bf16.h>
#include <math.h>

#define T_LEN 4096
#define DIM   2048
#define NH    6
#define DK    256
#define DVh   512
#define KD    1536
#define VD    3072
#define CK    64
#define NCHK  (T_LEN / CK)
#define NPAIR (NCHK / 2)

typedef __attribute__((ext_vector_type(8))) short bf16x8;
typedef __attribute__((ext_vector_type(4))) float f32x4;

__device__ __forceinline__ float silu_f(float v){ return v / (1.f + __expf(-v)); }

__device__ __forceinline__ unsigned short f2bf(float f) {
  unsigned int u = __float_as_uint(f);
  unsigned int r = u + 0x7FFFu + ((u >> 16) & 1u);
  return (unsigned short)(r >> 16);
}
__device__ __forceinline__ float bf2f(unsigned short s) {
  return __uint_as_float(((unsigned int)s) << 16);
}

// LDS-only barrier: drains lgkmcnt but leaves global loads/stores in flight.
__device__ __forceinline__ void bar_lds() {
  __builtin_amdgcn_sched_barrier(0);
  asm volatile("s_waitcnt lgkmcnt(0)" ::: "memory");
  __builtin_amdgcn_s_barrier();
  __builtin_amdgcn_sched_barrier(0);
}

// ---------------- cast fp32 -> bf16 ----------------
__global__ __launch_bounds__(256) void cast_bf16(
    const float* __restrict__ in, unsigned short* __restrict__ out)
{
  int i = blockIdx.x * 256 + threadIdx.x;
  float4 v4 = ((const float4*)in)[i];
  ushort4 o4;
  o4.x = f2bf(v4.x); o4.y = f2bf(v4.y); o4.z = f2bf(v4.z); o4.w = f2bf(v4.w);
  ((ushort4*)out)[i] = o4;
}

// ---------------- transpose + cast: in[R][Cn] fp32 -> out[Cn][R] bf16 ----------------
__global__ __launch_bounds__(256) void tcast(
    const float* __restrict__ in, unsigned short* __restrict__ out, int R, int Cn)
{
  __shared__ float tile[32][33];
  int bx = blockIdx.x * 32;
  int by = blockIdx.y * 32;
  int tx = threadIdx.x & 31, ty = threadIdx.x >> 5;
#pragma unroll
  for (int i = 0; i < 32; i += 8)
    tile[ty + i][tx] = in[(size_t)(by + ty + i) * Cn + bx + tx];
  __syncthreads();
#pragma unroll
  for (int i = 0; i < 32; i += 8)
    out[(size_t)(bx + ty + i) * R + by + tx] = f2bf(tile[tx][ty + i]);
}

// ---------------- bf16 MFMA GEMM (m97 structure) ----------------
__global__ __launch_bounds__(256) void gemm_bt_bf16(
    const unsigned short* __restrict__ A, const unsigned short* __restrict__ BT,
    void* __restrict__ Cout, int M, int N, int K, int act)
{
  __shared__ unsigned short As[128 * 32];
  __shared__ unsigned short Bs[128 * 32];
  const int tid = threadIdx.x;
  const int bm = blockIdx.y * 128, bn = blockIdx.x * 128;
  const int lane = tid & 63, wave = tid >> 6;
  const int wm = (wave >> 1) * 64, wn = (wave & 1) * 64;
  const int fr = lane & 15, kq = lane >> 4;

  f32x4 acc[4][4];
#pragma unroll
  for (int i = 0; i < 4; ++i)
#pragma unroll
    for (int j = 0; j < 4; ++j) acc[i][j] = (f32x4){0.f, 0.f, 0.f, 0.f};

  const int r0 = tid >> 2, c0 = (tid & 3) * 8;
  const int r1 = r0 + 64;

  for (int k0 = 0; k0 < K; k0 += 32) {
    __builtin_amdgcn_global_load_lds(
        (const __attribute__((address_space(1))) unsigned int*)(A + (size_t)(bm + r0) * K + k0 + c0),
        (__attribute__((address_space(3))) unsigned int*)(As + r0 * 32 + c0), 16, 0, 0);
    __builtin_amdgcn_global_load_lds(
        (const __attribute__((address_space(1))) unsigned int*)(A + (size_t)(bm + r1) * K + k0 + c0),
        (__attribute__((address_space(3))) unsigned int*)(As + r1 * 32 + c0), 16, 0, 0);
    __builtin_amdgcn_global_load_lds(
        (const __attribute__((address_space(1))) unsigned int*)(BT + (size_t)(bn + r0) * K + k0 + c0),
        (__attribute__((address_space(3))) unsigned int*)(Bs + r0 * 32 + c0), 16, 0, 0);
    __builtin_amdgcn_global_load_lds(
        (const __attribute__((address_space(1))) unsigned int*)(BT + (size_t)(bn + r1) * K + k0 + c0),
        (__attribute__((address_space(3))) unsigned int*)(Bs + r1 * 32 + c0), 16, 0, 0);
    __syncthreads();

    bf16x8 af[4], bfr[4];
#pragma unroll
    for (int i = 0; i < 4; ++i)
      af[i] = *(const bf16x8*)(As + (wm + i * 16 + fr) * 32 + kq * 8);
#pragma unroll
    for (int j = 0; j < 4; ++j)
      bfr[j] = *(const bf16x8*)(Bs + (wn + j * 16 + fr) * 32 + kq * 8);
#pragma unroll
    for (int i = 0; i < 4; ++i)
#pragma unroll
      for (int j = 0; j < 4; ++j)
        acc[i][j] = __builtin_amdgcn_mfma_f32_16x16x32_bf16(af[i], bfr[j], acc[i][j], 0, 0, 0);
    __syncthreads();
  }

  if (act == 2) {
    unsigned short* C = (unsigned short*)Cout;
#pragma unroll
    for (int i = 0; i < 4; ++i) {
      int rbase = bm + wm + i * 16 + kq * 4;
#pragma unroll
      for (int r = 0; r < 4; ++r) {
        size_t rowoff = (size_t)(rbase + r) * N + bn + wn + fr;
#pragma unroll
        for (int j = 0; j < 4; ++j) C[rowoff + j * 16] = f2bf(acc[i][j][r]);
      }
    }
  } else {
    float* C = (float*)Cout;
#pragma unroll
    for (int i = 0; i < 4; ++i) {
      int rbase = bm + wm + i * 16 + kq * 4;
#pragma unroll
      for (int r = 0; r < 4; ++r) {
        size_t rowoff = (size_t)(rbase + r) * N + bn + wn + fr;
#pragma unroll
        for (int j = 0; j < 4; ++j) {
          float v = acc[i][j][r];
          if (act == 1) v = silu_f(v);
          C[rowoff + j * 16] = v;
        }
      }
    }
  }
}

// ---------------- dyn = tg @ gen_w2 ----------------
__global__ __launch_bounds__(256) void proj_dyn(
    const float* __restrict__ tg, const float* __restrict__ w2, float* __restrict__ dyn)
{
  int t = blockIdx.x, tid = threadIdx.x;
  float g = tg[(size_t)t * 256 + tid];
  float p[4];
#pragma unroll
  for (int j = 0; j < 4; ++j) p[j] = g * w2[tid * 4 + j];
#pragma unroll
  for (int j = 0; j < 4; ++j)
    for (int m = 32; m >= 1; m >>= 1) p[j] += __shfl_xor(p[j], m);
  __shared__ float red[4][4];
  if ((tid & 63) == 0) {
    int w = tid >> 6;
#pragma unroll
    for (int j = 0; j < 4; ++j) red[w][j] = p[j];
  }
  __syncthreads();
  if (tid < 4) dyn[(size_t)t * 4 + tid] = red[0][tid] + red[1][tid] + red[2][tid] + red[3][tid];
}

// ---------------- beta / raw decay log-gate g ----------------
__global__ __launch_bounds__(256) void proj_bg(
    const float* __restrict__ h, const float* __restrict__ Wb, const float* __restrict__ Wa,
    const float* __restrict__ A_log, const float* __restrict__ dt_bias,
    float* __restrict__ beta, float* __restrict__ gout)
{
  int t = blockIdx.x, tid = threadIdx.x;
  float pb[6], pa[6];
#pragma unroll
  for (int j = 0; j < 6; ++j) { pb[j] = 0.f; pa[j] = 0.f; }
  for (int d = tid; d < DIM; d += 256) {
    float hv = h[(size_t)t * DIM + d];
#pragma unroll
    for (int j = 0; j < 6; ++j) {
      pb[j] += hv * Wb[d * 6 + j];
      pa[j] += hv * Wa[d * 6 + j];
    }
  }
#pragma unroll
  for (int j = 0; j < 6; ++j)
    for (int m = 32; m >= 1; m >>= 1) { pb[j] += __shfl_xor(pb[j], m); pa[j] += __shfl_xor(pa[j], m); }
  __shared__ float rb[4][6], ra[4][6];
  if ((tid & 63) == 0) {
    int w = tid >> 6;
#pragma unroll
    for (int j = 0; j < 6; ++j) { rb[w][j] = pb[j]; ra[w][j] = pa[j]; }
  }
  __syncthreads();
  if (tid < 6) {
    int j = tid;
    float sb = rb[0][j] + rb[1][j] + rb[2][j] + rb[3][j];
    float sa = ra[0][j] + ra[1][j] + ra[2][j] + ra[3][j];
    beta[(size_t)t * 6 + j] = 1.f / (1.f + expf(-sb));
    float z = sa + dt_bias[j];
    float sp = (z > 20.f) ? z : log1pf(expf(z));
    gout[(size_t)t * 6 + j] = -expf(A_log[j]) * sp;   // raw log-gate (g < 0)
  }
}

// ---------------- causal dynamic conv + silu ----------------
__global__ __launch_bounds__(256) void conv_kernel(
    const float* __restrict__ x, const float* __restrict__ dyn,
    const float* __restrict__ cw, float* __restrict__ v)
{
  int c = blockIdx.x * 256 + threadIdx.x;
  int t = blockIdx.y;
  float4 w4 = ((const float4*)cw)[c];
  float d0 = dyn[t * 4 + 0], d1 = dyn[t * 4 + 1], d2 = dyn[t * 4 + 2], d3 = dyn[t * 4 + 3];
  float acc = (w4.w + d3) * x[(size_t)t * VD + c];
  if (t >= 1) acc += (w4.z + d2) * x[(size_t)(t - 1) * VD + c];
  if (t >= 2) acc += (w4.y + d1) * x[(size_t)(t - 2) * VD + c];
  if (t >= 3) acc += (w4.x + d0) * x[(size_t)(t - 3) * VD + c];
  v[(size_t)t * VD + c] = silu_f(acc);
}

// ---------------- l2norm(q)*scale, l2norm(k) in place ----------------
__global__ __launch_bounds__(64) void l2norm_qk(
    float* __restrict__ q, float* __restrict__ k)
{
  size_t base = (size_t)blockIdx.x * 256;
  int tid = threadIdx.x;
  float4 qv = ((float4*)(q + base))[tid];
  float4 kv = ((float4*)(k + base))[tid];
  float sq = qv.x*qv.x + qv.y*qv.y + qv.z*qv.z + qv.w*qv.w;
  float sk = kv.x*kv.x + kv.y*kv.y + kv.z*kv.z + kv.w*kv.w;
  for (int m = 32; m >= 1; m >>= 1) { sq += __shfl_xor(sq, m); sk += __shfl_xor(sk, m); }
  float rq = rsqrtf(sq + 1e-6f) * 0.0625f;   // fold DK^-0.5
  float rk = rsqrtf(sk + 1e-6f);
  qv.x *= rq; qv.y *= rq; qv.z *= rq; qv.w *= rq;
  kv.x *= rk; kv.y *= rk; kv.z *= rk; kv.w *= rk;
  ((float4*)(q + base))[tid] = qv;
  ((float4*)(k + base))[tid] = kv;
}

// ---------------- P1: within-chunk inclusive cumsum of g, gamma = exp(c_end) ----------------
__global__ __launch_bounds__(64) void cumsum_g(
    const float* __restrict__ g, float* __restrict__ c, float* __restrict__ gammas)
{
  int ch = blockIdx.x, h = blockIdx.y;
  int t0 = ch * CK;
  int lane = threadIdx.x;
  float cum = g[(size_t)(t0 + lane) * 6 + h];
  for (int off = 1; off < 64; off <<= 1) {
    float n = __shfl_up(cum, off);
    if (lane >= off) cum += n;
  }
  c[(size_t)h * T_LEN + t0 + lane] = cum;
  if (lane == 63) gammas[h * NCHK + ch] = __expf(cum);
}

// ---------------- P2a: Kbar/Qbar = exp(c_t) * {k,q}  (bf16, same layout) ----------------
__global__ __launch_bounds__(384) void scale_kq(
    const float* __restrict__ q, const float* __restrict__ k, const float* __restrict__ c,
    unsigned short* __restrict__ Qb, unsigned short* __restrict__ Kb)
{
  int t = blockIdx.x;
  int tid = threadIdx.x;           // float4 index within row (384 = KD/4)
  int h = tid >> 6;
  float w1 = __expf(c[(size_t)h * T_LEN + t]);
  size_t off = (size_t)t * KD + tid * 4;
  float4 qv = *(const float4*)(q + off);
  float4 kv = *(const float4*)(k + off);
  ushort4 qo, ko;
  qo.x = f2bf(w1 * qv.x); qo.y = f2bf(w1 * qv.y); qo.z = f2bf(w1 * qv.z); qo.w = f2bf(w1 * qv.w);
  ko.x = f2bf(w1 * kv.x); ko.y = f2bf(w1 * kv.y); ko.z = f2bf(w1 * kv.z); ko.w = f2bf(w1 * kv.w);
  *(ushort4*)(Qb + off) = qo;
  *(ushort4*)(Kb + off) = ko;
}

// ---------------- P2b: KhT[h][ch][kk][tt] = exp(c_end - c_t) * k[t][kk]  (bf16) ----------------
__global__ __launch_bounds__(256) void make_khT(
    const float* __restrict__ k, const float* __restrict__ c,
    unsigned short* __restrict__ KhT)
{
  int ch = blockIdx.x, h = blockIdx.y;
  int t0 = ch * CK;
  int tt = threadIdx.x & 63, ks = threadIdx.x >> 6;
  float cend = c[(size_t)h * T_LEN + t0 + 63];
  float w2 = __expf(cend - c[(size_t)h * T_LEN + t0 + tt]);
  size_t obase = ((size_t)(h * NCHK + ch)) * DK * CK;
#pragma unroll 8
  for (int kb2 = 0; kb2 < 64; ++kb2) {
    int kk = ks * 64 + kb2;
    float kv = k[(size_t)(t0 + tt) * KD + h * 256 + kk];
    KhT[obase + (size_t)kk * CK + tt] = f2bf(w2 * kv);
  }
}

// ---------------- P3: per (h,chunk): L, P via MFMA ----------------
__global__ __launch_bounds__(256) void chunk_lp(
    const float* __restrict__ q, const float* __restrict__ k,
    const float* __restrict__ c, const float* __restrict__ beta,
    float* __restrict__ Lg, unsigned short* __restrict__ Pm)
{
  const int ch = blockIdx.x, h = blockIdx.y;
  const int t0 = ch * CK;
  const int tid = threadIdx.x;
  const int w = tid >> 6, lane = tid & 63, fr = lane & 15, kq = lane >> 4;
  __shared__ unsigned short kb[64][264];
  __shared__ unsigned short qb[64][264];
  __shared__ float cs[64], bs[64];
#pragma unroll
  for (int i = 0; i < 16; ++i) {
    int fi = tid + i * 256;
    int r = fi >> 6, d4 = fi & 63;
    float4 kv = *(const float4*)(k + (size_t)(t0 + r) * KD + h * 256 + d4 * 4);
    float4 qv = *(const float4*)(q + (size_t)(t0 + r) * KD + h * 256 + d4 * 4);
    ushort4 k4, q4;
    k4.x = f2bf(kv.x); k4.y = f2bf(kv.y); k4.z = f2bf(kv.z); k4.w = f2bf(kv.w);
    q4.x = f2bf(qv.x); q4.y = f2bf(qv.y); q4.z = f2bf(qv.z); q4.w = f2bf(qv.w);
    *(ushort4*)&kb[r][d4 * 4] = k4;
    *(ushort4*)&qb[r][d4 * 4] = q4;
  }
  if (tid < 64) {
    cs[tid] = c[(size_t)h * T_LEN + t0 + tid];
    bs[tid] = beta[(size_t)(t0 + tid) * 6 + h];
  }
  __syncthreads();

  f32x4 akk[4], aqk[4];
#pragma unroll
  for (int j = 0; j < 4; ++j) { akk[j] = (f32x4){0,0,0,0}; aqk[j] = (f32x4){0,0,0,0}; }
#pragma unroll
  for (int kt = 0; kt < 8; ++kt) {
    bf16x8 ak = *(const bf16x8*)&kb[16 * w + fr][kt * 32 + kq * 8];
    bf16x8 aq = *(const bf16x8*)&qb[16 * w + fr][kt * 32 + kq * 8];
#pragma unroll
    for (int j = 0; j < 4; ++j) {
      bf16x8 b = *(const bf16x8*)&kb[j * 16 + fr][kt * 32 + kq * 8];
      akk[j] = __builtin_amdgcn_mfma_f32_16x16x32_bf16(ak, b, akk[j], 0, 0, 0);
      aqk[j] = __builtin_amdgcn_mfma_f32_16x16x32_bf16(aq, b, aqk[j], 0, 0, 0);
    }
  }
  size_t base = ((size_t)(h * NCHK + ch)) * CK * CK;
#pragma unroll
  for (int j = 0; j < 4; ++j) {
#pragma unroll
    for (int r = 0; r < 4; ++r) {
      int t = 16 * w + kq * 4 + r, col = j * 16 + fr;
      float e = __expf(fminf(cs[t] - cs[col], 0.f));
      Lg[base + t * 64 + col] = (col < t) ? bs[t] * e * akk[j][r] : 0.f;
      Pm[base + t * 64 + col] = f2bf((col <= t) ? e * aqk[j][r] : 0.f);
    }
  }
}

// ---------------- P3b: cross-block W21 = Kbar2·Kh1^T, U21 = Qbar2·Kh1^T ----------------
// W21[t2][t1] = e^{c2(t2)} e^{c1end-c1(t1)} (k_{t2}.k_{t1}); full 64x64 (no mask:
// all of chunk 2 causally sees all of chunk 1). Kh1 is rebuilt from fp32 k + c.
__global__ __launch_bounds__(256) void cross_lp(
    const unsigned short* __restrict__ Kb, const unsigned short* __restrict__ Qb,
    const float* __restrict__ k, const float* __restrict__ c,
    unsigned short* __restrict__ W21, unsigned short* __restrict__ U21)
{
  const int p = blockIdx.x, h = blockIdx.y;
  const int t01 = p * 128, t02 = t01 + 64;
  const int tid = threadIdx.x;
  const int w = tid >> 6, lane = tid & 63, fr = lane & 15, kq = lane >> 4;
  __shared__ float wg[64];
  if (tid < 64) {
    float cend = c[(size_t)h * T_LEN + t01 + 63];
    wg[tid] = __expf(cend - c[(size_t)h * T_LEN + t01 + tid]);
  }
  __syncthreads();
  bf16x8 kfr[8], qfr[8];
  {
    const unsigned short* kr = Kb + (size_t)(t02 + 16 * w + fr) * KD + h * 256 + kq * 8;
    const unsigned short* qr = Qb + (size_t)(t02 + 16 * w + fr) * KD + h * 256 + kq * 8;
#pragma unroll
    for (int kt = 0; kt < 8; ++kt) {
      kfr[kt] = *(const bf16x8*)(kr + kt * 32);
      qfr[kt] = *(const bf16x8*)(qr + kt * 32);
    }
  }
  f32x4 aw[4], au[4];
#pragma unroll
  for (int j = 0; j < 4; ++j) { aw[j] = (f32x4){0,0,0,0}; au[j] = (f32x4){0,0,0,0}; }
#pragma unroll
  for (int kt = 0; kt < 8; ++kt) {
#pragma unroll
    for (int j2 = 0; j2 < 4; ++j2) {
      int t1 = j2 * 16 + fr;
      float wt = wg[t1];
      const float* kp = k + (size_t)(t01 + t1) * KD + h * 256 + kt * 32 + kq * 8;
      float4 a0 = *(const float4*)(kp);
      float4 a1 = *(const float4*)(kp + 4);
      bf16x8 b;
      b[0] = (short)f2bf(wt * a0.x); b[1] = (short)f2bf(wt * a0.y);
      b[2] = (short)f2bf(wt * a0.z); b[3] = (short)f2bf(wt * a0.w);
      b[4] = (short)f2bf(wt * a1.x); b[5] = (short)f2bf(wt * a1.y);
      b[6] = (short)f2bf(wt * a1.z); b[7] = (short)f2bf(wt * a1.w);
      aw[j2] = __builtin_amdgcn_mfma_f32_16x16x32_bf16(kfr[kt], b, aw[j2], 0, 0, 0);
      au[j2] = __builtin_amdgcn_mfma_f32_16x16x32_bf16(qfr[kt], b, au[j2], 0, 0, 0);
    }
  }
  size_t pb = ((size_t)h * NPAIR + p) * 4096;
#pragma unroll
  for (int j2 = 0; j2 < 4; ++j2)
#pragma unroll
    for (int r = 0; r < 4; ++r) {
      int t2 = 16 * w + kq * 4 + r, t1 = j2 * 16 + fr;
      W21[pb + (size_t)t2 * 64 + t1] = f2bf(aw[j2][r]);
      U21[pb + (size_t)t2 * 64 + t1] = f2bf(au[j2][r]);
    }
}

// ---------------- P4: T' = (I+L)^{-1} diag(beta)  (bf16) ----------------
__global__ __launch_bounds__(64) void tri_inv(
    const float* __restrict__ Lg, const float* __restrict__ beta,
    unsigned short* __restrict__ Tm)
{
  const int ch = blockIdx.x, h = blockIdx.y;
  const size_t base = ((size_t)(h * NCHK + ch)) * CK * CK;
  const int j = threadIdx.x;
  __shared__ float Ll[64][65];
  __shared__ float Tl[64][65];
  for (int t = 0; t < 64; ++t) Ll[t][j] = Lg[base + t * 64 + j];
  __syncthreads();
  for (int t = 0; t < 64; ++t) {
    float s;
    if (j > t) s = 0.f;
    else if (j == t) s = 1.f;
    else {
      s = 0.f;
      for (int m = j; m < t; ++m) s -= Ll[t][m] * Tl[m][j];
    }
    Tl[t][j] = s;
  }
  float bj = beta[(size_t)(ch * 64 + j) * 6 + h];
  for (int t = 0; t < 64; ++t) Tm[base + t * 64 + j] = f2bf(Tl[t][j] * bj);
}

// ---------------- chunked gated delta-rule scan, PAIR form (MFMA, 8-wave) ----------------
// grid (32, 6): blockIdx.x = 16-col slice of DVh, blockIdx.y = head.
// R4: process TWO 64-chunks per iteration (128 tokens) -> 32 serial iterations.
// Evidence (R1-R3): per-chunk time is ~85% fixed overhead, insensitive to work
// inside; only fewer serial iterations attacks it. Block decomposition:
//   X1 = V1 - Kb1 S0;              DV1 = T'1 X1
//   X2 = V2 - g1*(Kb2 S0) - W21 DV1;  DV2 = T'2 X2   (W21 = Kb2·Kh1^T, precomp)
//   O1 = Qb1 S0 + P1 DV1
//   O2 = g1*(Qb2 S0) + U21 DV1 + P2 DV2              (U21 = Qb2·Kh1^T, precomp)
//   S  = g2*(g1 S0 + Kh1^T DV1) + Kh2^T DV2
// 8 waves = 2 halves (hf) x 4 t-groups (tw); each wave does its half's full
// K=256 reduction in ONE S0 pass. S[256][16] distributed: wave w owns rows
// 32w..32w+31. 5 barriers per pair (vs 8), 1 S0 round trip (vs 2).
__global__ __launch_bounds__(512, 1) void scan_pair(
    const unsigned short* __restrict__ Kb,   // [T][KD] Kbar
    const unsigned short* __restrict__ Qb,   // [T][KD] Qbar
    const unsigned short* __restrict__ KhT,  // [H][NCHK][DK][CK]
    const unsigned short* __restrict__ Tm,   // [H][NCHK][CK][CK]
    const unsigned short* __restrict__ Pm,   // [H][NCHK][CK][CK]
    const unsigned short* __restrict__ W21,  // [H][NPAIR][64][64]
    const unsigned short* __restrict__ U21,  // [H][NPAIR][64][64]
    const float* __restrict__ gammas,        // [H][NCHK]
    float* __restrict__ VO)                  // [T][VD]: V in, O out (in place)
{
  const int h = blockIdx.y, sl = blockIdx.x;
  const int tid = threadIdx.x;
  const int w = tid >> 6, lane = tid & 63;
  const int hf = w >> 2, tw = w & 3;
  const int fr = lane & 15, kq = lane >> 4;

  __shared__ unsigned short S0h[16][264];
  __shared__ unsigned short S0l[16][264];
  __shared__ unsigned short XT[2][16][72];
  __shared__ unsigned short DVT[2][16][72];

  f32x4 st[2];
  st[0] = (f32x4){0.f, 0.f, 0.f, 0.f};
  st[1] = (f32x4){0.f, 0.f, 0.f, 0.f};

  const int colg = h * DVh + sl * 16 + fr;
  const size_t hc0 = (size_t)h * NCHK;
  const int trow = 16 * tw + kq * 4;     // token-row base (within half) for V/O/XT/DVT
  const int frow = 16 * tw + fr;         // fragment row (within half)

  // zero-init S0 staging (cols 0..255 are the ones read)
  {
    int zr = tid >> 5, zc = (tid & 31) * 8;
    ushort4 z; z.x = 0; z.y = 0; z.z = 0; z.w = 0;
    *(ushort4*)&S0h[zr][zc]     = z;
    *(ushort4*)&S0h[zr][zc + 4] = z;
    *(ushort4*)&S0l[zr][zc]     = z;
    *(ushort4*)&S0l[zr][zc + 4] = z;
  }

  bf16x8 kfA[8], kfB[8];
  float vlA[4], vlB[4];

#define PREF(KF, VL, pp) do { \
    const unsigned short* kr_ = Kb + (size_t)((pp) * 128 + hf * 64 + frow) * KD + h * 256 + kq * 8; \
    _Pragma("unroll") \
    for (int kt = 0; kt < 8; ++kt) KF[kt] = *(const bf16x8*)(kr_ + kt * 32); \
    _Pragma("unroll") \
    for (int r = 0; r < 4; ++r) \
      VL[r] = VO[(size_t)((pp) * 128 + hf * 64 + trow + r) * VD + colg]; \
  } while (0)

#define BODY(pp, KF, VL, KFN, VLN) do { \
    const int p_ = (pp); \
    const int t0_ = p_ * 128; \
    const size_t cb1_ = hc0 + 2 * p_, cb2_ = cb1_ + 1; \
    const size_t cbx_ = hf ? cb2_ : cb1_; \
    bf16x8 qf[8]; \
    { const unsigned short* qr_ = Qb + (size_t)(t0_ + hf * 64 + frow) * KD + h * 256 + kq * 8; \
      _Pragma("unroll") \
      for (int kt = 0; kt < 8; ++kt) qf[kt] = *(const bf16x8*)(qr_ + kt * 32); } \
    bf16x8 tpa[2], ppa[2]; \
    { const unsigned short* tr_ = Tm + (cbx_ * CK + frow) * CK + kq * 8; \
      tpa[0] = *(const bf16x8*)(tr_); tpa[1] = *(const bf16x8*)(tr_ + 32); \
      const unsigned short* pr_ = Pm + (cbx_ * CK + frow) * CK + kq * 8; \
      ppa[0] = *(const bf16x8*)(pr_); ppa[1] = *(const bf16x8*)(pr_ + 32); } \
    bf16x8 wuf[4]; \
    if (hf) { \
      const size_t pb_ = ((size_t)h * NPAIR + p_) * 4096; \
      const unsigned short* wr_ = W21 + pb_ + (size_t)frow * 64 + kq * 8; \
      wuf[0] = *(const bf16x8*)(wr_); wuf[1] = *(const bf16x8*)(wr_ + 32); \
      const unsigned short* ur_ = U21 + pb_ + (size_t)frow * 64 + kq * 8; \
      wuf[2] = *(const bf16x8*)(ur_); wuf[3] = *(const bf16x8*)(ur_ + 32); } \
    bf16x8 kh1[2][2], kh2[2][2]; \
    _Pragma("unroll") \
    for (int i = 0; i < 2; ++i) { \
      const unsigned short* h1_ = KhT + (cb1_ * DK + 32 * w + 16 * i + fr) * CK + kq * 8; \
      kh1[i][0] = *(const bf16x8*)(h1_); kh1[i][1] = *(const bf16x8*)(h1_ + 32); \
      const unsigned short* h2_ = KhT + (cb2_ * DK + 32 * w + 16 * i + fr) * CK + kq * 8; \
      kh2[i][0] = *(const bf16x8*)(h2_); kh2[i][1] = *(const bf16x8*)(h2_ + 32); } \
    const float g1_ = gammas[cb1_], g2_ = gammas[cb2_]; \
    { const int pn_ = (p_ + 1 < NPAIR) ? p_ + 1 : p_; PREF(KFN, VLN, pn_); } \
    /* P1: Y(hf) = Kb(hf) S0, Oq(hf) = Qb(hf) S0 over K=256, single S0 pass */ \
    f32x4 yt, ot; \
    { f32x4 yh = (f32x4){0.f,0.f,0.f,0.f}, yl = yh, oh = yh, ol = yh; \
      _Pragma("unroll") \
      for (int kt = 0; kt < 8; ++kt) { \
        bf16x8 bh_ = *(const bf16x8*)&S0h[fr][kt * 32 + kq * 8]; \
        bf16x8 bl_ = *(const bf16x8*)&S0l[fr][kt * 32 + kq * 8]; \
        yh = __builtin_amdgcn_mfma_f32_16x16x32_bf16(KF[kt], bh_, yh, 0, 0, 0); \
        yl = __builtin_amdgcn_mfma_f32_16x16x32_bf16(KF[kt], bl_, yl, 0, 0, 0); \
        oh = __builtin_amdgcn_mfma_f32_16x16x32_bf16(qf[kt], bh_, oh, 0, 0, 0); \
        ol = __builtin_amdgcn_mfma_f32_16x16x32_bf16(qf[kt], bl_, ol, 0, 0, 0); } \
      yt = yh + yl; ot = oh + ol; } \
    if (hf == 0) { \
      ushort4 x4; \
      x4.x = f2bf(VL[0] - yt[0]); x4.y = f2bf(VL[1] - yt[1]); \
      x4.z = f2bf(VL[2] - yt[2]); x4.w = f2bf(VL[3] - yt[3]); \
      *(ushort4*)&XT[0][fr][trow] = x4; } \
    bar_lds();   /* B1: XT1 visible */ \
    if (hf == 0) { \
      f32x4 d = (f32x4){0.f,0.f,0.f,0.f}; \
      bf16x8 b0_ = *(const bf16x8*)&XT[0][fr][kq * 8]; \
      bf16x8 b1_ = *(const bf16x8*)&XT[0][fr][32 + kq * 8]; \
      d = __builtin_amdgcn_mfma_f32_16x16x32_bf16(tpa[0], b0_, d, 0, 0, 0); \
      d = __builtin_amdgcn_mfma_f32_16x16x32_bf16(tpa[1], b1_, d, 0, 0, 0); \
      ushort4 d4; \
      d4.x = f2bf(d[0]); d4.y = f2bf(d[1]); d4.z = f2bf(d[2]); d4.w = f2bf(d[3]); \
      *(ushort4*)&DVT[0][fr][trow] = d4; } \
    bar_lds();   /* B2: DVT1 visible */ \
    bf16x8 dv10 = *(const bf16x8*)&DVT[0][fr][kq * 8]; \
    bf16x8 dv11 = *(const bf16x8*)&DVT[0][fr][32 + kq * 8]; \
    if (hf == 0) { \
      f32x4 op = (f32x4){0.f,0.f,0.f,0.f}; \
      op = __builtin_amdgcn_mfma_f32_16x16x32_bf16(ppa[0], dv10, op, 0, 0, 0); \
      op = __builtin_amdgcn_mfma_f32_16x16x32_bf16(ppa[1], dv11, op, 0, 0, 0); \
      _Pragma("unroll") \
      for (int r = 0; r < 4; ++r) \
        VO[(size_t)(t0_ + trow + r) * VD + colg] = ot[r] + op[r]; \
    } else { \
      f32x4 xw = (f32x4){0.f,0.f,0.f,0.f}; \
      xw = __builtin_amdgcn_mfma_f32_16x16x32_bf16(wuf[0], dv10, xw, 0, 0, 0); \
      xw = __builtin_amdgcn_mfma_f32_16x16x32_bf16(wuf[1], dv11, xw, 0, 0, 0); \
      ushort4 x4; \
      x4.x = f2bf(VL[0] - g1_ * yt[0] - xw[0]); \
      x4.y = f2bf(VL[1] - g1_ * yt[1] - xw[1]); \
      x4.z = f2bf(VL[2] - g1_ * yt[2] - xw[2]); \
      x4.w = f2bf(VL[3] - g1_ * yt[3] - xw[3]); \
      *(ushort4*)&XT[1][fr][trow] = x4; } \
    /* state part A (all waves): st = g1*st + Kh1^T DV1 */ \
    _Pragma("unroll") \
    for (int i = 0; i < 2; ++i) { \
      st[i][0] *= g1_; st[i][1] *= g1_; st[i][2] *= g1_; st[i][3] *= g1_; \
      st[i] = __builtin_amdgcn_mfma_f32_16x16x32_bf16(kh1[i][0], dv10, st[i], 0, 0, 0); \
      st[i] = __builtin_amdgcn_mfma_f32_16x16x32_bf16(kh1[i][1], dv11, st[i], 0, 0, 0); } \
    bar_lds();   /* B3: XT2 visible */ \
    if (hf) { \
      f32x4 d = (f32x4){0.f,0.f,0.f,0.f}; \
      bf16x8 b0_ = *(const bf16x8*)&XT[1][fr][kq * 8]; \
      bf16x8 b1_ = *(const bf16x8*)&XT[1][fr][32 + kq * 8]; \
      d = __builtin_amdgcn_mfma_f32_16x16x32_bf16(tpa[0], b0_, d, 0, 0, 0); \
      d = __builtin_amdgcn_mfma_f32_16x16x32_bf16(tpa[1], b1_, d, 0, 0, 0); \
      ushort4 d4; \
      d4.x = f2bf(d[0]); d4.y = f2bf(d[1]); d4.z = f2bf(d[2]); d4.w = f2bf(d[3]); \
      *(ushort4*)&DVT[1][fr][trow] = d4; } \
    bar_lds();   /* B4: DVT2 visible */ \
    bf16x8 dv20 = *(const bf16x8*)&DVT[1][fr][kq * 8]; \
    bf16x8 dv21 = *(const bf16x8*)&DVT[1][fr][32 + kq * 8]; \
    if (hf) { \
      f32x4 op = (f32x4){0.f,0.f,0.f,0.f}; \
      op = __builtin_amdgcn_mfma_f32_16x16x32_bf16(wuf[2], dv10, op, 0, 0, 0); \
      op = __builtin_amdgcn_mfma_f32_16x16x32_bf16(wuf[3], dv11, op, 0, 0, 0); \
      op = __builtin_amdgcn_mfma_f32_16x16x32_bf16(ppa[0], dv20, op, 0, 0, 0); \
      op = __builtin_amdgcn_mfma_f32_16x16x32_bf16(ppa[1], dv21, op, 0, 0, 0); \
      _Pragma("unroll") \
      for (int r = 0; r < 4; ++r) \
        VO[(size_t)(t0_ + 64 + trow + r) * VD + colg] = g1_ * ot[r] + op[r]; } \
    /* state part B (all): st = g2*st + Kh2^T DV2; stage S0 hi/lo */ \
    _Pragma("unroll") \
    for (int i = 0; i < 2; ++i) { \
      st[i][0] *= g2_; st[i][1] *= g2_; st[i][2] *= g2_; st[i][3] *= g2_; \
      st[i] = __builtin_amdgcn_mfma_f32_16x16x32_bf16(kh2[i][0], dv20, st[i], 0, 0, 0); \
      st[i] = __builtin_amdgcn_mfma_f32_16x16x32_bf16(kh2[i][1], dv21, st[i], 0, 0, 0); \
      ushort4 hi4, lo4; \
      { float s0 = st[i][0], s1 = st[i][1], s2 = st[i][2], s3 = st[i][3]; \
        hi4.x = f2bf(s0); lo4.x = f2bf(s0 - bf2f(hi4.x)); \
        hi4.y = f2bf(s1); lo4.y = f2bf(s1 - bf2f(hi4.y)); \
        hi4.z = f2bf(s2); lo4.z = f2bf(s2 - bf2f(hi4.z)); \
        hi4.w = f2bf(s3); lo4.w = f2bf(s3 - bf2f(hi4.w)); } \
      *(ushort4*)&S0h[fr][32 * w + 16 * i + kq * 4] = hi4; \
      *(ushort4*)&S0l[fr][32 * w + 16 * i + kq * 4] = lo4; } \
    bar_lds();   /* B5: S0 visible for next pair */ \
  } while (0)

  PREF(kfA, vlA, 0);
  __syncthreads();   // covers the LDS zero-init
  for (int p = 0; p < NPAIR; p += 2) {
    BODY(p,     kfA, vlA, kfB, vlB);
    BODY(p + 1, kfB, vlB, kfA, vlA);
  }
#undef BODY
#undef PREF
}

// ---------------- gated RMSNorm ----------------
__global__ __launch_bounds__(256) void norm_gate(
    const float* __restrict__ o, const unsigned short* __restrict__ gate,
    const float* __restrict__ nw, unsigned short* __restrict__ out)
{
  int th = blockIdx.x, tid = threadIdx.x;
  size_t base = (size_t)th * DVh;
  float x0 = o[base + tid], x1 = o[base + 256 + tid];
  float ss = x0 * x0 + x1 * x1;
  for (int m = 32; m >= 1; m >>= 1) ss += __shfl_xor(ss, m);
  __shared__ float red[4];
  if ((tid & 63) == 0) red[tid >> 6] = ss;
  __syncthreads();
  float rms = rsqrtf((red[0] + red[1] + red[2] + red[3]) * (1.f / 512.f) + 1e-5f);
  float g0 = bf2f(gate[base + tid]), g1 = bf2f(gate[base + 256 + tid]);
  out[base + tid]       = f2bf(x0 * rms * nw[tid]       * silu_f(g0));
  out[base + 256 + tid] = f2bf(x1 * rms * nw[tid + 256] * silu_f(g1));
}

extern "C" void kernel_launch(void* const* d_in, const int* in_sizes, int n_in,
                              void* d_out, int out_size, void* d_ws, size_t ws_size,
                              hipStream_t stream)
{
  const float* h       = (const float*)d_in[0];
  const float* Wq      = (const float*)d_in[1];
  const float* Wk      = (const float*)d_in[2];
  const float* Wv      = (const float*)d_in[3];
  const float* Wb      = (const float*)d_in[4];
  const float* Wa      = (const float*)d_in[5];
  const float* Wg      = (const float*)d_in[6];
  const float* Wo      = (const float*)d_in[7];
  const float* A_log   = (const float*)d_in[8];
  const float* dt_bias = (const float*)d_in[9];
  const float* conv_w  = (const float*)d_in[10];
  const float* gen_w1  = (const float*)d_in[11];
  const float* gen_w2  = (const float*)d_in[12];
  const float* norm_w  = (const float*)d_in[13];
  float* out = (float*)d_out;

  const size_t TK = (size_t)T_LEN * KD, TV = (size_t)T_LEN * VD, TD = (size_t)T_LEN * DIM;

  float* ws   = (float*)d_ws;
  float* q    = ws;
  float* k    = q    + TK;
  float* x    = k    + TK;          // h@Wv conv input; region later reused (see aliases)
  float* v    = x    + TV;          // conv out; O written in place by scan
  float* tg   = v    + TV;          // T*256
  float* dyn  = tg   + (size_t)T_LEN * 256;
  float* beta = dyn  + (size_t)T_LEN * 4;
  float* g    = beta + (size_t)T_LEN * 6;
  float* c    = g    + (size_t)T_LEN * 6;       // [H][T]
  float* gam  = c    + (size_t)NH * T_LEN;      // [H][NCHK]
  float* fend = gam  + 512;
  unsigned short* bh      = (unsigned short*)fend;          // T*DIM
  unsigned short* wT      = bh      + TD;                   // DIM*VD
  unsigned short* gate_bf = wT      + (size_t)DIM * VD;     // T*VD
  unsigned short* go_bf   = gate_bf + TV;                   // T*VD
  // aliases (lifetime-disjoint):
  unsigned short* Kb_s  = bh;                 // Kbar: bh dead after projection GEMMs
  unsigned short* Qb_s  = (unsigned short*)x; // x region free after conv (50 MB)
  unsigned short* KhT_s = Qb_s + TK;
  unsigned short* Tm_s  = KhT_s + TK;         // H*NCHK*DK*CK == T*KD
  unsigned short* Pm_s  = Tm_s + (size_t)NH * NCHK * CK * CK;
  unsigned short* W21_s = Pm_s + (size_t)NH * NCHK * CK * CK;   // H*NPAIR*64*64
  unsigned short* U21_s = W21_s + (size_t)NH * NPAIR * 64 * 64; // chain = 34.6 MB < 50 MB
  float* Lg = (float*)go_bf;                  // consumed before norm_gate writes go_bf

  dim3 blk(256);
  cast_bf16<<<(TD / 4) / 256, blk, 0, stream>>>(h, bh);
  tcast<<<dim3(KD / 32, DIM / 32), blk, 0, stream>>>(Wq, wT, DIM, KD);
  gemm_bt_bf16<<<dim3(KD / 128, T_LEN / 128), blk, 0, stream>>>(bh, wT, q, T_LEN, KD, DIM, 1);
  tcast<<<dim3(KD / 32, DIM / 32), blk, 0, stream>>>(Wk, wT, DIM, KD);
  gemm_bt_bf16<<<dim3(KD / 128, T_LEN / 128), blk, 0, stream>>>(bh, wT, k, T_LEN, KD, DIM, 1);
  tcast<<<dim3(VD / 32, DIM / 32), blk, 0, stream>>>(Wv, wT, DIM, VD);
  gemm_bt_bf16<<<dim3(VD / 128, T_LEN / 128), blk, 0, stream>>>(bh, wT, x, T_LEN, VD, DIM, 0);
  tcast<<<dim3(VD / 32, DIM / 32), blk, 0, stream>>>(Wg, wT, DIM, VD);
  gemm_bt_bf16<<<dim3(VD / 128, T_LEN / 128), blk, 0, stream>>>(bh, wT, gate_bf, T_LEN, VD, DIM, 2);
  tcast<<<dim3(256 / 32, DIM / 32), blk, 0, stream>>>(gen_w1, wT, DIM, 256);
  gemm_bt_bf16<<<dim3(256 / 128, T_LEN / 128), blk, 0, stream>>>(bh, wT, tg, T_LEN, 256, DIM, 1);

  proj_dyn<<<T_LEN, blk, 0, stream>>>(tg, gen_w2, dyn);
  proj_bg<<<T_LEN, blk, 0, stream>>>(h, Wb, Wa, A_log, dt_bias, beta, g);
  conv_kernel<<<dim3(VD / 256, T_LEN), blk, 0, stream>>>(x, dyn, conv_w, v);
  l2norm_qk<<<T_LEN * NH, 64, 0, stream>>>(q, k);

  cumsum_g<<<dim3(NCHK, NH), 64, 0, stream>>>(g, c, gam);
  scale_kq<<<T_LEN, 384, 0, stream>>>(q, k, c, Qb_s, Kb_s);
  cross_lp<<<dim3(NPAIR, NH), blk, 0, stream>>>(Kb_s, Qb_s, k, c, W21_s, U21_s);
  make_khT<<<dim3(NCHK, NH), blk, 0, stream>>>(k, c, KhT_s);
  chunk_lp<<<dim3(NCHK, NH), blk, 0, stream>>>(q, k, c, beta, Lg, Pm_s);
  tri_inv<<<dim3(NCHK, NH), 64, 0, stream>>>(Lg, beta, Tm_s);

  scan_pair<<<dim3(DVh / 16, NH), 512, 0, stream>>>(
      Kb_s, Qb_s, KhT_s, Tm_s, Pm_s, W21_s, U21_s, gam, v);

  norm_gate<<<T_LEN * NH, blk, 0, stream>>>(v, gate_bf, norm_w, go_bf);
  tcast<<<dim3(DIM / 32, VD / 32), blk, 0, stream>>>(Wo, wT, VD, DIM);
  gemm_bt_bf16<<<dim3(DIM / 128, T_LEN / 128), blk, 0, stream>>>(go_bf, wT, out, T_LEN, DIM, VD, 0);
}

// Round 5
// 981.841 us; speedup vs baseline: 1.0844x; 1.0844x over previous
//
#include <hip/hip_runtime.h>
#include <hip/hip_bf16.h>
#include <math.h>

#define T_LEN 4096
#define DIM   2048
#define NH    6
#define DK    256
#define DVh   512
#define KD    1536
#define VD    3072
#define CK    64
#define NCHK  (T_LEN / CK)
#define NFUSE 9472   // 1536(q)+1536(k)+3072(x)+3072(gate)+256(tg)

typedef __attribute__((ext_vector_type(8))) short bf16x8;
typedef __attribute__((ext_vector_type(4))) float f32x4;

__device__ __forceinline__ float silu_f(float v){ return v / (1.f + __expf(-v)); }

__device__ __forceinline__ unsigned short f2bf(float f) {
  unsigned int u = __float_as_uint(f);
  unsigned int r = u + 0x7FFFu + ((u >> 16) & 1u);
  return (unsigned short)(r >> 16);
}
__device__ __forceinline__ float bf2f(unsigned short s) {
  return __uint_as_float(((unsigned int)s) << 16);
}

// LDS-only barrier: drains lgkmcnt but leaves global loads/stores in flight.
__device__ __forceinline__ void bar_lds() {
  __builtin_amdgcn_sched_barrier(0);
  asm volatile("s_waitcnt lgkmcnt(0)" ::: "memory");
  __builtin_amdgcn_s_barrier();
  __builtin_amdgcn_sched_barrier(0);
}

// ---------------- cast fp32 -> bf16 ----------------
__global__ __launch_bounds__(256) void cast_bf16(
    const float* __restrict__ in, unsigned short* __restrict__ out)
{
  int i = blockIdx.x * 256 + threadIdx.x;
  float4 v4 = ((const float4*)in)[i];
  ushort4 o4;
  o4.x = f2bf(v4.x); o4.y = f2bf(v4.y); o4.z = f2bf(v4.z); o4.w = f2bf(v4.w);
  ((ushort4*)out)[i] = o4;
}

// ---------------- transpose + cast: in[R][Cn] fp32 -> out[Cn][R] bf16 ----------------
__global__ __launch_bounds__(256) void tcast(
    const float* __restrict__ in, unsigned short* __restrict__ out, int R, int Cn)
{
  __shared__ float tile[32][33];
  int bx = blockIdx.x * 32;
  int by = blockIdx.y * 32;
  int tx = threadIdx.x & 31, ty = threadIdx.x >> 5;
#pragma unroll
  for (int i = 0; i < 32; i += 8)
    tile[ty + i][tx] = in[(size_t)(by + ty + i) * Cn + bx + tx];
  __syncthreads();
#pragma unroll
  for (int i = 0; i < 32; i += 8)
    out[(size_t)(bx + ty + i) * R + by + tx] = f2bf(tile[tx][ty + i]);
}

// ---------------- bf16 MFMA GEMM (m97 structure; generic, used for out-proj) ----------------
__global__ __launch_bounds__(256) void gemm_bt_bf16(
    const unsigned short* __restrict__ A, const unsigned short* __restrict__ BT,
    void* __restrict__ Cout, int M, int N, int K, int act)
{
  __shared__ unsigned short As[128 * 32];
  __shared__ unsigned short Bs[128 * 32];
  const int tid = threadIdx.x;
  const int bm = blockIdx.y * 128, bn = blockIdx.x * 128;
  const int lane = tid & 63, wave = tid >> 6;
  const int wm = (wave >> 1) * 64, wn = (wave & 1) * 64;
  const int fr = lane & 15, kq = lane >> 4;

  f32x4 acc[4][4];
#pragma unroll
  for (int i = 0; i < 4; ++i)
#pragma unroll
    for (int j = 0; j < 4; ++j) acc[i][j] = (f32x4){0.f, 0.f, 0.f, 0.f};

  const int r0 = tid >> 2, c0 = (tid & 3) * 8;
  const int r1 = r0 + 64;

  for (int k0 = 0; k0 < K; k0 += 32) {
    __builtin_amdgcn_global_load_lds(
        (const __attribute__((address_space(1))) unsigned int*)(A + (size_t)(bm + r0) * K + k0 + c0),
        (__attribute__((address_space(3))) unsigned int*)(As + r0 * 32 + c0), 16, 0, 0);
    __builtin_amdgcn_global_load_lds(
        (const __attribute__((address_space(1))) unsigned int*)(A + (size_t)(bm + r1) * K + k0 + c0),
        (__attribute__((address_space(3))) unsigned int*)(As + r1 * 32 + c0), 16, 0, 0);
    __builtin_amdgcn_global_load_lds(
        (const __attribute__((address_space(1))) unsigned int*)(BT + (size_t)(bn + r0) * K + k0 + c0),
        (__attribute__((address_space(3))) unsigned int*)(Bs + r0 * 32 + c0), 16, 0, 0);
    __builtin_amdgcn_global_load_lds(
        (const __attribute__((address_space(1))) unsigned int*)(BT + (size_t)(bn + r1) * K + k0 + c0),
        (__attribute__((address_space(3))) unsigned int*)(Bs + r1 * 32 + c0), 16, 0, 0);
    __syncthreads();

    bf16x8 af[4], bfr[4];
#pragma unroll
    for (int i = 0; i < 4; ++i)
      af[i] = *(const bf16x8*)(As + (wm + i * 16 + fr) * 32 + kq * 8);
#pragma unroll
    for (int j = 0; j < 4; ++j)
      bfr[j] = *(const bf16x8*)(Bs + (wn + j * 16 + fr) * 32 + kq * 8);
#pragma unroll
    for (int i = 0; i < 4; ++i)
#pragma unroll
      for (int j = 0; j < 4; ++j)
        acc[i][j] = __builtin_amdgcn_mfma_f32_16x16x32_bf16(af[i], bfr[j], acc[i][j], 0, 0, 0);
    __syncthreads();
  }

  if (act == 2) {
    unsigned short* C = (unsigned short*)Cout;
#pragma unroll
    for (int i = 0; i < 4; ++i) {
      int rbase = bm + wm + i * 16 + kq * 4;
#pragma unroll
      for (int r = 0; r < 4; ++r) {
        size_t rowoff = (size_t)(rbase + r) * N + bn + wn + fr;
#pragma unroll
        for (int j = 0; j < 4; ++j) C[rowoff + j * 16] = f2bf(acc[i][j][r]);
      }
    }
  } else {
    float* C = (float*)Cout;
#pragma unroll
    for (int i = 0; i < 4; ++i) {
      int rbase = bm + wm + i * 16 + kq * 4;
#pragma unroll
      for (int r = 0; r < 4; ++r) {
        size_t rowoff = (size_t)(rbase + r) * N + bn + wn + fr;
#pragma unroll
        for (int j = 0; j < 4; ++j) {
          float v = acc[i][j][r];
          if (act == 1) v = silu_f(v);
          C[rowoff + j * 16] = v;
        }
      }
    }
  }
}

// ---------------- fused projection GEMM: [T][DIM] x [DIM][9472] in one launch ----------------
// Segments (col ranges of the stacked B^T): [0,1536) q silu | [1536,3072) k silu |
// [3072,6144) x linear | [6144,9216) gate bf16 | [9216,9472) tg silu.
// Each 128-col block lies entirely within one segment -> per-block uniform epilogue.
__global__ __launch_bounds__(256) void gemm_fused(
    const unsigned short* __restrict__ A, const unsigned short* __restrict__ BT,
    float* __restrict__ Cq, float* __restrict__ Ck, float* __restrict__ Cx,
    unsigned short* __restrict__ Cg, float* __restrict__ Ct)
{
  __shared__ unsigned short As[128 * 32];
  __shared__ unsigned short Bs[128 * 32];
  const int tid = threadIdx.x;
  const int bm = blockIdx.y * 128, bn = blockIdx.x * 128;
  const int lane = tid & 63, wave = tid >> 6;
  const int wm = (wave >> 1) * 64, wn = (wave & 1) * 64;
  const int fr = lane & 15, kq = lane >> 4;
  const int K = DIM;

  f32x4 acc[4][4];
#pragma unroll
  for (int i = 0; i < 4; ++i)
#pragma unroll
    for (int j = 0; j < 4; ++j) acc[i][j] = (f32x4){0.f, 0.f, 0.f, 0.f};

  const int r0 = tid >> 2, c0 = (tid & 3) * 8;
  const int r1 = r0 + 64;

  for (int k0 = 0; k0 < K; k0 += 32) {
    __builtin_amdgcn_global_load_lds(
        (const __attribute__((address_space(1))) unsigned int*)(A + (size_t)(bm + r0) * K + k0 + c0),
        (__attribute__((address_space(3))) unsigned int*)(As + r0 * 32 + c0), 16, 0, 0);
    __builtin_amdgcn_global_load_lds(
        (const __attribute__((address_space(1))) unsigned int*)(A + (size_t)(bm + r1) * K + k0 + c0),
        (__attribute__((address_space(3))) unsigned int*)(As + r1 * 32 + c0), 16, 0, 0);
    __builtin_amdgcn_global_load_lds(
        (const __attribute__((address_space(1))) unsigned int*)(BT + (size_t)(bn + r0) * K + k0 + c0),
        (__attribute__((address_space(3))) unsigned int*)(Bs + r0 * 32 + c0), 16, 0, 0);
    __builtin_amdgcn_global_load_lds(
        (const __attribute__((address_space(1))) unsigned int*)(BT + (size_t)(bn + r1) * K + k0 + c0),
        (__attribute__((address_space(3))) unsigned int*)(Bs + r1 * 32 + c0), 16, 0, 0);
    __syncthreads();

    bf16x8 af[4], bfr[4];
#pragma unroll
    for (int i = 0; i < 4; ++i)
      af[i] = *(const bf16x8*)(As + (wm + i * 16 + fr) * 32 + kq * 8);
#pragma unroll
    for (int j = 0; j < 4; ++j)
      bfr[j] = *(const bf16x8*)(Bs + (wn + j * 16 + fr) * 32 + kq * 8);
#pragma unroll
    for (int i = 0; i < 4; ++i)
#pragma unroll
      for (int j = 0; j < 4; ++j)
        acc[i][j] = __builtin_amdgcn_mfma_f32_16x16x32_bf16(af[i], bfr[j], acc[i][j], 0, 0, 0);
    __syncthreads();
  }

  // segment resolve (block-uniform)
  float* Fd = nullptr; unsigned short* Bd = nullptr;
  int strideN, cb, mode;   // mode: 0=fp32, 1=silu fp32, 2=bf16
  if (bn < 1536)      { Fd = Cq; strideN = 1536; cb = bn;        mode = 1; }
  else if (bn < 3072) { Fd = Ck; strideN = 1536; cb = bn - 1536; mode = 1; }
  else if (bn < 6144) { Fd = Cx; strideN = 3072; cb = bn - 3072; mode = 0; }
  else if (bn < 9216) { Bd = Cg; strideN = 3072; cb = bn - 6144; mode = 2; }
  else                { Fd = Ct; strideN = 256;  cb = bn - 9216; mode = 1; }

  if (mode == 2) {
#pragma unroll
    for (int i = 0; i < 4; ++i) {
      int rbase = bm + wm + i * 16 + kq * 4;
#pragma unroll
      for (int r = 0; r < 4; ++r) {
        size_t rowoff = (size_t)(rbase + r) * strideN + cb + wn + fr;
#pragma unroll
        for (int j = 0; j < 4; ++j) Bd[rowoff + j * 16] = f2bf(acc[i][j][r]);
      }
    }
  } else {
#pragma unroll
    for (int i = 0; i < 4; ++i) {
      int rbase = bm + wm + i * 16 + kq * 4;
#pragma unroll
      for (int r = 0; r < 4; ++r) {
        size_t rowoff = (size_t)(rbase + r) * strideN + cb + wn + fr;
#pragma unroll
        for (int j = 0; j < 4; ++j) {
          float v = acc[i][j][r];
          if (mode == 1) v = silu_f(v);
          Fd[rowoff + j * 16] = v;
        }
      }
    }
  }
}

// ---------------- dyn = tg @ gen_w2 ----------------
__global__ __launch_bounds__(256) void proj_dyn(
    const float* __restrict__ tg, const float* __restrict__ w2, float* __restrict__ dyn)
{
  int t = blockIdx.x, tid = threadIdx.x;
  float g = tg[(size_t)t * 256 + tid];
  float p[4];
#pragma unroll
  for (int j = 0; j < 4; ++j) p[j] = g * w2[tid * 4 + j];
#pragma unroll
  for (int j = 0; j < 4; ++j)
    for (int m = 32; m >= 1; m >>= 1) p[j] += __shfl_xor(p[j], m);
  __shared__ float red[4][4];
  if ((tid & 63) == 0) {
    int w = tid >> 6;
#pragma unroll
    for (int j = 0; j < 4; ++j) red[w][j] = p[j];
  }
  __syncthreads();
  if (tid < 4) dyn[(size_t)t * 4 + tid] = red[0][tid] + red[1][tid] + red[2][tid] + red[3][tid];
}

// ---------------- beta / raw decay log-gate g ----------------
__global__ __launch_bounds__(256) void proj_bg(
    const float* __restrict__ h, const float* __restrict__ Wb, const float* __restrict__ Wa,
    const float* __restrict__ A_log, const float* __restrict__ dt_bias,
    float* __restrict__ beta, float* __restrict__ gout)
{
  int t = blockIdx.x, tid = threadIdx.x;
  float pb[6], pa[6];
#pragma unroll
  for (int j = 0; j < 6; ++j) { pb[j] = 0.f; pa[j] = 0.f; }
  for (int d = tid; d < DIM; d += 256) {
    float hv = h[(size_t)t * DIM + d];
#pragma unroll
    for (int j = 0; j < 6; ++j) {
      pb[j] += hv * Wb[d * 6 + j];
      pa[j] += hv * Wa[d * 6 + j];
    }
  }
#pragma unroll
  for (int j = 0; j < 6; ++j)
    for (int m = 32; m >= 1; m >>= 1) { pb[j] += __shfl_xor(pb[j], m); pa[j] += __shfl_xor(pa[j], m); }
  __shared__ float rb[4][6], ra[4][6];
  if ((tid & 63) == 0) {
    int w = tid >> 6;
#pragma unroll
    for (int j = 0; j < 6; ++j) { rb[w][j] = pb[j]; ra[w][j] = pa[j]; }
  }
  __syncthreads();
  if (tid < 6) {
    int j = tid;
    float sb = rb[0][j] + rb[1][j] + rb[2][j] + rb[3][j];
    float sa = ra[0][j] + ra[1][j] + ra[2][j] + ra[3][j];
    beta[(size_t)t * 6 + j] = 1.f / (1.f + expf(-sb));
    float z = sa + dt_bias[j];
    float sp = (z > 20.f) ? z : log1pf(expf(z));
    gout[(size_t)t * 6 + j] = -expf(A_log[j]) * sp;   // raw log-gate (g < 0)
  }
}

// ---------------- causal dynamic conv + silu ----------------
__global__ __launch_bounds__(256) void conv_kernel(
    const float* __restrict__ x, const float* __restrict__ dyn,
    const float* __restrict__ cw, float* __restrict__ v)
{
  int c = blockIdx.x * 256 + threadIdx.x;
  int t = blockIdx.y;
  float4 w4 = ((const float4*)cw)[c];
  float d0 = dyn[t * 4 + 0], d1 = dyn[t * 4 + 1], d2 = dyn[t * 4 + 2], d3 = dyn[t * 4 + 3];
  float acc = (w4.w + d3) * x[(size_t)t * VD + c];
  if (t >= 1) acc += (w4.z + d2) * x[(size_t)(t - 1) * VD + c];
  if (t >= 2) acc += (w4.y + d1) * x[(size_t)(t - 2) * VD + c];
  if (t >= 3) acc += (w4.x + d0) * x[(size_t)(t - 3) * VD + c];
  v[(size_t)t * VD + c] = silu_f(acc);
}

// ---------------- P1: within-chunk inclusive cumsum of g, gamma = exp(c_end) ----------------
__global__ __launch_bounds__(64) void cumsum_g(
    const float* __restrict__ g, float* __restrict__ c, float* __restrict__ gammas)
{
  int ch = blockIdx.x, h = blockIdx.y;
  int t0 = ch * CK;
  int lane = threadIdx.x;
  float cum = g[(size_t)(t0 + lane) * 6 + h];
  for (int off = 1; off < 64; off <<= 1) {
    float n = __shfl_up(cum, off);
    if (lane >= off) cum += n;
  }
  c[(size_t)h * T_LEN + t0 + lane] = cum;
  if (lane == 63) gammas[h * NCHK + ch] = __expf(cum);
}

// ---------------- fused l2norm + Kbar/Qbar scale (replaces l2norm_qk + scale_kq) ----------------
// 384 threads = 6 waves; wave h handles head h of row t. Normalizes q,k in place
// (fp32, consumed by chunk_lp/make_khT) and writes Qb/Kb = exp(c_t)*normalized (bf16).
__global__ __launch_bounds__(384) void l2scale(
    float* __restrict__ q, float* __restrict__ k, const float* __restrict__ c,
    unsigned short* __restrict__ Qb, unsigned short* __restrict__ Kb)
{
  int t = blockIdx.x;
  int h = threadIdx.x >> 6, lane = threadIdx.x & 63;
  size_t off = (size_t)t * KD + h * 256 + lane * 4;
  float4 qv = *(const float4*)(q + off);
  float4 kv = *(const float4*)(k + off);
  float sq = qv.x*qv.x + qv.y*qv.y + qv.z*qv.z + qv.w*qv.w;
  float sk = kv.x*kv.x + kv.y*kv.y + kv.z*kv.z + kv.w*kv.w;
  for (int m = 32; m >= 1; m >>= 1) { sq += __shfl_xor(sq, m); sk += __shfl_xor(sk, m); }
  float rq = rsqrtf(sq + 1e-6f) * 0.0625f;   // fold DK^-0.5
  float rk = rsqrtf(sk + 1e-6f);
  qv.x *= rq; qv.y *= rq; qv.z *= rq; qv.w *= rq;
  kv.x *= rk; kv.y *= rk; kv.z *= rk; kv.w *= rk;
  *(float4*)(q + off) = qv;
  *(float4*)(k + off) = kv;
  float w1 = __expf(c[(size_t)h * T_LEN + t]);
  ushort4 qo, ko;
  qo.x = f2bf(w1 * qv.x); qo.y = f2bf(w1 * qv.y); qo.z = f2bf(w1 * qv.z); qo.w = f2bf(w1 * qv.w);
  ko.x = f2bf(w1 * kv.x); ko.y = f2bf(w1 * kv.y); ko.z = f2bf(w1 * kv.z); ko.w = f2bf(w1 * kv.w);
  *(ushort4*)(Qb + off) = qo;
  *(ushort4*)(Kb + off) = ko;
}

// ---------------- P2b: KhT[h][ch][kk][tt] = exp(c_end - c_t) * k[t][kk]  (bf16) ----------------
__global__ __launch_bounds__(256) void make_khT(
    const float* __restrict__ k, const float* __restrict__ c,
    unsigned short* __restrict__ KhT)
{
  int ch = blockIdx.x, h = blockIdx.y;
  int t0 = ch * CK;
  int tt = threadIdx.x & 63, ks = threadIdx.x >> 6;
  float cend = c[(size_t)h * T_LEN + t0 + 63];
  float w2 = __expf(cend - c[(size_t)h * T_LEN + t0 + tt]);
  size_t obase = ((size_t)(h * NCHK + ch)) * DK * CK;
#pragma unroll 8
  for (int kb2 = 0; kb2 < 64; ++kb2) {
    int kk = ks * 64 + kb2;
    float kv = k[(size_t)(t0 + tt) * KD + h * 256 + kk];
    KhT[obase + (size_t)kk * CK + tt] = f2bf(w2 * kv);
  }
}

// ---------------- P3: per (h,chunk): L, P via MFMA ----------------
__global__ __launch_bounds__(256) void chunk_lp(
    const float* __restrict__ q, const float* __restrict__ k,
    const float* __restrict__ c, const float* __restrict__ beta,
    float* __restrict__ Lg, unsigned short* __restrict__ Pm)
{
  const int ch = blockIdx.x, h = blockIdx.y;
  const int t0 = ch * CK;
  const int tid = threadIdx.x;
  const int w = tid >> 6, lane = tid & 63, fr = lane & 15, kq = lane >> 4;
  __shared__ unsigned short kb[64][264];
  __shared__ unsigned short qb[64][264];
  __shared__ float cs[64], bs[64];
#pragma unroll
  for (int i = 0; i < 16; ++i) {
    int fi = tid + i * 256;
    int r = fi >> 6, d4 = fi & 63;
    float4 kv = *(const float4*)(k + (size_t)(t0 + r) * KD + h * 256 + d4 * 4);
    float4 qv = *(const float4*)(q + (size_t)(t0 + r) * KD + h * 256 + d4 * 4);
    ushort4 k4, q4;
    k4.x = f2bf(kv.x); k4.y = f2bf(kv.y); k4.z = f2bf(kv.z); k4.w = f2bf(kv.w);
    q4.x = f2bf(qv.x); q4.y = f2bf(qv.y); q4.z = f2bf(qv.z); q4.w = f2bf(qv.w);
    *(ushort4*)&kb[r][d4 * 4] = k4;
    *(ushort4*)&qb[r][d4 * 4] = q4;
  }
  if (tid < 64) {
    cs[tid] = c[(size_t)h * T_LEN + t0 + tid];
    bs[tid] = beta[(size_t)(t0 + tid) * 6 + h];
  }
  __syncthreads();

  f32x4 akk[4], aqk[4];
#pragma unroll
  for (int j = 0; j < 4; ++j) { akk[j] = (f32x4){0,0,0,0}; aqk[j] = (f32x4){0,0,0,0}; }
#pragma unroll
  for (int kt = 0; kt < 8; ++kt) {
    bf16x8 ak = *(const bf16x8*)&kb[16 * w + fr][kt * 32 + kq * 8];
    bf16x8 aq = *(const bf16x8*)&qb[16 * w + fr][kt * 32 + kq * 8];
#pragma unroll
    for (int j = 0; j < 4; ++j) {
      bf16x8 b = *(const bf16x8*)&kb[j * 16 + fr][kt * 32 + kq * 8];
      akk[j] = __builtin_amdgcn_mfma_f32_16x16x32_bf16(ak, b, akk[j], 0, 0, 0);
      aqk[j] = __builtin_amdgcn_mfma_f32_16x16x32_bf16(aq, b, aqk[j], 0, 0, 0);
    }
  }
  size_t base = ((size_t)(h * NCHK + ch)) * CK * CK;
#pragma unroll
  for (int j = 0; j < 4; ++j) {
#pragma unroll
    for (int r = 0; r < 4; ++r) {
      int t = 16 * w + kq * 4 + r, col = j * 16 + fr;
      float e = __expf(fminf(cs[t] - cs[col], 0.f));
      Lg[base + t * 64 + col] = (col < t) ? bs[t] * e * akk[j][r] : 0.f;
      Pm[base + t * 64 + col] = f2bf((col <= t) ? e * aqk[j][r] : 0.f);
    }
  }
}

// ---------------- P4: T' = (I+L)^{-1} diag(beta)  (bf16) ----------------
__global__ __launch_bounds__(64) void tri_inv(
    const float* __restrict__ Lg, const float* __restrict__ beta,
    unsigned short* __restrict__ Tm)
{
  const int ch = blockIdx.x, h = blockIdx.y;
  const size_t base = ((size_t)(h * NCHK + ch)) * CK * CK;
  const int j = threadIdx.x;
  __shared__ float Ll[64][65];
  __shared__ float Tl[64][65];
  for (int t = 0; t < 64; ++t) Ll[t][j] = Lg[base + t * 64 + j];
  __syncthreads();
  for (int t = 0; t < 64; ++t) {
    float s;
    if (j > t) s = 0.f;
    else if (j == t) s = 1.f;
    else {
      s = 0.f;
      for (int m = j; m < t; ++m) s -= Ll[t][m] * Tl[m][j];
    }
    Tl[t][j] = s;
  }
  float bj = beta[(size_t)(ch * 64 + j) * 6 + h];
  for (int t = 0; t < 64; ++t) Tm[base + t * 64 + j] = f2bf(Tl[t][j] * bj);
}

// ---------------- chunked gated delta-rule scan (MFMA, 8-wave) — R3 form ----------------
// grid (32, 6): blockIdx.x = 16-col slice of DVh, blockIdx.y = head.
// 8 waves (512 threads) = 4 t-groups (tw) x 2 K-groups (kg).
// State S[256][16] fp32 in accumulators: wave w owns DK rows 32w..32w+31.
// Phase 1's DK=256 reduction split across kg (128 each); partial Y/O exchanged
// through LDS. 2 waves/SIMD hide each other's stalls. Best measured scan: 226.6 us.
__global__ __launch_bounds__(512, 2) void scan_chunk(
    const unsigned short* __restrict__ Kb,   // [T][KD] Kbar
    const unsigned short* __restrict__ Qb,   // [T][KD] Qbar
    const unsigned short* __restrict__ KhT,  // [H][NCHK][DK][CK]
    const unsigned short* __restrict__ Tm,   // [H][NCHK][CK][CK]
    const unsigned short* __restrict__ Pm,   // [H][NCHK][CK][CK]
    const float* __restrict__ gammas,        // [H][NCHK]
    float* __restrict__ VO)                  // [T][VD]: V in, O out (in place)
{
  const int h = blockIdx.y, sl = blockIdx.x;
  const int tid = threadIdx.x;
  const int w = tid >> 6, lane = tid & 63;
  const int tw = w & 3, kg = w >> 2;
  const int fr = lane & 15, kq = lane >> 4;

  __shared__ unsigned short S0h[16][264];
  __shared__ unsigned short S0l[16][264];
  __shared__ unsigned short XT[16][72];
  __shared__ unsigned short DVT[16][72];
  __shared__ float PY[2][4][16][20];   // partial Y, [kg][tw][fr][kq*4+r]
  __shared__ float PO[2][4][16][20];   // partial O

  f32x4 st[2];
  st[0] = (f32x4){0.f, 0.f, 0.f, 0.f};
  st[1] = (f32x4){0.f, 0.f, 0.f, 0.f};

  const int colg = h * DVh + sl * 16 + fr;
  const size_t hc0 = (size_t)h * NCHK;

  // zero-init S0 staging (cols 0..255 are the ones read)
  {
    int zr = tid >> 5;          // 0..15
    int zc = (tid & 31) * 8;    // 0..248
    ushort4 z; z.x = 0; z.y = 0; z.z = 0; z.w = 0;
    *(ushort4*)&S0h[zr][zc]     = z;
    *(ushort4*)&S0h[zr][zc + 4] = z;
    *(ushort4*)&S0l[zr][zc]     = z;
    *(ushort4*)&S0l[zr][zc + 4] = z;
  }

  bf16x8 kfA[4], kfB[4], qfA[4], qfB[4];
  float vlA[4], vlB[4];

#define PREF(KF, QF, VL, chn) do { \
    const unsigned short* kr_ = Kb + (size_t)((chn) * CK + 16 * tw + fr) * KD + h * 256 + kg * 128 + kq * 8; \
    const unsigned short* qr_ = Qb + (size_t)((chn) * CK + 16 * tw + fr) * KD + h * 256 + kg * 128 + kq * 8; \
    _Pragma("unroll") \
    for (int kt = 0; kt < 4; ++kt) { \
      KF[kt] = *(const bf16x8*)(kr_ + kt * 32); \
      QF[kt] = *(const bf16x8*)(qr_ + kt * 32); } \
    if (kg == 0) { \
      _Pragma("unroll") \
      for (int r = 0; r < 4; ++r) VL[r] = VO[(size_t)((chn) * CK + 16 * tw + kq * 4 + r) * VD + colg]; } \
  } while (0)

#define BODY(chx, KF, QF, VL, KFN, QFN, VLN) do { \
    const int ch_ = (chx); \
    const int t0_ = ch_ * CK; \
    const size_t cb_ = hc0 + ch_; \
    /* tpf: kg0 = T' rows (for DV), kg1 = P rows (for O) */ \
    bf16x8 tpf[2]; \
    { const unsigned short* b_ = (kg == 0 ? Tm : Pm) + (cb_ * CK + 16 * tw + fr) * CK + kq * 8; \
      tpf[0] = *(const bf16x8*)(b_); tpf[1] = *(const bf16x8*)(b_ + 32); } \
    bf16x8 hfr[2][2]; \
    _Pragma("unroll") \
    for (int i = 0; i < 2; ++i) { \
      const unsigned short* hr_ = KhT + (cb_ * DK + 32 * w + 16 * i + fr) * CK + kq * 8; \
      hfr[i][0] = *(const bf16x8*)(hr_); hfr[i][1] = *(const bf16x8*)(hr_ + 32); } \
    const float gam_ = gammas[cb_]; \
    { const int chn_ = (ch_ + 1 < NCHK) ? ch_ + 1 : ch_; PREF(KFN, QFN, VLN, chn_); } \
    /* P1: partial Y/O over this wave's half of DK (4 kt) */ \
    f32x4 yt, ot; \
    { f32x4 yh = (f32x4){0.f,0.f,0.f,0.f}, yl = yh, oh = yh, ol = yh; \
      __builtin_amdgcn_s_setprio(1); \
      _Pragma("unroll") \
      for (int kt = 0; kt < 4; ++kt) { \
        const int ka_ = (kg * 4 + kt) * 32 + kq * 8; \
        bf16x8 bh_ = *(const bf16x8*)&S0h[fr][ka_]; \
        bf16x8 bl_ = *(const bf16x8*)&S0l[fr][ka_]; \
        yh = __builtin_amdgcn_mfma_f32_16x16x32_bf16(KF[kt], bh_, yh, 0, 0, 0); \
        yl = __builtin_amdgcn_mfma_f32_16x16x32_bf16(KF[kt], bl_, yl, 0, 0, 0); \
        oh = __builtin_amdgcn_mfma_f32_16x16x32_bf16(QF[kt], bh_, oh, 0, 0, 0); \
        ol = __builtin_amdgcn_mfma_f32_16x16x32_bf16(QF[kt], bl_, ol, 0, 0, 0); } \
      __builtin_amdgcn_s_setprio(0); \
      yt = yh + yl; ot = oh + ol; } \
    *(f32x4*)&PY[kg][tw][fr][kq * 4] = yt; \
    *(f32x4*)&PO[kg][tw][fr][kq * 4] = ot; \
    bar_lds();   /* B1: partials visible */ \
    if (kg == 0) { \
      f32x4 yo = *(const f32x4*)&PY[1][tw][fr][kq * 4]; \
      ushort4 x4; \
      x4.x = f2bf(VL[0] - (yt[0] + yo[0])); \
      x4.y = f2bf(VL[1] - (yt[1] + yo[1])); \
      x4.z = f2bf(VL[2] - (yt[2] + yo[2])); \
      x4.w = f2bf(VL[3] - (yt[3] + yo[3])); \
      *(ushort4*)&XT[fr][16 * tw + kq * 4] = x4; \
    } else { \
      f32x4 oo = *(const f32x4*)&PO[0][tw][fr][kq * 4]; \
      ot[0] += oo[0]; ot[1] += oo[1]; ot[2] += oo[2]; ot[3] += oo[3]; } \
    bar_lds();   /* B2: XT visible */ \
    /* P2: DV = T' X (kg0 only) */ \
    if (kg == 0) { \
      f32x4 d = (f32x4){0.f,0.f,0.f,0.f}; \
      bf16x8 b0_ = *(const bf16x8*)&XT[fr][kq * 8]; \
      bf16x8 b1_ = *(const bf16x8*)&XT[fr][32 + kq * 8]; \
      d = __builtin_amdgcn_mfma_f32_16x16x32_bf16(tpf[0], b0_, d, 0, 0, 0); \
      d = __builtin_amdgcn_mfma_f32_16x16x32_bf16(tpf[1], b1_, d, 0, 0, 0); \
      ushort4 d4; \
      d4.x = f2bf(d[0]); d4.y = f2bf(d[1]); d4.z = f2bf(d[2]); d4.w = f2bf(d[3]); \
      *(ushort4*)&DVT[fr][16 * tw + kq * 4] = d4; } \
    bar_lds();   /* B3: DVT visible */ \
    /* P3: O-store (kg1), state update + S0 staging (all) */ \
    { bf16x8 dv0_ = *(const bf16x8*)&DVT[fr][kq * 8]; \
      bf16x8 dv1_ = *(const bf16x8*)&DVT[fr][32 + kq * 8]; \
      if (kg == 1) { \
        f32x4 op = (f32x4){0.f,0.f,0.f,0.f}; \
        op = __builtin_amdgcn_mfma_f32_16x16x32_bf16(tpf[0], dv0_, op, 0, 0, 0); \
        op = __builtin_amdgcn_mfma_f32_16x16x32_bf16(tpf[1], dv1_, op, 0, 0, 0); \
        _Pragma("unroll") \
        for (int r = 0; r < 4; ++r) \
          VO[(size_t)(t0_ + 16 * tw + kq * 4 + r) * VD + colg] = ot[r] + op[r]; } \
      __builtin_amdgcn_s_setprio(1); \
      _Pragma("unroll") \
      for (int i = 0; i < 2; ++i) { \
        st[i][0] *= gam_; st[i][1] *= gam_; st[i][2] *= gam_; st[i][3] *= gam_; \
        st[i] = __builtin_amdgcn_mfma_f32_16x16x32_bf16(hfr[i][0], dv0_, st[i], 0, 0, 0); \
        st[i] = __builtin_amdgcn_mfma_f32_16x16x32_bf16(hfr[i][1], dv1_, st[i], 0, 0, 0); \
        ushort4 hi4, lo4; \
        { float s0 = st[i][0], s1 = st[i][1], s2 = st[i][2], s3 = st[i][3]; \
          hi4.x = f2bf(s0); lo4.x = f2bf(s0 - bf2f(hi4.x)); \
          hi4.y = f2bf(s1); lo4.y = f2bf(s1 - bf2f(hi4.y)); \
          hi4.z = f2bf(s2); lo4.z = f2bf(s2 - bf2f(hi4.z)); \
          hi4.w = f2bf(s3); lo4.w = f2bf(s3 - bf2f(hi4.w)); } \
        *(ushort4*)&S0h[fr][32 * w + 16 * i + kq * 4] = hi4; \
        *(ushort4*)&S0l[fr][32 * w + 16 * i + kq * 4] = lo4; } \
      __builtin_amdgcn_s_setprio(0); } \
    bar_lds();   /* B4: S0 visible for next chunk */ \
  } while (0)

  PREF(kfA, qfA, vlA, 0);
  __syncthreads();   // covers the LDS zero-init
  for (int ch = 0; ch < NCHK; ch += 2) {
    BODY(ch,     kfA, qfA, vlA, kfB, qfB, vlB);
    BODY(ch + 1, kfB, qfB, vlB, kfA, qfA, vlA);
  }
#undef BODY
#undef PREF
}

// ---------------- gated RMSNorm ----------------
__global__ __launch_bounds__(256) void norm_gate(
    const float* __restrict__ o, const unsigned short* __restrict__ gate,
    const float* __restrict__ nw, unsigned short* __restrict__ out)
{
  int th = blockIdx.x, tid = threadIdx.x;
  size_t base = (size_t)th * DVh;
  float x0 = o[base + tid], x1 = o[base + 256 + tid];
  float ss = x0 * x0 + x1 * x1;
  for (int m = 32; m >= 1; m >>= 1) ss += __shfl_xor(ss, m);
  __shared__ float red[4];
  if ((tid & 63) == 0) red[tid >> 6] = ss;
  __syncthreads();
  float rms = rsqrtf((red[0] + red[1] + red[2] + red[3]) * (1.f / 512.f) + 1e-5f);
  float g0 = bf2f(gate[base + tid]), g1 = bf2f(gate[base + 256 + tid]);
  out[base + tid]       = f2bf(x0 * rms * nw[tid]       * silu_f(g0));
  out[base + 256 + tid] = f2bf(x1 * rms * nw[tid + 256] * silu_f(g1));
}

extern "C" void kernel_launch(void* const* d_in, const int* in_sizes, int n_in,
                              void* d_out, int out_size, void* d_ws, size_t ws_size,
                              hipStream_t stream)
{
  const float* h       = (const float*)d_in[0];
  const float* Wq      = (const float*)d_in[1];
  const float* Wk      = (const float*)d_in[2];
  const float* Wv      = (const float*)d_in[3];
  const float* Wb      = (const float*)d_in[4];
  const float* Wa      = (const float*)d_in[5];
  const float* Wg      = (const float*)d_in[6];
  const float* Wo      = (const float*)d_in[7];
  const float* A_log   = (const float*)d_in[8];
  const float* dt_bias = (const float*)d_in[9];
  const float* conv_w  = (const float*)d_in[10];
  const float* gen_w1  = (const float*)d_in[11];
  const float* gen_w2  = (const float*)d_in[12];
  const float* norm_w  = (const float*)d_in[13];
  float* out = (float*)d_out;

  const size_t TK = (size_t)T_LEN * KD, TV = (size_t)T_LEN * VD, TD = (size_t)T_LEN * DIM;

  float* ws   = (float*)d_ws;
  float* q    = ws;
  float* k    = q    + TK;
  float* x    = k    + TK;          // h@Wv conv input; region later reused (see aliases)
  float* v    = x    + TV;          // conv out; O written in place by scan
  float* tg   = v    + TV;          // T*256
  float* dyn  = tg   + (size_t)T_LEN * 256;
  float* beta = dyn  + (size_t)T_LEN * 4;
  float* g    = beta + (size_t)T_LEN * 6;
  float* c    = g    + (size_t)T_LEN * 6;       // [H][T]
  float* gam  = c    + (size_t)NH * T_LEN;      // [H][NCHK]
  float* fend = gam  + 512;
  unsigned short* bh      = (unsigned short*)fend;          // T*DIM
  unsigned short* wT      = bh      + TD;                   // DIM*VD (used for Wo only)
  unsigned short* gate_bf = wT      + (size_t)DIM * VD;     // T*VD
  unsigned short* go_bf   = gate_bf + TV;                   // T*VD
  // aliases (lifetime-disjoint):
  unsigned short* Kb_s  = bh;                 // Kbar: bh dead after fused GEMM
  unsigned short* Qb_s  = (unsigned short*)x; // x region free after conv
  unsigned short* KhT_s = Qb_s + TK;
  unsigned short* Tm_s  = KhT_s + TK;         // H*NCHK*DK*CK == T*KD
  unsigned short* Pm_s  = Tm_s + (size_t)NH * NCHK * CK * CK;
  float* Lg = (float*)go_bf;                  // consumed before norm_gate writes go_bf
  // stacked B^T for fused GEMM: [9472][2048] bf16 = 38.8 MB; aliases v region
  // (50.3 MB) — used only before conv_kernel writes v.
  unsigned short* wTall = (unsigned short*)v;

  dim3 blk(256);
  cast_bf16<<<(TD / 4) / 256, blk, 0, stream>>>(h, bh);
  // stack all five projection weights (transposed) into wTall
  tcast<<<dim3(KD / 32, DIM / 32), blk, 0, stream>>>(Wq, wTall + (size_t)0 * DIM, DIM, KD);
  tcast<<<dim3(KD / 32, DIM / 32), blk, 0, stream>>>(Wk, wTall + (size_t)1536 * DIM, DIM, KD);
  tcast<<<dim3(VD / 32, DIM / 32), blk, 0, stream>>>(Wv, wTall + (size_t)3072 * DIM, DIM, VD);
  tcast<<<dim3(VD / 32, DIM / 32), blk, 0, stream>>>(Wg, wTall + (size_t)6144 * DIM, DIM, VD);
  tcast<<<dim3(256 / 32, DIM / 32), blk, 0, stream>>>(gen_w1, wTall + (size_t)9216 * DIM, DIM, 256);
  // one fused GEMM for q | k | x | gate | tg
  gemm_fused<<<dim3(NFUSE / 128, T_LEN / 128), blk, 0, stream>>>(
      bh, wTall, q, k, x, gate_bf, tg);

  proj_bg<<<T_LEN, blk, 0, stream>>>(h, Wb, Wa, A_log, dt_bias, beta, g);
  cumsum_g<<<dim3(NCHK, NH), 64, 0, stream>>>(g, c, gam);
  proj_dyn<<<T_LEN, blk, 0, stream>>>(tg, gen_w2, dyn);
  conv_kernel<<<dim3(VD / 256, T_LEN), blk, 0, stream>>>(x, dyn, conv_w, v);
  l2scale<<<T_LEN, 384, 0, stream>>>(q, k, c, Qb_s, Kb_s);

  make_khT<<<dim3(NCHK, NH), blk, 0, stream>>>(k, c, KhT_s);
  chunk_lp<<<dim3(NCHK, NH), blk, 0, stream>>>(q, k, c, beta, Lg, Pm_s);
  tri_inv<<<dim3(NCHK, NH), 64, 0, stream>>>(Lg, beta, Tm_s);

  scan_chunk<<<dim3(DVh / 16, NH), 512, 0, stream>>>(Kb_s, Qb_s, KhT_s, Tm_s, Pm_s, gam, v);

  norm_gate<<<T_LEN * NH, blk, 0, stream>>>(v, gate_bf, norm_w, go_bf);
  tcast<<<dim3(DIM / 32, VD / 32), blk, 0, stream>>>(Wo, wT, VD, DIM);
  gemm_bt_bf16<<<dim3(DIM / 128, T_LEN / 128), blk, 0, stream>>>(go_bf, wT, out, T_LEN, DIM, VD, 0);
}

// Round 6
// 954.454 us; speedup vs baseline: 1.1155x; 1.0287x over previous
//
#include <hip/hip_runtime.h>
#include <hip/hip_bf16.h>
#include <math.h>

#define T_LEN 4096
#define DIM   2048
#define NH    6
#define DK    256
#define DVh   512
#define KD    1536
#define VD    3072
#define CK    64
#define NCHK  (T_LEN / CK)
#define NFUSE 9472   // 1536(q)+1536(k)+3072(x)+3072(gate)+256(tg)

typedef __attribute__((ext_vector_type(8))) short bf16x8;
typedef __attribute__((ext_vector_type(4))) float f32x4;

__device__ __forceinline__ float silu_f(float v){ return v / (1.f + __expf(-v)); }

__device__ __forceinline__ unsigned short f2bf(float f) {
  unsigned int u = __float_as_uint(f);
  unsigned int r = u + 0x7FFFu + ((u >> 16) & 1u);
  return (unsigned short)(r >> 16);
}
__device__ __forceinline__ float bf2f(unsigned short s) {
  return __uint_as_float(((unsigned int)s) << 16);
}

// LDS-only barrier: drains lgkmcnt but leaves global loads/stores in flight.
__device__ __forceinline__ void bar_lds() {
  __builtin_amdgcn_sched_barrier(0);
  asm volatile("s_waitcnt lgkmcnt(0)" ::: "memory");
  __builtin_amdgcn_s_barrier();
  __builtin_amdgcn_sched_barrier(0);
}

// ---------------- cast fp32 -> bf16 ----------------
__global__ __launch_bounds__(256) void cast_bf16(
    const float* __restrict__ in, unsigned short* __restrict__ out)
{
  int i = blockIdx.x * 256 + threadIdx.x;
  float4 v4 = ((const float4*)in)[i];
  ushort4 o4;
  o4.x = f2bf(v4.x); o4.y = f2bf(v4.y); o4.z = f2bf(v4.z); o4.w = f2bf(v4.w);
  ((ushort4*)out)[i] = o4;
}

// ---------------- transpose + cast: in[R][Cn] fp32 -> out[Cn][R] bf16 ----------------
__global__ __launch_bounds__(256) void tcast(
    const float* __restrict__ in, unsigned short* __restrict__ out, int R, int Cn)
{
  __shared__ float tile[32][33];
  int bx = blockIdx.x * 32;
  int by = blockIdx.y * 32;
  int tx = threadIdx.x & 31, ty = threadIdx.x >> 5;
#pragma unroll
  for (int i = 0; i < 32; i += 8)
    tile[ty + i][tx] = in[(size_t)(by + ty + i) * Cn + bx + tx];
  __syncthreads();
#pragma unroll
  for (int i = 0; i < 32; i += 8)
    out[(size_t)(bx + ty + i) * R + by + tx] = f2bf(tile[tx][ty + i]);
}

// ---------------- bf16 MFMA GEMM (m97 structure; generic, used for out-proj) ----------------
__global__ __launch_bounds__(256) void gemm_bt_bf16(
    const unsigned short* __restrict__ A, const unsigned short* __restrict__ BT,
    void* __restrict__ Cout, int M, int N, int K, int act)
{
  __shared__ unsigned short As[128 * 32];
  __shared__ unsigned short Bs[128 * 32];
  const int tid = threadIdx.x;
  const int bm = blockIdx.y * 128, bn = blockIdx.x * 128;
  const int lane = tid & 63, wave = tid >> 6;
  const int wm = (wave >> 1) * 64, wn = (wave & 1) * 64;
  const int fr = lane & 15, kq = lane >> 4;

  f32x4 acc[4][4];
#pragma unroll
  for (int i = 0; i < 4; ++i)
#pragma unroll
    for (int j = 0; j < 4; ++j) acc[i][j] = (f32x4){0.f, 0.f, 0.f, 0.f};

  const int r0 = tid >> 2, c0 = (tid & 3) * 8;
  const int r1 = r0 + 64;

  for (int k0 = 0; k0 < K; k0 += 32) {
    __builtin_amdgcn_global_load_lds(
        (const __attribute__((address_space(1))) unsigned int*)(A + (size_t)(bm + r0) * K + k0 + c0),
        (__attribute__((address_space(3))) unsigned int*)(As + r0 * 32 + c0), 16, 0, 0);
    __builtin_amdgcn_global_load_lds(
        (const __attribute__((address_space(1))) unsigned int*)(A + (size_t)(bm + r1) * K + k0 + c0),
        (__attribute__((address_space(3))) unsigned int*)(As + r1 * 32 + c0), 16, 0, 0);
    __builtin_amdgcn_global_load_lds(
        (const __attribute__((address_space(1))) unsigned int*)(BT + (size_t)(bn + r0) * K + k0 + c0),
        (__attribute__((address_space(3))) unsigned int*)(Bs + r0 * 32 + c0), 16, 0, 0);
    __builtin_amdgcn_global_load_lds(
        (const __attribute__((address_space(1))) unsigned int*)(BT + (size_t)(bn + r1) * K + k0 + c0),
        (__attribute__((address_space(3))) unsigned int*)(Bs + r1 * 32 + c0), 16, 0, 0);
    __syncthreads();

    bf16x8 af[4], bfr[4];
#pragma unroll
    for (int i = 0; i < 4; ++i)
      af[i] = *(const bf16x8*)(As + (wm + i * 16 + fr) * 32 + kq * 8);
#pragma unroll
    for (int j = 0; j < 4; ++j)
      bfr[j] = *(const bf16x8*)(Bs + (wn + j * 16 + fr) * 32 + kq * 8);
#pragma unroll
    for (int i = 0; i < 4; ++i)
#pragma unroll
      for (int j = 0; j < 4; ++j)
        acc[i][j] = __builtin_amdgcn_mfma_f32_16x16x32_bf16(af[i], bfr[j], acc[i][j], 0, 0, 0);
    __syncthreads();
  }

  if (act == 2) {
    unsigned short* C = (unsigned short*)Cout;
#pragma unroll
    for (int i = 0; i < 4; ++i) {
      int rbase = bm + wm + i * 16 + kq * 4;
#pragma unroll
      for (int r = 0; r < 4; ++r) {
        size_t rowoff = (size_t)(rbase + r) * N + bn + wn + fr;
#pragma unroll
        for (int j = 0; j < 4; ++j) C[rowoff + j * 16] = f2bf(acc[i][j][r]);
      }
    }
  } else {
    float* C = (float*)Cout;
#pragma unroll
    for (int i = 0; i < 4; ++i) {
      int rbase = bm + wm + i * 16 + kq * 4;
#pragma unroll
      for (int r = 0; r < 4; ++r) {
        size_t rowoff = (size_t)(rbase + r) * N + bn + wn + fr;
#pragma unroll
        for (int j = 0; j < 4; ++j) {
          float v = acc[i][j][r];
          if (act == 1) v = silu_f(v);
          C[rowoff + j * 16] = v;
        }
      }
    }
  }
}

// ---------------- fused projection GEMM: [T][DIM] x [DIM][9472], 1D grid ----------------
// R6: grouped block ordering (GROUP=8 along M, M-fastest within group) so each
// co-resident wave of ~256 blocks covers an 8Mx32N supertile: working set
// 8 A-panels (4MB) + 32 B-panels (16MB), L2/L3-resident -> kills the 9x B
// over-fetch measured in R5 (FETCH 500MB vs 55.6MB unique inputs).
// Segments: [0,1536) q silu | [1536,3072) k silu | [3072,6144) x linear |
// [6144,9216) gate bf16 | [9216,9472) tg silu.
__global__ __launch_bounds__(256) void gemm_fused(
    const unsigned short* __restrict__ A, const unsigned short* __restrict__ BT,
    float* __restrict__ Cq, float* __restrict__ Ck, float* __restrict__ Cx,
    unsigned short* __restrict__ Cg, float* __restrict__ Ct)
{
  __shared__ unsigned short As[128 * 32];
  __shared__ unsigned short Bs[128 * 32];
  const int tid = threadIdx.x;
  // grouped (triton-style) block mapping
  const int NPN = NFUSE / 128;           // 74
  const int GROUP = 8;                   // along M; 32 % 8 == 0
  const int npig = GROUP * NPN;          // 592
  const int pid = blockIdx.x;
  const int gid = pid / npig;
  const int pm = gid * GROUP + (pid % GROUP);
  const int pn = (pid % npig) / GROUP;
  const int bm = pm * 128, bn = pn * 128;
  const int lane = tid & 63, wave = tid >> 6;
  const int wm = (wave >> 1) * 64, wn = (wave & 1) * 64;
  const int fr = lane & 15, kq = lane >> 4;
  const int K = DIM;

  f32x4 acc[4][4];
#pragma unroll
  for (int i = 0; i < 4; ++i)
#pragma unroll
    for (int j = 0; j < 4; ++j) acc[i][j] = (f32x4){0.f, 0.f, 0.f, 0.f};

  const int r0 = tid >> 2, c0 = (tid & 3) * 8;
  const int r1 = r0 + 64;

  for (int k0 = 0; k0 < K; k0 += 32) {
    __builtin_amdgcn_global_load_lds(
        (const __attribute__((address_space(1))) unsigned int*)(A + (size_t)(bm + r0) * K + k0 + c0),
        (__attribute__((address_space(3))) unsigned int*)(As + r0 * 32 + c0), 16, 0, 0);
    __builtin_amdgcn_global_load_lds(
        (const __attribute__((address_space(1))) unsigned int*)(A + (size_t)(bm + r1) * K + k0 + c0),
        (__attribute__((address_space(3))) unsigned int*)(As + r1 * 32 + c0), 16, 0, 0);
    __builtin_amdgcn_global_load_lds(
        (const __attribute__((address_space(1))) unsigned int*)(BT + (size_t)(bn + r0) * K + k0 + c0),
        (__attribute__((address_space(3))) unsigned int*)(Bs + r0 * 32 + c0), 16, 0, 0);
    __builtin_amdgcn_global_load_lds(
        (const __attribute__((address_space(1))) unsigned int*)(BT + (size_t)(bn + r1) * K + k0 + c0),
        (__attribute__((address_space(3))) unsigned int*)(Bs + r1 * 32 + c0), 16, 0, 0);
    __syncthreads();

    bf16x8 af[4], bfr[4];
#pragma unroll
    for (int i = 0; i < 4; ++i)
      af[i] = *(const bf16x8*)(As + (wm + i * 16 + fr) * 32 + kq * 8);
#pragma unroll
    for (int j = 0; j < 4; ++j)
      bfr[j] = *(const bf16x8*)(Bs + (wn + j * 16 + fr) * 32 + kq * 8);
#pragma unroll
    for (int i = 0; i < 4; ++i)
#pragma unroll
      for (int j = 0; j < 4; ++j)
        acc[i][j] = __builtin_amdgcn_mfma_f32_16x16x32_bf16(af[i], bfr[j], acc[i][j], 0, 0, 0);
    __syncthreads();
  }

  // segment resolve (block-uniform)
  float* Fd = nullptr; unsigned short* Bd = nullptr;
  int strideN, cb, mode;   // mode: 0=fp32, 1=silu fp32, 2=bf16
  if (bn < 1536)      { Fd = Cq; strideN = 1536; cb = bn;        mode = 1; }
  else if (bn < 3072) { Fd = Ck; strideN = 1536; cb = bn - 1536; mode = 1; }
  else if (bn < 6144) { Fd = Cx; strideN = 3072; cb = bn - 3072; mode = 0; }
  else if (bn < 9216) { Bd = Cg; strideN = 3072; cb = bn - 6144; mode = 2; }
  else                { Fd = Ct; strideN = 256;  cb = bn - 9216; mode = 1; }

  if (mode == 2) {
#pragma unroll
    for (int i = 0; i < 4; ++i) {
      int rbase = bm + wm + i * 16 + kq * 4;
#pragma unroll
      for (int r = 0; r < 4; ++r) {
        size_t rowoff = (size_t)(rbase + r) * strideN + cb + wn + fr;
#pragma unroll
        for (int j = 0; j < 4; ++j) Bd[rowoff + j * 16] = f2bf(acc[i][j][r]);
      }
    }
  } else {
#pragma unroll
    for (int i = 0; i < 4; ++i) {
      int rbase = bm + wm + i * 16 + kq * 4;
#pragma unroll
      for (int r = 0; r < 4; ++r) {
        size_t rowoff = (size_t)(rbase + r) * strideN + cb + wn + fr;
#pragma unroll
        for (int j = 0; j < 4; ++j) {
          float v = acc[i][j][r];
          if (mode == 1) v = silu_f(v);
          Fd[rowoff + j * 16] = v;
        }
      }
    }
  }
}

// ---------------- dyn = tg @ gen_w2 ----------------
__global__ __launch_bounds__(256) void proj_dyn(
    const float* __restrict__ tg, const float* __restrict__ w2, float* __restrict__ dyn)
{
  int t = blockIdx.x, tid = threadIdx.x;
  float g = tg[(size_t)t * 256 + tid];
  float p[4];
#pragma unroll
  for (int j = 0; j < 4; ++j) p[j] = g * w2[tid * 4 + j];
#pragma unroll
  for (int j = 0; j < 4; ++j)
    for (int m = 32; m >= 1; m >>= 1) p[j] += __shfl_xor(p[j], m);
  __shared__ float red[4][4];
  if ((tid & 63) == 0) {
    int w = tid >> 6;
#pragma unroll
    for (int j = 0; j < 4; ++j) red[w][j] = p[j];
  }
  __syncthreads();
  if (tid < 4) dyn[(size_t)t * 4 + tid] = red[0][tid] + red[1][tid] + red[2][tid] + red[3][tid];
}

// ---------------- beta / raw decay log-gate g ----------------
__global__ __launch_bounds__(256) void proj_bg(
    const float* __restrict__ h, const float* __restrict__ Wb, const float* __restrict__ Wa,
    const float* __restrict__ A_log, const float* __restrict__ dt_bias,
    float* __restrict__ beta, float* __restrict__ gout)
{
  int t = blockIdx.x, tid = threadIdx.x;
  float pb[6], pa[6];
#pragma unroll
  for (int j = 0; j < 6; ++j) { pb[j] = 0.f; pa[j] = 0.f; }
  for (int d = tid; d < DIM; d += 256) {
    float hv = h[(size_t)t * DIM + d];
#pragma unroll
    for (int j = 0; j < 6; ++j) {
      pb[j] += hv * Wb[d * 6 + j];
      pa[j] += hv * Wa[d * 6 + j];
    }
  }
#pragma unroll
  for (int j = 0; j < 6; ++j)
    for (int m = 32; m >= 1; m >>= 1) { pb[j] += __shfl_xor(pb[j], m); pa[j] += __shfl_xor(pa[j], m); }
  __shared__ float rb[4][6], ra[4][6];
  if ((tid & 63) == 0) {
    int w = tid >> 6;
#pragma unroll
    for (int j = 0; j < 6; ++j) { rb[w][j] = pb[j]; ra[w][j] = pa[j]; }
  }
  __syncthreads();
  if (tid < 6) {
    int j = tid;
    float sb = rb[0][j] + rb[1][j] + rb[2][j] + rb[3][j];
    float sa = ra[0][j] + ra[1][j] + ra[2][j] + ra[3][j];
    beta[(size_t)t * 6 + j] = 1.f / (1.f + expf(-sb));
    float z = sa + dt_bias[j];
    float sp = (z > 20.f) ? z : log1pf(expf(z));
    gout[(size_t)t * 6 + j] = -expf(A_log[j]) * sp;   // raw log-gate (g < 0)
  }
}

// ---------------- causal dynamic conv + silu (8 timesteps/thread, R6) ----------------
// Reuses x loads across taps: 11 loads per 8 outputs vs 32 in the per-t form.
__global__ __launch_bounds__(256) void conv_kernel(
    const float* __restrict__ x, const float* __restrict__ dyn,
    const float* __restrict__ cw, float* __restrict__ v)
{
  int c = blockIdx.x * 256 + threadIdx.x;
  int t0 = blockIdx.y * 8;
  float4 w4 = ((const float4*)cw)[c];
  float xs[11];
#pragma unroll
  for (int i = 0; i < 11; ++i) {
    int t = t0 - 3 + i;
    xs[i] = (t >= 0) ? x[(size_t)t * VD + c] : 0.f;
  }
#pragma unroll
  for (int j = 0; j < 8; ++j) {
    int t = t0 + j;
    float4 dd = ((const float4*)dyn)[t];
    float acc = (w4.x + dd.x) * xs[j]
              + (w4.y + dd.y) * xs[j + 1]
              + (w4.z + dd.z) * xs[j + 2]
              + (w4.w + dd.w) * xs[j + 3];
    v[(size_t)t * VD + c] = silu_f(acc);
  }
}

// ---------------- P1: within-chunk inclusive cumsum of g, gamma = exp(c_end) ----------------
__global__ __launch_bounds__(64) void cumsum_g(
    const float* __restrict__ g, float* __restrict__ c, float* __restrict__ gammas)
{
  int ch = blockIdx.x, h = blockIdx.y;
  int t0 = ch * CK;
  int lane = threadIdx.x;
  float cum = g[(size_t)(t0 + lane) * 6 + h];
  for (int off = 1; off < 64; off <<= 1) {
    float n = __shfl_up(cum, off);
    if (lane >= off) cum += n;
  }
  c[(size_t)h * T_LEN + t0 + lane] = cum;
  if (lane == 63) gammas[h * NCHK + ch] = __expf(cum);
}

// ---------------- fused l2norm + Kbar/Qbar scale ----------------
__global__ __launch_bounds__(384) void l2scale(
    float* __restrict__ q, float* __restrict__ k, const float* __restrict__ c,
    unsigned short* __restrict__ Qb, unsigned short* __restrict__ Kb)
{
  int t = blockIdx.x;
  int h = threadIdx.x >> 6, lane = threadIdx.x & 63;
  size_t off = (size_t)t * KD + h * 256 + lane * 4;
  float4 qv = *(const float4*)(q + off);
  float4 kv = *(const float4*)(k + off);
  float sq = qv.x*qv.x + qv.y*qv.y + qv.z*qv.z + qv.w*qv.w;
  float sk = kv.x*kv.x + kv.y*kv.y + kv.z*kv.z + kv.w*kv.w;
  for (int m = 32; m >= 1; m >>= 1) { sq += __shfl_xor(sq, m); sk += __shfl_xor(sk, m); }
  float rq = rsqrtf(sq + 1e-6f) * 0.0625f;   // fold DK^-0.5
  float rk = rsqrtf(sk + 1e-6f);
  qv.x *= rq; qv.y *= rq; qv.z *= rq; qv.w *= rq;
  kv.x *= rk; kv.y *= rk; kv.z *= rk; kv.w *= rk;
  *(float4*)(q + off) = qv;
  *(float4*)(k + off) = kv;
  float w1 = __expf(c[(size_t)h * T_LEN + t]);
  ushort4 qo, ko;
  qo.x = f2bf(w1 * qv.x); qo.y = f2bf(w1 * qv.y); qo.z = f2bf(w1 * qv.z); qo.w = f2bf(w1 * qv.w);
  ko.x = f2bf(w1 * kv.x); ko.y = f2bf(w1 * kv.y); ko.z = f2bf(w1 * kv.z); ko.w = f2bf(w1 * kv.w);
  *(ushort4*)(Qb + off) = qo;
  *(ushort4*)(Kb + off) = ko;
}

// ---------------- P2b: KhT[h][ch][kk][tt] = exp(c_end - c_t) * k[t][kk]  (bf16) ----------------
__global__ __launch_bounds__(256) void make_khT(
    const float* __restrict__ k, const float* __restrict__ c,
    unsigned short* __restrict__ KhT)
{
  int ch = blockIdx.x, h = blockIdx.y;
  int t0 = ch * CK;
  int tt = threadIdx.x & 63, ks = threadIdx.x >> 6;
  float cend = c[(size_t)h * T_LEN + t0 + 63];
  float w2 = __expf(cend - c[(size_t)h * T_LEN + t0 + tt]);
  size_t obase = ((size_t)(h * NCHK + ch)) * DK * CK;
#pragma unroll 8
  for (int kb2 = 0; kb2 < 64; ++kb2) {
    int kk = ks * 64 + kb2;
    float kv = k[(size_t)(t0 + tt) * KD + h * 256 + kk];
    KhT[obase + (size_t)kk * CK + tt] = f2bf(w2 * kv);
  }
}

// ---------------- P3: per (h,chunk): L, P via MFMA ----------------
__global__ __launch_bounds__(256) void chunk_lp(
    const float* __restrict__ q, const float* __restrict__ k,
    const float* __restrict__ c, const float* __restrict__ beta,
    float* __restrict__ Lg, unsigned short* __restrict__ Pm)
{
  const int ch = blockIdx.x, h = blockIdx.y;
  const int t0 = ch * CK;
  const int tid = threadIdx.x;
  const int w = tid >> 6, lane = tid & 63, fr = lane & 15, kq = lane >> 4;
  __shared__ unsigned short kb[64][264];
  __shared__ unsigned short qb[64][264];
  __shared__ float cs[64], bs[64];
#pragma unroll
  for (int i = 0; i < 16; ++i) {
    int fi = tid + i * 256;
    int r = fi >> 6, d4 = fi & 63;
    float4 kv = *(const float4*)(k + (size_t)(t0 + r) * KD + h * 256 + d4 * 4);
    float4 qv = *(const float4*)(q + (size_t)(t0 + r) * KD + h * 256 + d4 * 4);
    ushort4 k4, q4;
    k4.x = f2bf(kv.x); k4.y = f2bf(kv.y); k4.z = f2bf(kv.z); k4.w = f2bf(kv.w);
    q4.x = f2bf(qv.x); q4.y = f2bf(qv.y); q4.z = f2bf(qv.z); q4.w = f2bf(qv.w);
    *(ushort4*)&kb[r][d4 * 4] = k4;
    *(ushort4*)&qb[r][d4 * 4] = q4;
  }
  if (tid < 64) {
    cs[tid] = c[(size_t)h * T_LEN + t0 + tid];
    bs[tid] = beta[(size_t)(t0 + tid) * 6 + h];
  }
  __syncthreads();

  f32x4 akk[4], aqk[4];
#pragma unroll
  for (int j = 0; j < 4; ++j) { akk[j] = (f32x4){0,0,0,0}; aqk[j] = (f32x4){0,0,0,0}; }
#pragma unroll
  for (int kt = 0; kt < 8; ++kt) {
    bf16x8 ak = *(const bf16x8*)&kb[16 * w + fr][kt * 32 + kq * 8];
    bf16x8 aq = *(const bf16x8*)&qb[16 * w + fr][kt * 32 + kq * 8];
#pragma unroll
    for (int j = 0; j < 4; ++j) {
      bf16x8 b = *(const bf16x8*)&kb[j * 16 + fr][kt * 32 + kq * 8];
      akk[j] = __builtin_amdgcn_mfma_f32_16x16x32_bf16(ak, b, akk[j], 0, 0, 0);
      aqk[j] = __builtin_amdgcn_mfma_f32_16x16x32_bf16(aq, b, aqk[j], 0, 0, 0);
    }
  }
  size_t base = ((size_t)(h * NCHK + ch)) * CK * CK;
#pragma unroll
  for (int j = 0; j < 4; ++j) {
#pragma unroll
    for (int r = 0; r < 4; ++r) {
      int t = 16 * w + kq * 4 + r, col = j * 16 + fr;
      float e = __expf(fminf(cs[t] - cs[col], 0.f));
      Lg[base + t * 64 + col] = (col < t) ? bs[t] * e * akk[j][r] : 0.f;
      Pm[base + t * 64 + col] = f2bf((col <= t) ? e * aqk[j][r] : 0.f);
    }
  }
}

// ---------------- P4: T' = (I+L)^{-1} diag(beta)  (bf16) ----------------
__global__ __launch_bounds__(64) void tri_inv(
    const float* __restrict__ Lg, const float* __restrict__ beta,
    unsigned short* __restrict__ Tm)
{
  const int ch = blockIdx.x, h = blockIdx.y;
  const size_t base = ((size_t)(h * NCHK + ch)) * CK * CK;
  const int j = threadIdx.x;
  __shared__ float Ll[64][65];
  __shared__ float Tl[64][65];
  for (int t = 0; t < 64; ++t) Ll[t][j] = Lg[base + t * 64 + j];
  __syncthreads();
  for (int t = 0; t < 64; ++t) {
    float s;
    if (j > t) s = 0.f;
    else if (j == t) s = 1.f;
    else {
      s = 0.f;
      for (int m = j; m < t; ++m) s -= Ll[t][m] * Tl[m][j];
    }
    Tl[t][j] = s;
  }
  float bj = beta[(size_t)(ch * 64 + j) * 6 + h];
  for (int t = 0; t < 64; ++t) Tm[base + t * 64 + j] = f2bf(Tl[t][j] * bj);
}

// ---------------- chunked gated delta-rule scan (MFMA, 8-wave) — R3 form ----------------
__global__ __launch_bounds__(512, 2) void scan_chunk(
    const unsigned short* __restrict__ Kb,   // [T][KD] Kbar
    const unsigned short* __restrict__ Qb,   // [T][KD] Qbar
    const unsigned short* __restrict__ KhT,  // [H][NCHK][DK][CK]
    const unsigned short* __restrict__ Tm,   // [H][NCHK][CK][CK]
    const unsigned short* __restrict__ Pm,   // [H][NCHK][CK][CK]
    const float* __restrict__ gammas,        // [H][NCHK]
    float* __restrict__ VO)                  // [T][VD]: V in, O out (in place)
{
  const int h = blockIdx.y, sl = blockIdx.x;
  const int tid = threadIdx.x;
  const int w = tid >> 6, lane = tid & 63;
  const int tw = w & 3, kg = w >> 2;
  const int fr = lane & 15, kq = lane >> 4;

  __shared__ unsigned short S0h[16][264];
  __shared__ unsigned short S0l[16][264];
  __shared__ unsigned short XT[16][72];
  __shared__ unsigned short DVT[16][72];
  __shared__ float PY[2][4][16][20];   // partial Y, [kg][tw][fr][kq*4+r]
  __shared__ float PO[2][4][16][20];   // partial O

  f32x4 st[2];
  st[0] = (f32x4){0.f, 0.f, 0.f, 0.f};
  st[1] = (f32x4){0.f, 0.f, 0.f, 0.f};

  const int colg = h * DVh + sl * 16 + fr;
  const size_t hc0 = (size_t)h * NCHK;

  // zero-init S0 staging (cols 0..255 are the ones read)
  {
    int zr = tid >> 5;          // 0..15
    int zc = (tid & 31) * 8;    // 0..248
    ushort4 z; z.x = 0; z.y = 0; z.z = 0; z.w = 0;
    *(ushort4*)&S0h[zr][zc]     = z;
    *(ushort4*)&S0h[zr][zc + 4] = z;
    *(ushort4*)&S0l[zr][zc]     = z;
    *(ushort4*)&S0l[zr][zc + 4] = z;
  }

  bf16x8 kfA[4], kfB[4], qfA[4], qfB[4];
  float vlA[4], vlB[4];

#define PREF(KF, QF, VL, chn) do { \
    const unsigned short* kr_ = Kb + (size_t)((chn) * CK + 16 * tw + fr) * KD + h * 256 + kg * 128 + kq * 8; \
    const unsigned short* qr_ = Qb + (size_t)((chn) * CK + 16 * tw + fr) * KD + h * 256 + kg * 128 + kq * 8; \
    _Pragma("unroll") \
    for (int kt = 0; kt < 4; ++kt) { \
      KF[kt] = *(const bf16x8*)(kr_ + kt * 32); \
      QF[kt] = *(const bf16x8*)(qr_ + kt * 32); } \
    if (kg == 0) { \
      _Pragma("unroll") \
      for (int r = 0; r < 4; ++r) VL[r] = VO[(size_t)((chn) * CK + 16 * tw + kq * 4 + r) * VD + colg]; } \
  } while (0)

#define BODY(chx, KF, QF, VL, KFN, QFN, VLN) do { \
    const int ch_ = (chx); \
    const int t0_ = ch_ * CK; \
    const size_t cb_ = hc0 + ch_; \
    /* tpf: kg0 = T' rows (for DV), kg1 = P rows (for O) */ \
    bf16x8 tpf[2]; \
    { const unsigned short* b_ = (kg == 0 ? Tm : Pm) + (cb_ * CK + 16 * tw + fr) * CK + kq * 8; \
      tpf[0] = *(const bf16x8*)(b_); tpf[1] = *(const bf16x8*)(b_ + 32); } \
    bf16x8 hfr[2][2]; \
    _Pragma("unroll") \
    for (int i = 0; i < 2; ++i) { \
      const unsigned short* hr_ = KhT + (cb_ * DK + 32 * w + 16 * i + fr) * CK + kq * 8; \
      hfr[i][0] = *(const bf16x8*)(hr_); hfr[i][1] = *(const bf16x8*)(hr_ + 32); } \
    const float gam_ = gammas[cb_]; \
    { const int chn_ = (ch_ + 1 < NCHK) ? ch_ + 1 : ch_; PREF(KFN, QFN, VLN, chn_); } \
    /* P1: partial Y/O over this wave's half of DK (4 kt) */ \
    f32x4 yt, ot; \
    { f32x4 yh = (f32x4){0.f,0.f,0.f,0.f}, yl = yh, oh = yh, ol = yh; \
      __builtin_amdgcn_s_setprio(1); \
      _Pragma("unroll") \
      for (int kt = 0; kt < 4; ++kt) { \
        const int ka_ = (kg * 4 + kt) * 32 + kq * 8; \
        bf16x8 bh_ = *(const bf16x8*)&S0h[fr][ka_]; \
        bf16x8 bl_ = *(const bf16x8*)&S0l[fr][ka_]; \
        yh = __builtin_amdgcn_mfma_f32_16x16x32_bf16(KF[kt], bh_, yh, 0, 0, 0); \
        yl = __builtin_amdgcn_mfma_f32_16x16x32_bf16(KF[kt], bl_, yl, 0, 0, 0); \
        oh = __builtin_amdgcn_mfma_f32_16x16x32_bf16(QF[kt], bh_, oh, 0, 0, 0); \
        ol = __builtin_amdgcn_mfma_f32_16x16x32_bf16(QF[kt], bl_, ol, 0, 0, 0); } \
      __builtin_amdgcn_s_setprio(0); \
      yt = yh + yl; ot = oh + ol; } \
    *(f32x4*)&PY[kg][tw][fr][kq * 4] = yt; \
    *(f32x4*)&PO[kg][tw][fr][kq * 4] = ot; \
    bar_lds();   /* B1: partials visible */ \
    if (kg == 0) { \
      f32x4 yo = *(const f32x4*)&PY[1][tw][fr][kq * 4]; \
      ushort4 x4; \
      x4.x = f2bf(VL[0] - (yt[0] + yo[0])); \
      x4.y = f2bf(VL[1] - (yt[1] + yo[1])); \
      x4.z = f2bf(VL[2] - (yt[2] + yo[2])); \
      x4.w = f2bf(VL[3] - (yt[3] + yo[3])); \
      *(ushort4*)&XT[fr][16 * tw + kq * 4] = x4; \
    } else { \
      f32x4 oo = *(const f32x4*)&PO[0][tw][fr][kq * 4]; \
      ot[0] += oo[0]; ot[1] += oo[1]; ot[2] += oo[2]; ot[3] += oo[3]; } \
    bar_lds();   /* B2: XT visible */ \
    /* P2: DV = T' X (kg0 only) */ \
    if (kg == 0) { \
      f32x4 d = (f32x4){0.f,0.f,0.f,0.f}; \
      bf16x8 b0_ = *(const bf16x8*)&XT[fr][kq * 8]; \
      bf16x8 b1_ = *(const bf16x8*)&XT[fr][32 + kq * 8]; \
      d = __builtin_amdgcn_mfma_f32_16x16x32_bf16(tpf[0], b0_, d, 0, 0, 0); \
      d = __builtin_amdgcn_mfma_f32_16x16x32_bf16(tpf[1], b1_, d, 0, 0, 0); \
      ushort4 d4; \
      d4.x = f2bf(d[0]); d4.y = f2bf(d[1]); d4.z = f2bf(d[2]); d4.w = f2bf(d[3]); \
      *(ushort4*)&DVT[fr][16 * tw + kq * 4] = d4; } \
    bar_lds();   /* B3: DVT visible */ \
    /* P3: O-store (kg1), state update + S0 staging (all) */ \
    { bf16x8 dv0_ = *(const bf16x8*)&DVT[fr][kq * 8]; \
      bf16x8 dv1_ = *(const bf16x8*)&DVT[fr][32 + kq * 8]; \
      if (kg == 1) { \
        f32x4 op = (f32x4){0.f,0.f,0.f,0.f}; \
        op = __builtin_amdgcn_mfma_f32_16x16x32_bf16(tpf[0], dv0_, op, 0, 0, 0); \
        op = __builtin_amdgcn_mfma_f32_16x16x32_bf16(tpf[1], dv1_, op, 0, 0, 0); \
        _Pragma("unroll") \
        for (int r = 0; r < 4; ++r) \
          VO[(size_t)(t0_ + 16 * tw + kq * 4 + r) * VD + colg] = ot[r] + op[r]; } \
      __builtin_amdgcn_s_setprio(1); \
      _Pragma("unroll") \
      for (int i = 0; i < 2; ++i) { \
        st[i][0] *= gam_; st[i][1] *= gam_; st[i][2] *= gam_; st[i][3] *= gam_; \
        st[i] = __builtin_amdgcn_mfma_f32_16x16x32_bf16(hfr[i][0], dv0_, st[i], 0, 0, 0); \
        st[i] = __builtin_amdgcn_mfma_f32_16x16x32_bf16(hfr[i][1], dv1_, st[i], 0, 0, 0); \
        ushort4 hi4, lo4; \
        { float s0 = st[i][0], s1 = st[i][1], s2 = st[i][2], s3 = st[i][3]; \
          hi4.x = f2bf(s0); lo4.x = f2bf(s0 - bf2f(hi4.x)); \
          hi4.y = f2bf(s1); lo4.y = f2bf(s1 - bf2f(hi4.y)); \
          hi4.z = f2bf(s2); lo4.z = f2bf(s2 - bf2f(hi4.z)); \
          hi4.w = f2bf(s3); lo4.w = f2bf(s3 - bf2f(hi4.w)); } \
        *(ushort4*)&S0h[fr][32 * w + 16 * i + kq * 4] = hi4; \
        *(ushort4*)&S0l[fr][32 * w + 16 * i + kq * 4] = lo4; } \
      __builtin_amdgcn_s_setprio(0); } \
    bar_lds();   /* B4: S0 visible for next chunk */ \
  } while (0)

  PREF(kfA, qfA, vlA, 0);
  __syncthreads();   // covers the LDS zero-init
  for (int ch = 0; ch < NCHK; ch += 2) {
    BODY(ch,     kfA, qfA, vlA, kfB, qfB, vlB);
    BODY(ch + 1, kfB, qfB, vlB, kfA, qfA, vlA);
  }
#undef BODY
#undef PREF
}

// ---------------- gated RMSNorm ----------------
__global__ __launch_bounds__(256) void norm_gate(
    const float* __restrict__ o, const unsigned short* __restrict__ gate,
    const float* __restrict__ nw, unsigned short* __restrict__ out)
{
  int th = blockIdx.x, tid = threadIdx.x;
  size_t base = (size_t)th * DVh;
  float x0 = o[base + tid], x1 = o[base + 256 + tid];
  float ss = x0 * x0 + x1 * x1;
  for (int m = 32; m >= 1; m >>= 1) ss += __shfl_xor(ss, m);
  __shared__ float red[4];
  if ((tid & 63) == 0) red[tid >> 6] = ss;
  __syncthreads();
  float rms = rsqrtf((red[0] + red[1] + red[2] + red[3]) * (1.f / 512.f) + 1e-5f);
  float g0 = bf2f(gate[base + tid]), g1 = bf2f(gate[base + 256 + tid]);
  out[base + tid]       = f2bf(x0 * rms * nw[tid]       * silu_f(g0));
  out[base + 256 + tid] = f2bf(x1 * rms * nw[tid + 256] * silu_f(g1));
}

extern "C" void kernel_launch(void* const* d_in, const int* in_sizes, int n_in,
                              void* d_out, int out_size, void* d_ws, size_t ws_size,
                              hipStream_t stream)
{
  const float* h       = (const float*)d_in[0];
  const float* Wq      = (const float*)d_in[1];
  const float* Wk      = (const float*)d_in[2];
  const float* Wv      = (const float*)d_in[3];
  const float* Wb      = (const float*)d_in[4];
  const float* Wa      = (const float*)d_in[5];
  const float* Wg      = (const float*)d_in[6];
  const float* Wo      = (const float*)d_in[7];
  const float* A_log   = (const float*)d_in[8];
  const float* dt_bias = (const float*)d_in[9];
  const float* conv_w  = (const float*)d_in[10];
  const float* gen_w1  = (const float*)d_in[11];
  const float* gen_w2  = (const float*)d_in[12];
  const float* norm_w  = (const float*)d_in[13];
  float* out = (float*)d_out;

  const size_t TK = (size_t)T_LEN * KD, TV = (size_t)T_LEN * VD, TD = (size_t)T_LEN * DIM;

  float* ws   = (float*)d_ws;
  float* q    = ws;
  float* k    = q    + TK;
  float* x    = k    + TK;          // h@Wv conv input; region later reused (see aliases)
  float* v    = x    + TV;          // conv out; O written in place by scan
  float* tg   = v    + TV;          // T*256
  float* dyn  = tg   + (size_t)T_LEN * 256;
  float* beta = dyn  + (size_t)T_LEN * 4;
  float* g    = beta + (size_t)T_LEN * 6;
  float* c    = g    + (size_t)T_LEN * 6;       // [H][T]
  float* gam  = c    + (size_t)NH * T_LEN;      // [H][NCHK]
  float* fend = gam  + 512;
  unsigned short* bh      = (unsigned short*)fend;          // T*DIM
  unsigned short* wT      = bh      + TD;                   // DIM*VD (used for Wo only)
  unsigned short* gate_bf = wT      + (size_t)DIM * VD;     // T*VD
  unsigned short* go_bf   = gate_bf + TV;                   // T*VD
  // aliases (lifetime-disjoint):
  unsigned short* Kb_s  = bh;                 // Kbar: bh dead after fused GEMM
  unsigned short* Qb_s  = (unsigned short*)x; // x region free after conv
  unsigned short* KhT_s = Qb_s + TK;
  unsigned short* Tm_s  = KhT_s + TK;         // H*NCHK*DK*CK == T*KD
  unsigned short* Pm_s  = Tm_s + (size_t)NH * NCHK * CK * CK;
  float* Lg = (float*)go_bf;                  // consumed before norm_gate writes go_bf
  // stacked B^T for fused GEMM: [9472][2048] bf16 = 38.8 MB; aliases v region
  // (50.3 MB) — used only before conv_kernel writes v.
  unsigned short* wTall = (unsigned short*)v;

  dim3 blk(256);
  cast_bf16<<<(TD / 4) / 256, blk, 0, stream>>>(h, bh);
  // stack all five projection weights (transposed) into wTall
  tcast<<<dim3(KD / 32, DIM / 32), blk, 0, stream>>>(Wq, wTall + (size_t)0 * DIM, DIM, KD);
  tcast<<<dim3(KD / 32, DIM / 32), blk, 0, stream>>>(Wk, wTall + (size_t)1536 * DIM, DIM, KD);
  tcast<<<dim3(VD / 32, DIM / 32), blk, 0, stream>>>(Wv, wTall + (size_t)3072 * DIM, DIM, VD);
  tcast<<<dim3(VD / 32, DIM / 32), blk, 0, stream>>>(Wg, wTall + (size_t)6144 * DIM, DIM, VD);
  tcast<<<dim3(256 / 32, DIM / 32), blk, 0, stream>>>(gen_w1, wTall + (size_t)9216 * DIM, DIM, 256);
  // one fused GEMM for q | k | x | gate | tg (1D grid, grouped block order)
  gemm_fused<<<dim3((NFUSE / 128) * (T_LEN / 128)), blk, 0, stream>>>(
      bh, wTall, q, k, x, gate_bf, tg);

  proj_bg<<<T_LEN, blk, 0, stream>>>(h, Wb, Wa, A_log, dt_bias, beta, g);
  cumsum_g<<<dim3(NCHK, NH), 64, 0, stream>>>(g, c, gam);
  proj_dyn<<<T_LEN, blk, 0, stream>>>(tg, gen_w2, dyn);
  conv_kernel<<<dim3(VD / 256, T_LEN / 8), blk, 0, stream>>>(x, dyn, conv_w, v);
  l2scale<<<T_LEN, 384, 0, stream>>>(q, k, c, Qb_s, Kb_s);

  make_khT<<<dim3(NCHK, NH), blk, 0, stream>>>(k, c, KhT_s);
  chunk_lp<<<dim3(NCHK, NH), blk, 0, stream>>>(q, k, c, beta, Lg, Pm_s);
  tri_inv<<<dim3(NCHK, NH), 64, 0, stream>>>(Lg, beta, Tm_s);

  scan_chunk<<<dim3(DVh / 16, NH), 512, 0, stream>>>(Kb_s, Qb_s, KhT_s, Tm_s, Pm_s, gam, v);

  norm_gate<<<T_LEN * NH, blk, 0, stream>>>(v, gate_bf, norm_w, go_bf);
  tcast<<<dim3(DIM / 32, VD / 32), blk, 0, stream>>>(Wo, wT, VD, DIM);
  gemm_bt_bf16<<<dim3(DIM / 128, T_LEN / 128), blk, 0, stream>>>(go_bf, wT, out, T_LEN, DIM, VD, 0);
}

// Round 7
// 909.693 us; speedup vs baseline: 1.1704x; 1.0492x over previous
//
#include <hip/hip_runtime.h>
#include <hip/hip_bf16.h>
#include <math.h>

#define T_LEN 4096
#define DIM   2048
#define NH    6
#define DK    256
#define DVh   512
#define KD    1536
#define VD    3072
#define CK    64
#define NCHK  (T_LEN / CK)
#define NFUSE 9472   // 1536(q)+1536(k)+3072(x)+3072(gate)+256(tg)

typedef __attribute__((ext_vector_type(8))) short bf16x8;
typedef __attribute__((ext_vector_type(4))) float f32x4;

#define AS1 __attribute__((address_space(1)))
#define AS3 __attribute__((address_space(3)))

__device__ __forceinline__ float silu_f(float v){ return v / (1.f + __expf(-v)); }

__device__ __forceinline__ unsigned short f2bf(float f) {
  unsigned int u = __float_as_uint(f);
  unsigned int r = u + 0x7FFFu + ((u >> 16) & 1u);
  return (unsigned short)(r >> 16);
}
__device__ __forceinline__ float bf2f(unsigned short s) {
  return __uint_as_float(((unsigned int)s) << 16);
}

// LDS-only barrier: drains lgkmcnt but leaves global loads/stores in flight.
__device__ __forceinline__ void bar_lds() {
  __builtin_amdgcn_sched_barrier(0);
  asm volatile("s_waitcnt lgkmcnt(0)" ::: "memory");
  __builtin_amdgcn_s_barrier();
  __builtin_amdgcn_sched_barrier(0);
}

// ---------------- cast fp32 -> bf16 ----------------
__global__ __launch_bounds__(256) void cast_bf16(
    const float* __restrict__ in, unsigned short* __restrict__ out)
{
  int i = blockIdx.x * 256 + threadIdx.x;
  float4 v4 = ((const float4*)in)[i];
  ushort4 o4;
  o4.x = f2bf(v4.x); o4.y = f2bf(v4.y); o4.z = f2bf(v4.z); o4.w = f2bf(v4.w);
  ((ushort4*)out)[i] = o4;
}

// ---------------- transpose + cast: in[R][Cn] fp32 -> out[Cn][R] bf16 ----------------
__global__ __launch_bounds__(256) void tcast(
    const float* __restrict__ in, unsigned short* __restrict__ out, int R, int Cn)
{
  __shared__ float tile[32][33];
  int bx = blockIdx.x * 32;
  int by = blockIdx.y * 32;
  int tx = threadIdx.x & 31, ty = threadIdx.x >> 5;
#pragma unroll
  for (int i = 0; i < 32; i += 8)
    tile[ty + i][tx] = in[(size_t)(by + ty + i) * Cn + bx + tx];
  __syncthreads();
#pragma unroll
  for (int i = 0; i < 32; i += 8)
    out[(size_t)(bx + ty + i) * R + by + tx] = f2bf(tile[tx][ty + i]);
}

// ======== R7 pipelined GEMM core (BK=64, double-buffered, counted vmcnt) ========
// LDS per buffer: A,B each [2 ks][128 rows][32 cols] bf16 (linear in 16B chunks).
// Per thread per tile: 8 global_load_lds (4 A + 4 B). Boundary wait vmcnt(8):
// the next-staged tile's 8 loads remain in flight across the barrier (T3/T4).
// chunk c = tid + 256*i: ks=c>>9, row=(c>>2)&127, pc=c&3.
#define PSTAGE(Amat, Bmat, bufi, t_, Aptr, Bptr, Kk) do { \
    int k0_ = (t_) << 6; \
    _Pragma("unroll") \
    for (int i_ = 0; i_ < 4; ++i_) { \
      int c_ = threadIdx.x + 256 * i_; \
      int ks_ = c_ >> 9, row_ = (c_ >> 2) & 127, pc_ = c_ & 3; \
      int gc_ = k0_ + ks_ * 32 + pc_ * 8; \
      __builtin_amdgcn_global_load_lds( \
          (const AS1 unsigned int*)(Aptr + (size_t)(bm + row_) * (Kk) + gc_), \
          (AS3 unsigned int*)(&Amat[bufi][0] + c_ * 8), 16, 0, 0); \
      __builtin_amdgcn_global_load_lds( \
          (const AS1 unsigned int*)(Bptr + (size_t)(bn + row_) * (Kk) + gc_), \
          (AS3 unsigned int*)(&Bmat[bufi][0] + c_ * 8), 16, 0, 0); \
    } } while (0)

#define PGEMM_LOOP(Amat, Bmat, Aptr, Bptr, Kk, NTt) do { \
    PSTAGE(Amat, Bmat, 0, 0, Aptr, Bptr, Kk); \
    PSTAGE(Amat, Bmat, 1, 1, Aptr, Bptr, Kk); \
    __builtin_amdgcn_sched_barrier(0); \
    asm volatile("s_waitcnt vmcnt(8)" ::: "memory"); \
    __builtin_amdgcn_s_barrier(); \
    __builtin_amdgcn_sched_barrier(0); \
    for (int t = 0; t < (NTt); ++t) { \
      const unsigned short* as_ = &Amat[t & 1][0]; \
      const unsigned short* bs_ = &Bmat[t & 1][0]; \
      bf16x8 af_[2][4], bf_[2][4]; \
      _Pragma("unroll") \
      for (int ks_ = 0; ks_ < 2; ++ks_) { \
        _Pragma("unroll") \
        for (int i_ = 0; i_ < 4; ++i_) { \
          af_[ks_][i_] = *(const bf16x8*)(as_ + ks_ * 4096 + (wm + i_ * 16 + fr) * 32 + kq * 8); \
          bf_[ks_][i_] = *(const bf16x8*)(bs_ + ks_ * 4096 + (wn + i_ * 16 + fr) * 32 + kq * 8); \
        } } \
      __builtin_amdgcn_s_setprio(1); \
      _Pragma("unroll") \
      for (int i_ = 0; i_ < 4; ++i_) \
        _Pragma("unroll") \
        for (int j_ = 0; j_ < 4; ++j_) \
          acc[i_][j_] = __builtin_amdgcn_mfma_f32_16x16x32_bf16(af_[0][i_], bf_[0][j_], acc[i_][j_], 0, 0, 0); \
      __builtin_amdgcn_s_setprio(0); \
      bar_lds();   /* B1: all waves' ds_reads of this buffer retired */ \
      if (t + 2 < (NTt)) PSTAGE(Amat, Bmat, t & 1, t + 2, Aptr, Bptr, Kk); \
      __builtin_amdgcn_s_setprio(1); \
      _Pragma("unroll") \
      for (int i_ = 0; i_ < 4; ++i_) \
        _Pragma("unroll") \
        for (int j_ = 0; j_ < 4; ++j_) \
          acc[i_][j_] = __builtin_amdgcn_mfma_f32_16x16x32_bf16(af_[1][i_], bf_[1][j_], acc[i_][j_], 0, 0, 0); \
      __builtin_amdgcn_s_setprio(0); \
      __builtin_amdgcn_sched_barrier(0); \
      if (t + 2 < (NTt)) { asm volatile("s_waitcnt vmcnt(8)" ::: "memory"); } \
      else               { asm volatile("s_waitcnt vmcnt(0)" ::: "memory"); } \
      __builtin_amdgcn_s_barrier(); \
      __builtin_amdgcn_sched_barrier(0); \
    } } while (0)

// ---------------- generic pipelined GEMM (used for out-proj) ----------------
__global__ __launch_bounds__(256) void gemm_bt_bf16(
    const unsigned short* __restrict__ A, const unsigned short* __restrict__ BT,
    void* __restrict__ Cout, int M, int N, int K, int act)
{
  __shared__ unsigned short As[2][8192];
  __shared__ unsigned short Bs[2][8192];
  const int tid = threadIdx.x;
  const int bm = blockIdx.y * 128, bn = blockIdx.x * 128;
  const int lane = tid & 63, wave = tid >> 6;
  const int wm = (wave >> 1) * 64, wn = (wave & 1) * 64;
  const int fr = lane & 15, kq = lane >> 4;
  const int NT = K >> 6;

  f32x4 acc[4][4];
#pragma unroll
  for (int i = 0; i < 4; ++i)
#pragma unroll
    for (int j = 0; j < 4; ++j) acc[i][j] = (f32x4){0.f, 0.f, 0.f, 0.f};

  PGEMM_LOOP(As, Bs, A, BT, K, NT);

  if (act == 2) {
    unsigned short* C = (unsigned short*)Cout;
#pragma unroll
    for (int i = 0; i < 4; ++i) {
      int rbase = bm + wm + i * 16 + kq * 4;
#pragma unroll
      for (int r = 0; r < 4; ++r) {
        size_t rowoff = (size_t)(rbase + r) * N + bn + wn + fr;
#pragma unroll
        for (int j = 0; j < 4; ++j) C[rowoff + j * 16] = f2bf(acc[i][j][r]);
      }
    }
  } else {
    float* C = (float*)Cout;
#pragma unroll
    for (int i = 0; i < 4; ++i) {
      int rbase = bm + wm + i * 16 + kq * 4;
#pragma unroll
      for (int r = 0; r < 4; ++r) {
        size_t rowoff = (size_t)(rbase + r) * N + bn + wn + fr;
#pragma unroll
        for (int j = 0; j < 4; ++j) {
          float v = acc[i][j][r];
          if (act == 1) v = silu_f(v);
          C[rowoff + j * 16] = v;
        }
      }
    }
  }
}

// ---------------- fused projection GEMM (pipelined, grouped 1D grid) ----------------
// Segments: [0,1536) q silu | [1536,3072) k silu | [3072,6144) x linear |
// [6144,9216) gate bf16 | [9216,9472) tg silu.
__global__ __launch_bounds__(256) void gemm_fused(
    const unsigned short* __restrict__ A, const unsigned short* __restrict__ BT,
    float* __restrict__ Cq, float* __restrict__ Ck, float* __restrict__ Cx,
    unsigned short* __restrict__ Cg, float* __restrict__ Ct)
{
  __shared__ unsigned short As[2][8192];
  __shared__ unsigned short Bs[2][8192];
  const int tid = threadIdx.x;
  // grouped block mapping (R6)
  const int NPN = NFUSE / 128;           // 74
  const int GROUP = 8;
  const int npig = GROUP * NPN;          // 592
  const int pid = blockIdx.x;
  const int gid = pid / npig;
  const int pm = gid * GROUP + (pid % GROUP);
  const int pn = (pid % npig) / GROUP;
  const int bm = pm * 128, bn = pn * 128;
  const int lane = tid & 63, wave = tid >> 6;
  const int wm = (wave >> 1) * 64, wn = (wave & 1) * 64;
  const int fr = lane & 15, kq = lane >> 4;
  const int NT = DIM >> 6;               // 32

  f32x4 acc[4][4];
#pragma unroll
  for (int i = 0; i < 4; ++i)
#pragma unroll
    for (int j = 0; j < 4; ++j) acc[i][j] = (f32x4){0.f, 0.f, 0.f, 0.f};

  PGEMM_LOOP(As, Bs, A, BT, DIM, NT);

  // segment resolve (block-uniform)
  float* Fd = nullptr; unsigned short* Bd = nullptr;
  int strideN, cb, mode;   // mode: 0=fp32, 1=silu fp32, 2=bf16
  if (bn < 1536)      { Fd = Cq; strideN = 1536; cb = bn;        mode = 1; }
  else if (bn < 3072) { Fd = Ck; strideN = 1536; cb = bn - 1536; mode = 1; }
  else if (bn < 6144) { Fd = Cx; strideN = 3072; cb = bn - 3072; mode = 0; }
  else if (bn < 9216) { Bd = Cg; strideN = 3072; cb = bn - 6144; mode = 2; }
  else                { Fd = Ct; strideN = 256;  cb = bn - 9216; mode = 1; }

  if (mode == 2) {
#pragma unroll
    for (int i = 0; i < 4; ++i) {
      int rbase = bm + wm + i * 16 + kq * 4;
#pragma unroll
      for (int r = 0; r < 4; ++r) {
        size_t rowoff = (size_t)(rbase + r) * strideN + cb + wn + fr;
#pragma unroll
        for (int j = 0; j < 4; ++j) Bd[rowoff + j * 16] = f2bf(acc[i][j][r]);
      }
    }
  } else {
#pragma unroll
    for (int i = 0; i < 4; ++i) {
      int rbase = bm + wm + i * 16 + kq * 4;
#pragma unroll
      for (int r = 0; r < 4; ++r) {
        size_t rowoff = (size_t)(rbase + r) * strideN + cb + wn + fr;
#pragma unroll
        for (int j = 0; j < 4; ++j) {
          float v = acc[i][j][r];
          if (mode == 1) v = silu_f(v);
          Fd[rowoff + j * 16] = v;
        }
      }
    }
  }
}

// ---------------- dyn = tg @ gen_w2 ----------------
__global__ __launch_bounds__(256) void proj_dyn(
    const float* __restrict__ tg, const float* __restrict__ w2, float* __restrict__ dyn)
{
  int t = blockIdx.x, tid = threadIdx.x;
  float g = tg[(size_t)t * 256 + tid];
  float p[4];
#pragma unroll
  for (int j = 0; j < 4; ++j) p[j] = g * w2[tid * 4 + j];
#pragma unroll
  for (int j = 0; j < 4; ++j)
    for (int m = 32; m >= 1; m >>= 1) p[j] += __shfl_xor(p[j], m);
  __shared__ float red[4][4];
  if ((tid & 63) == 0) {
    int w = tid >> 6;
#pragma unroll
    for (int j = 0; j < 4; ++j) red[w][j] = p[j];
  }
  __syncthreads();
  if (tid < 4) dyn[(size_t)t * 4 + tid] = red[0][tid] + red[1][tid] + red[2][tid] + red[3][tid];
}

// ---------------- beta / raw decay log-gate g ----------------
__global__ __launch_bounds__(256) void proj_bg(
    const float* __restrict__ h, const float* __restrict__ Wb, const float* __restrict__ Wa,
    const float* __restrict__ A_log, const float* __restrict__ dt_bias,
    float* __restrict__ beta, float* __restrict__ gout)
{
  int t = blockIdx.x, tid = threadIdx.x;
  float pb[6], pa[6];
#pragma unroll
  for (int j = 0; j < 6; ++j) { pb[j] = 0.f; pa[j] = 0.f; }
  for (int d = tid; d < DIM; d += 256) {
    float hv = h[(size_t)t * DIM + d];
#pragma unroll
    for (int j = 0; j < 6; ++j) {
      pb[j] += hv * Wb[d * 6 + j];
      pa[j] += hv * Wa[d * 6 + j];
    }
  }
#pragma unroll
  for (int j = 0; j < 6; ++j)
    for (int m = 32; m >= 1; m >>= 1) { pb[j] += __shfl_xor(pb[j], m); pa[j] += __shfl_xor(pa[j], m); }
  __shared__ float rb[4][6], ra[4][6];
  if ((tid & 63) == 0) {
    int w = tid >> 6;
#pragma unroll
    for (int j = 0; j < 6; ++j) { rb[w][j] = pb[j]; ra[w][j] = pa[j]; }
  }
  __syncthreads();
  if (tid < 6) {
    int j = tid;
    float sb = rb[0][j] + rb[1][j] + rb[2][j] + rb[3][j];
    float sa = ra[0][j] + ra[1][j] + ra[2][j] + ra[3][j];
    beta[(size_t)t * 6 + j] = 1.f / (1.f + expf(-sb));
    float z = sa + dt_bias[j];
    float sp = (z > 20.f) ? z : log1pf(expf(z));
    gout[(size_t)t * 6 + j] = -expf(A_log[j]) * sp;   // raw log-gate (g < 0)
  }
}

// ---------------- causal dynamic conv + silu (8 timesteps/thread) ----------------
__global__ __launch_bounds__(256) void conv_kernel(
    const float* __restrict__ x, const float* __restrict__ dyn,
    const float* __restrict__ cw, float* __restrict__ v)
{
  int c = blockIdx.x * 256 + threadIdx.x;
  int t0 = blockIdx.y * 8;
  float4 w4 = ((const float4*)cw)[c];
  float xs[11];
#pragma unroll
  for (int i = 0; i < 11; ++i) {
    int t = t0 - 3 + i;
    xs[i] = (t >= 0) ? x[(size_t)t * VD + c] : 0.f;
  }
#pragma unroll
  for (int j = 0; j < 8; ++j) {
    int t = t0 + j;
    float4 dd = ((const float4*)dyn)[t];
    float acc = (w4.x + dd.x) * xs[j]
              + (w4.y + dd.y) * xs[j + 1]
              + (w4.z + dd.z) * xs[j + 2]
              + (w4.w + dd.w) * xs[j + 3];
    v[(size_t)t * VD + c] = silu_f(acc);
  }
}

// ---------------- P1: within-chunk inclusive cumsum of g, gamma = exp(c_end) ----------------
__global__ __launch_bounds__(64) void cumsum_g(
    const float* __restrict__ g, float* __restrict__ c, float* __restrict__ gammas)
{
  int ch = blockIdx.x, h = blockIdx.y;
  int t0 = ch * CK;
  int lane = threadIdx.x;
  float cum = g[(size_t)(t0 + lane) * 6 + h];
  for (int off = 1; off < 64; off <<= 1) {
    float n = __shfl_up(cum, off);
    if (lane >= off) cum += n;
  }
  c[(size_t)h * T_LEN + t0 + lane] = cum;
  if (lane == 63) gammas[h * NCHK + ch] = __expf(cum);
}

// ---------------- fused l2norm + Kbar/Qbar scale ----------------
__global__ __launch_bounds__(384) void l2scale(
    float* __restrict__ q, float* __restrict__ k, const float* __restrict__ c,
    unsigned short* __restrict__ Qb, unsigned short* __restrict__ Kb)
{
  int t = blockIdx.x;
  int h = threadIdx.x >> 6, lane = threadIdx.x & 63;
  size_t off = (size_t)t * KD + h * 256 + lane * 4;
  float4 qv = *(const float4*)(q + off);
  float4 kv = *(const float4*)(k + off);
  float sq = qv.x*qv.x + qv.y*qv.y + qv.z*qv.z + qv.w*qv.w;
  float sk = kv.x*kv.x + kv.y*kv.y + kv.z*kv.z + kv.w*kv.w;
  for (int m = 32; m >= 1; m >>= 1) { sq += __shfl_xor(sq, m); sk += __shfl_xor(sk, m); }
  float rq = rsqrtf(sq + 1e-6f) * 0.0625f;   // fold DK^-0.5
  float rk = rsqrtf(sk + 1e-6f);
  qv.x *= rq; qv.y *= rq; qv.z *= rq; qv.w *= rq;
  kv.x *= rk; kv.y *= rk; kv.z *= rk; kv.w *= rk;
  *(float4*)(q + off) = qv;
  *(float4*)(k + off) = kv;
  float w1 = __expf(c[(size_t)h * T_LEN + t]);
  ushort4 qo, ko;
  qo.x = f2bf(w1 * qv.x); qo.y = f2bf(w1 * qv.y); qo.z = f2bf(w1 * qv.z); qo.w = f2bf(w1 * qv.w);
  ko.x = f2bf(w1 * kv.x); ko.y = f2bf(w1 * kv.y); ko.z = f2bf(w1 * kv.z); ko.w = f2bf(w1 * kv.w);
  *(ushort4*)(Qb + off) = qo;
  *(ushort4*)(Kb + off) = ko;
}

// ---------------- P2b: KhT[h][ch][kk][tt] = exp(c_end - c_t) * k[t][kk]  (bf16) ----------------
__global__ __launch_bounds__(256) void make_khT(
    const float* __restrict__ k, const float* __restrict__ c,
    unsigned short* __restrict__ KhT)
{
  int ch = blockIdx.x, h = blockIdx.y;
  int t0 = ch * CK;
  int tt = threadIdx.x & 63, ks = threadIdx.x >> 6;
  float cend = c[(size_t)h * T_LEN + t0 + 63];
  float w2 = __expf(cend - c[(size_t)h * T_LEN + t0 + tt]);
  size_t obase = ((size_t)(h * NCHK + ch)) * DK * CK;
#pragma unroll 8
  for (int kb2 = 0; kb2 < 64; ++kb2) {
    int kk = ks * 64 + kb2;
    float kv = k[(size_t)(t0 + tt) * KD + h * 256 + kk];
    KhT[obase + (size_t)kk * CK + tt] = f2bf(w2 * kv);
  }
}

// ---------------- P3: per (h,chunk): L, P via MFMA ----------------
__global__ __launch_bounds__(256) void chunk_lp(
    const float* __restrict__ q, const float* __restrict__ k,
    const float* __restrict__ c, const float* __restrict__ beta,
    float* __restrict__ Lg, unsigned short* __restrict__ Pm)
{
  const int ch = blockIdx.x, h = blockIdx.y;
  const int t0 = ch * CK;
  const int tid = threadIdx.x;
  const int w = tid >> 6, lane = tid & 63, fr = lane & 15, kq = lane >> 4;
  __shared__ unsigned short kb[64][264];
  __shared__ unsigned short qb[64][264];
  __shared__ float cs[64], bs[64];
#pragma unroll
  for (int i = 0; i < 16; ++i) {
    int fi = tid + i * 256;
    int r = fi >> 6, d4 = fi & 63;
    float4 kv = *(const float4*)(k + (size_t)(t0 + r) * KD + h * 256 + d4 * 4);
    float4 qv = *(const float4*)(q + (size_t)(t0 + r) * KD + h * 256 + d4 * 4);
    ushort4 k4, q4;
    k4.x = f2bf(kv.x); k4.y = f2bf(kv.y); k4.z = f2bf(kv.z); k4.w = f2bf(kv.w);
    q4.x = f2bf(qv.x); q4.y = f2bf(qv.y); q4.z = f2bf(qv.z); q4.w = f2bf(qv.w);
    *(ushort4*)&kb[r][d4 * 4] = k4;
    *(ushort4*)&qb[r][d4 * 4] = q4;
  }
  if (tid < 64) {
    cs[tid] = c[(size_t)h * T_LEN + t0 + tid];
    bs[tid] = beta[(size_t)(t0 + tid) * 6 + h];
  }
  __syncthreads();

  f32x4 akk[4], aqk[4];
#pragma unroll
  for (int j = 0; j < 4; ++j) { akk[j] = (f32x4){0,0,0,0}; aqk[j] = (f32x4){0,0,0,0}; }
#pragma unroll
  for (int kt = 0; kt < 8; ++kt) {
    bf16x8 ak = *(const bf16x8*)&kb[16 * w + fr][kt * 32 + kq * 8];
    bf16x8 aq = *(const bf16x8*)&qb[16 * w + fr][kt * 32 + kq * 8];
#pragma unroll
    for (int j = 0; j < 4; ++j) {
      bf16x8 b = *(const bf16x8*)&kb[j * 16 + fr][kt * 32 + kq * 8];
      akk[j] = __builtin_amdgcn_mfma_f32_16x16x32_bf16(ak, b, akk[j], 0, 0, 0);
      aqk[j] = __builtin_amdgcn_mfma_f32_16x16x32_bf16(aq, b, aqk[j], 0, 0, 0);
    }
  }
  size_t base = ((size_t)(h * NCHK + ch)) * CK * CK;
#pragma unroll
  for (int j = 0; j < 4; ++j) {
#pragma unroll
    for (int r = 0; r < 4; ++r) {
      int t = 16 * w + kq * 4 + r, col = j * 16 + fr;
      float e = __expf(fminf(cs[t] - cs[col], 0.f));
      Lg[base + t * 64 + col] = (col < t) ? bs[t] * e * akk[j][r] : 0.f;
      Pm[base + t * 64 + col] = f2bf((col <= t) ? e * aqk[j][r] : 0.f);
    }
  }
}

// ---------------- P4: T' = (I+L)^{-1} diag(beta)  (bf16) ----------------
__global__ __launch_bounds__(64) void tri_inv(
    const float* __restrict__ Lg, const float* __restrict__ beta,
    unsigned short* __restrict__ Tm)
{
  const int ch = blockIdx.x, h = blockIdx.y;
  const size_t base = ((size_t)(h * NCHK + ch)) * CK * CK;
  const int j = threadIdx.x;
  __shared__ float Ll[64][65];
  __shared__ float Tl[64][65];
  for (int t = 0; t < 64; ++t) Ll[t][j] = Lg[base + t * 64 + j];
  __syncthreads();
  for (int t = 0; t < 64; ++t) {
    float s;
    if (j > t) s = 0.f;
    else if (j == t) s = 1.f;
    else {
      s = 0.f;
      for (int m = j; m < t; ++m) s -= Ll[t][m] * Tl[m][j];
    }
    Tl[t][j] = s;
  }
  float bj = beta[(size_t)(ch * 64 + j) * 6 + h];
  for (int t = 0; t < 64; ++t) Tm[base + t * 64 + j] = f2bf(Tl[t][j] * bj);
}

// ---------------- chunked gated delta-rule scan (MFMA, 8-wave) — R3 form ----------------
__global__ __launch_bounds__(512, 2) void scan_chunk(
    const unsigned short* __restrict__ Kb,   // [T][KD] Kbar
    const unsigned short* __restrict__ Qb,   // [T][KD] Qbar
    const unsigned short* __restrict__ KhT,  // [H][NCHK][DK][CK]
    const unsigned short* __restrict__ Tm,   // [H][NCHK][CK][CK]
    const unsigned short* __restrict__ Pm,   // [H][NCHK][CK][CK]
    const float* __restrict__ gammas,        // [H][NCHK]
    float* __restrict__ VO)                  // [T][VD]: V in, O out (in place)
{
  const int h = blockIdx.y, sl = blockIdx.x;
  const int tid = threadIdx.x;
  const int w = tid >> 6, lane = tid & 63;
  const int tw = w & 3, kg = w >> 2;
  const int fr = lane & 15, kq = lane >> 4;

  __shared__ unsigned short S0h[16][264];
  __shared__ unsigned short S0l[16][264];
  __shared__ unsigned short XT[16][72];
  __shared__ unsigned short DVT[16][72];
  __shared__ float PY[2][4][16][20];   // partial Y, [kg][tw][fr][kq*4+r]
  __shared__ float PO[2][4][16][20];   // partial O

  f32x4 st[2];
  st[0] = (f32x4){0.f, 0.f, 0.f, 0.f};
  st[1] = (f32x4){0.f, 0.f, 0.f, 0.f};

  const int colg = h * DVh + sl * 16 + fr;
  const size_t hc0 = (size_t)h * NCHK;

  // zero-init S0 staging (cols 0..255 are the ones read)
  {
    int zr = tid >> 5;          // 0..15
    int zc = (tid & 31) * 8;    // 0..248
    ushort4 z; z.x = 0; z.y = 0; z.z = 0; z.w = 0;
    *(ushort4*)&S0h[zr][zc]     = z;
    *(ushort4*)&S0h[zr][zc + 4] = z;
    *(ushort4*)&S0l[zr][zc]     = z;
    *(ushort4*)&S0l[zr][zc + 4] = z;
  }

  bf16x8 kfA[4], kfB[4], qfA[4], qfB[4];
  float vlA[4], vlB[4];

#define PREF(KF, QF, VL, chn) do { \
    const unsigned short* kr_ = Kb + (size_t)((chn) * CK + 16 * tw + fr) * KD + h * 256 + kg * 128 + kq * 8; \
    const unsigned short* qr_ = Qb + (size_t)((chn) * CK + 16 * tw + fr) * KD + h * 256 + kg * 128 + kq * 8; \
    _Pragma("unroll") \
    for (int kt = 0; kt < 4; ++kt) { \
      KF[kt] = *(const bf16x8*)(kr_ + kt * 32); \
      QF[kt] = *(const bf16x8*)(qr_ + kt * 32); } \
    if (kg == 0) { \
      _Pragma("unroll") \
      for (int r = 0; r < 4; ++r) VL[r] = VO[(size_t)((chn) * CK + 16 * tw + kq * 4 + r) * VD + colg]; } \
  } while (0)

#define BODY(chx, KF, QF, VL, KFN, QFN, VLN) do { \
    const int ch_ = (chx); \
    const int t0_ = ch_ * CK; \
    const size_t cb_ = hc0 + ch_; \
    /* tpf: kg0 = T' rows (for DV), kg1 = P rows (for O) */ \
    bf16x8 tpf[2]; \
    { const unsigned short* b_ = (kg == 0 ? Tm : Pm) + (cb_ * CK + 16 * tw + fr) * CK + kq * 8; \
      tpf[0] = *(const bf16x8*)(b_); tpf[1] = *(const bf16x8*)(b_ + 32); } \
    bf16x8 hfr[2][2]; \
    _Pragma("unroll") \
    for (int i = 0; i < 2; ++i) { \
      const unsigned short* hr_ = KhT + (cb_ * DK + 32 * w + 16 * i + fr) * CK + kq * 8; \
      hfr[i][0] = *(const bf16x8*)(hr_); hfr[i][1] = *(const bf16x8*)(hr_ + 32); } \
    const float gam_ = gammas[cb_]; \
    { const int chn_ = (ch_ + 1 < NCHK) ? ch_ + 1 : ch_; PREF(KFN, QFN, VLN, chn_); } \
    /* P1: partial Y/O over this wave's half of DK (4 kt) */ \
    f32x4 yt, ot; \
    { f32x4 yh = (f32x4){0.f,0.f,0.f,0.f}, yl = yh, oh = yh, ol = yh; \
      __builtin_amdgcn_s_setprio(1); \
      _Pragma("unroll") \
      for (int kt = 0; kt < 4; ++kt) { \
        const int ka_ = (kg * 4 + kt) * 32 + kq * 8; \
        bf16x8 bh_ = *(const bf16x8*)&S0h[fr][ka_]; \
        bf16x8 bl_ = *(const bf16x8*)&S0l[fr][ka_]; \
        yh = __builtin_amdgcn_mfma_f32_16x16x32_bf16(KF[kt], bh_, yh, 0, 0, 0); \
        yl = __builtin_amdgcn_mfma_f32_16x16x32_bf16(KF[kt], bl_, yl, 0, 0, 0); \
        oh = __builtin_amdgcn_mfma_f32_16x16x32_bf16(QF[kt], bh_, oh, 0, 0, 0); \
        ol = __builtin_amdgcn_mfma_f32_16x16x32_bf16(QF[kt], bl_, ol, 0, 0, 0); } \
      __builtin_amdgcn_s_setprio(0); \
      yt = yh + yl; ot = oh + ol; } \
    *(f32x4*)&PY[kg][tw][fr][kq * 4] = yt; \
    *(f32x4*)&PO[kg][tw][fr][kq * 4] = ot; \
    bar_lds();   /* B1: partials visible */ \
    if (kg == 0) { \
      f32x4 yo = *(const f32x4*)&PY[1][tw][fr][kq * 4]; \
      ushort4 x4; \
      x4.x = f2bf(VL[0] - (yt[0] + yo[0])); \
      x4.y = f2bf(VL[1] - (yt[1] + yo[1])); \
      x4.z = f2bf(VL[2] - (yt[2] + yo[2])); \
      x4.w = f2bf(VL[3] - (yt[3] + yo[3])); \
      *(ushort4*)&XT[fr][16 * tw + kq * 4] = x4; \
    } else { \
      f32x4 oo = *(const f32x4*)&PO[0][tw][fr][kq * 4]; \
      ot[0] += oo[0]; ot[1] += oo[1]; ot[2] += oo[2]; ot[3] += oo[3]; } \
    bar_lds();   /* B2: XT visible */ \
    /* P2: DV = T' X (kg0 only) */ \
    if (kg == 0) { \
      f32x4 d = (f32x4){0.f,0.f,0.f,0.f}; \
      bf16x8 b0_ = *(const bf16x8*)&XT[fr][kq * 8]; \
      bf16x8 b1_ = *(const bf16x8*)&XT[fr][32 + kq * 8]; \
      d = __builtin_amdgcn_mfma_f32_16x16x32_bf16(tpf[0], b0_, d, 0, 0, 0); \
      d = __builtin_amdgcn_mfma_f32_16x16x32_bf16(tpf[1], b1_, d, 0, 0, 0); \
      ushort4 d4; \
      d4.x = f2bf(d[0]); d4.y = f2bf(d[1]); d4.z = f2bf(d[2]); d4.w = f2bf(d[3]); \
      *(ushort4*)&DVT[fr][16 * tw + kq * 4] = d4; } \
    bar_lds();   /* B3: DVT visible */ \
    /* P3: O-store (kg1), state update + S0 staging (all) */ \
    { bf16x8 dv0_ = *(const bf16x8*)&DVT[fr][kq * 8]; \
      bf16x8 dv1_ = *(const bf16x8*)&DVT[fr][32 + kq * 8]; \
      if (kg == 1) { \
        f32x4 op = (f32x4){0.f,0.f,0.f,0.f}; \
        op = __builtin_amdgcn_mfma_f32_16x16x32_bf16(tpf[0], dv0_, op, 0, 0, 0); \
        op = __builtin_amdgcn_mfma_f32_16x16x32_bf16(tpf[1], dv1_, op, 0, 0, 0); \
        _Pragma("unroll") \
        for (int r = 0; r < 4; ++r) \
          VO[(size_t)(t0_ + 16 * tw + kq * 4 + r) * VD + colg] = ot[r] + op[r]; } \
      __builtin_amdgcn_s_setprio(1); \
      _Pragma("unroll") \
      for (int i = 0; i < 2; ++i) { \
        st[i][0] *= gam_; st[i][1] *= gam_; st[i][2] *= gam_; st[i][3] *= gam_; \
        st[i] = __builtin_amdgcn_mfma_f32_16x16x32_bf16(hfr[i][0], dv0_, st[i], 0, 0, 0); \
        st[i] = __builtin_amdgcn_mfma_f32_16x16x32_bf16(hfr[i][1], dv1_, st[i], 0, 0, 0); \
        ushort4 hi4, lo4; \
        { float s0 = st[i][0], s1 = st[i][1], s2 = st[i][2], s3 = st[i][3]; \
          hi4.x = f2bf(s0); lo4.x = f2bf(s0 - bf2f(hi4.x)); \
          hi4.y = f2bf(s1); lo4.y = f2bf(s1 - bf2f(hi4.y)); \
          hi4.z = f2bf(s2); lo4.z = f2bf(s2 - bf2f(hi4.z)); \
          hi4.w = f2bf(s3); lo4.w = f2bf(s3 - bf2f(hi4.w)); } \
        *(ushort4*)&S0h[fr][32 * w + 16 * i + kq * 4] = hi4; \
        *(ushort4*)&S0l[fr][32 * w + 16 * i + kq * 4] = lo4; } \
      __builtin_amdgcn_s_setprio(0); } \
    bar_lds();   /* B4: S0 visible for next chunk */ \
  } while (0)

  PREF(kfA, qfA, vlA, 0);
  __syncthreads();   // covers the LDS zero-init
  for (int ch = 0; ch < NCHK; ch += 2) {
    BODY(ch,     kfA, qfA, vlA, kfB, qfB, vlB);
    BODY(ch + 1, kfB, qfB, vlB, kfA, qfA, vlA);
  }
#undef BODY
#undef PREF
}

// ---------------- gated RMSNorm ----------------
__global__ __launch_bounds__(256) void norm_gate(
    const float* __restrict__ o, const unsigned short* __restrict__ gate,
    const float* __restrict__ nw, unsigned short* __restrict__ out)
{
  int th = blockIdx.x, tid = threadIdx.x;
  size_t base = (size_t)th * DVh;
  float x0 = o[base + tid], x1 = o[base + 256 + tid];
  float ss = x0 * x0 + x1 * x1;
  for (int m = 32; m >= 1; m >>= 1) ss += __shfl_xor(ss, m);
  __shared__ float red[4];
  if ((tid & 63) == 0) red[tid >> 6] = ss;
  __syncthreads();
  float rms = rsqrtf((red[0] + red[1] + red[2] + red[3]) * (1.f / 512.f) + 1e-5f);
  float g0 = bf2f(gate[base + tid]), g1 = bf2f(gate[base + 256 + tid]);
  out[base + tid]       = f2bf(x0 * rms * nw[tid]       * silu_f(g0));
  out[base + 256 + tid] = f2bf(x1 * rms * nw[tid + 256] * silu_f(g1));
}

extern "C" void kernel_launch(void* const* d_in, const int* in_sizes, int n_in,
                              void* d_out, int out_size, void* d_ws, size_t ws_size,
                              hipStream_t stream)
{
  const float* h       = (const float*)d_in[0];
  const float* Wq      = (const float*)d_in[1];
  const float* Wk      = (const float*)d_in[2];
  const float* Wv      = (const float*)d_in[3];
  const float* Wb      = (const float*)d_in[4];
  const float* Wa      = (const float*)d_in[5];
  const float* Wg      = (const float*)d_in[6];
  const float* Wo      = (const float*)d_in[7];
  const float* A_log   = (const float*)d_in[8];
  const float* dt_bias = (const float*)d_in[9];
  const float* conv_w  = (const float*)d_in[10];
  const float* gen_w1  = (const float*)d_in[11];
  const float* gen_w2  = (const float*)d_in[12];
  const float* norm_w  = (const float*)d_in[13];
  float* out = (float*)d_out;

  const size_t TK = (size_t)T_LEN * KD, TV = (size_t)T_LEN * VD, TD = (size_t)T_LEN * DIM;

  float* ws   = (float*)d_ws;
  float* q    = ws;
  float* k    = q    + TK;
  float* x    = k    + TK;          // h@Wv conv input; region later reused (see aliases)
  float* v    = x    + TV;          // conv out; O written in place by scan
  float* tg   = v    + TV;          // T*256
  float* dyn  = tg   + (size_t)T_LEN * 256;
  float* beta = dyn  + (size_t)T_LEN * 4;
  float* g    = beta + (size_t)T_LEN * 6;
  float* c    = g    + (size_t)T_LEN * 6;       // [H][T]
  float* gam  = c    + (size_t)NH * T_LEN;      // [H][NCHK]
  float* fend = gam  + 512;
  unsigned short* bh      = (unsigned short*)fend;          // T*DIM
  unsigned short* wT      = bh      + TD;                   // DIM*VD (used for Wo only)
  unsigned short* gate_bf = wT      + (size_t)DIM * VD;     // T*VD
  unsigned short* go_bf   = gate_bf + TV;                   // T*VD
  // aliases (lifetime-disjoint):
  unsigned short* Kb_s  = bh;                 // Kbar: bh dead after fused GEMM
  unsigned short* Qb_s  = (unsigned short*)x; // x region free after conv
  unsigned short* KhT_s = Qb_s + TK;
  unsigned short* Tm_s  = KhT_s + TK;         // H*NCHK*DK*CK == T*KD
  unsigned short* Pm_s  = Tm_s + (size_t)NH * NCHK * CK * CK;
  float* Lg = (float*)go_bf;                  // consumed before norm_gate writes go_bf
  // stacked B^T for fused GEMM: [9472][2048] bf16 = 38.8 MB; aliases v region
  // (50.3 MB) — used only before conv_kernel writes v.
  unsigned short* wTall = (unsigned short*)v;

  dim3 blk(256);
  cast_bf16<<<(TD / 4) / 256, blk, 0, stream>>>(h, bh);
  // stack all five projection weights (transposed) into wTall
  tcast<<<dim3(KD / 32, DIM / 32), blk, 0, stream>>>(Wq, wTall + (size_t)0 * DIM, DIM, KD);
  tcast<<<dim3(KD / 32, DIM / 32), blk, 0, stream>>>(Wk, wTall + (size_t)1536 * DIM, DIM, KD);
  tcast<<<dim3(VD / 32, DIM / 32), blk, 0, stream>>>(Wv, wTall + (size_t)3072 * DIM, DIM, VD);
  tcast<<<dim3(VD / 32, DIM / 32), blk, 0, stream>>>(Wg, wTall + (size_t)6144 * DIM, DIM, VD);
  tcast<<<dim3(256 / 32, DIM / 32), blk, 0, stream>>>(gen_w1, wTall + (size_t)9216 * DIM, DIM, 256);
  // one fused GEMM for q | k | x | gate | tg (1D grid, grouped block order)
  gemm_fused<<<dim3((NFUSE / 128) * (T_LEN / 128)), blk, 0, stream>>>(
      bh, wTall, q, k, x, gate_bf, tg);

  proj_bg<<<T_LEN, blk, 0, stream>>>(h, Wb, Wa, A_log, dt_bias, beta, g);
  cumsum_g<<<dim3(NCHK, NH), 64, 0, stream>>>(g, c, gam);
  proj_dyn<<<T_LEN, blk, 0, stream>>>(tg, gen_w2, dyn);
  conv_kernel<<<dim3(VD / 256, T_LEN / 8), blk, 0, stream>>>(x, dyn, conv_w, v);
  l2scale<<<T_LEN, 384, 0, stream>>>(q, k, c, Qb_s, Kb_s);

  make_khT<<<dim3(NCHK, NH), blk, 0, stream>>>(k, c, KhT_s);
  chunk_lp<<<dim3(NCHK, NH), blk, 0, stream>>>(q, k, c, beta, Lg, Pm_s);
  tri_inv<<<dim3(NCHK, NH), 64, 0, stream>>>(Lg, beta, Tm_s);

  scan_chunk<<<dim3(DVh / 16, NH), 512, 0, stream>>>(Kb_s, Qb_s, KhT_s, Tm_s, Pm_s, gam, v);

  norm_gate<<<T_LEN * NH, blk, 0, stream>>>(v, gate_bf, norm_w, go_bf);
  tcast<<<dim3(DIM / 32, VD / 32), blk, 0, stream>>>(Wo, wT, VD, DIM);
  gemm_bt_bf16<<<dim3(DIM / 128, T_LEN / 128), blk, 0, stream>>>(go_bf, wT, out, T_LEN, DIM, VD, 0);
}

// Round 8
// 905.951 us; speedup vs baseline: 1.1752x; 1.0041x over previous
//
#include <hip/hip_runtime.h>
#include <hip/hip_bf16.h>
#include <math.h>

#define T_LEN 4096
#define DIM   2048
#define NH    6
#define DK    256
#define DVh   512
#define KD    1536
#define VD    3072
#define CK    64
#define NCHK  (T_LEN / CK)
#define NFUSE 9472   // 1536(q)+1536(k)+3072(x)+3072(gate)+256(tg)

typedef __attribute__((ext_vector_type(8))) short bf16x8;
typedef __attribute__((ext_vector_type(4))) float f32x4;

#define AS1 __attribute__((address_space(1)))
#define AS3 __attribute__((address_space(3)))

__device__ __forceinline__ float silu_f(float v){ return v / (1.f + __expf(-v)); }

__device__ __forceinline__ unsigned short f2bf(float f) {
  unsigned int u = __float_as_uint(f);
  unsigned int r = u + 0x7FFFu + ((u >> 16) & 1u);
  return (unsigned short)(r >> 16);
}
__device__ __forceinline__ float bf2f(unsigned short s) {
  return __uint_as_float(((unsigned int)s) << 16);
}

// LDS-only barrier: drains lgkmcnt but leaves global loads/stores in flight.
__device__ __forceinline__ void bar_lds() {
  __builtin_amdgcn_sched_barrier(0);
  asm volatile("s_waitcnt lgkmcnt(0)" ::: "memory");
  __builtin_amdgcn_s_barrier();
  __builtin_amdgcn_sched_barrier(0);
}

// ---------------- cast fp32 -> bf16 ----------------
__global__ __launch_bounds__(256) void cast_bf16(
    const float* __restrict__ in, unsigned short* __restrict__ out)
{
  int i = blockIdx.x * 256 + threadIdx.x;
  float4 v4 = ((const float4*)in)[i];
  ushort4 o4;
  o4.x = f2bf(v4.x); o4.y = f2bf(v4.y); o4.z = f2bf(v4.z); o4.w = f2bf(v4.w);
  ((ushort4*)out)[i] = o4;
}

// ---------------- transpose + cast: in[R][Cn] fp32 -> out[Cn][R] bf16 ----------------
__global__ __launch_bounds__(256) void tcast(
    const float* __restrict__ in, unsigned short* __restrict__ out, int R, int Cn)
{
  __shared__ float tile[32][33];
  int bx = blockIdx.x * 32;
  int by = blockIdx.y * 32;
  int tx = threadIdx.x & 31, ty = threadIdx.x >> 5;
#pragma unroll
  for (int i = 0; i < 32; i += 8)
    tile[ty + i][tx] = in[(size_t)(by + ty + i) * Cn + bx + tx];
  __syncthreads();
#pragma unroll
  for (int i = 0; i < 32; i += 8)
    out[(size_t)(bx + ty + i) * R + by + tx] = f2bf(tile[tx][ty + i]);
}

// ======== R7/R8 pipelined GEMM core (BK=64, dbuf, counted vmcnt, T2 swizzle) ========
// LDS per buffer: A,B each [2 ks][128 rows][32 cols] bf16. R8: the row stride is
// 64B -> fragment ds_read_b128 at fixed kq was an 8-way bank conflict (1.94e7
// measured, invariant R5-R7). Fix per rule #21: LDS dest stays linear (m104
// constraint of global_load_lds); the 16B slot permutation slot' = pc ^
// ((row>>1)&3) is realized by pre-swizzling the GLOBAL source column, and the
// reader picks slot kq ^ ((fr>>1)&3). Bank-quad = 4*(row&1)+slot' -> 8 distinct
// per 8 rows -> 2-way residual (free, m136). Same 64B segment per 4-lane group
// -> coalescing/FETCH unchanged.
#define PSTAGE(Amat, Bmat, bufi, t_, Aptr, Bptr, Kk) do { \
    int k0_ = (t_) << 6; \
    _Pragma("unroll") \
    for (int i_ = 0; i_ < 4; ++i_) { \
      int c_ = threadIdx.x + 256 * i_; \
      int ks_ = c_ >> 9, row_ = (c_ >> 2) & 127, pc_ = c_ & 3; \
      int pcs_ = pc_ ^ ((row_ >> 1) & 3); \
      int gc_ = k0_ + ks_ * 32 + pcs_ * 8; \
      __builtin_amdgcn_global_load_lds( \
          (const AS1 unsigned int*)(Aptr + (size_t)(bm + row_) * (Kk) + gc_), \
          (AS3 unsigned int*)(&Amat[bufi][0] + c_ * 8), 16, 0, 0); \
      __builtin_amdgcn_global_load_lds( \
          (const AS1 unsigned int*)(Bptr + (size_t)(bn + row_) * (Kk) + gc_), \
          (AS3 unsigned int*)(&Bmat[bufi][0] + c_ * 8), 16, 0, 0); \
    } } while (0)

#define PGEMM_LOOP(Amat, Bmat, Aptr, Bptr, Kk, NTt) do { \
    PSTAGE(Amat, Bmat, 0, 0, Aptr, Bptr, Kk); \
    PSTAGE(Amat, Bmat, 1, 1, Aptr, Bptr, Kk); \
    __builtin_amdgcn_sched_barrier(0); \
    asm volatile("s_waitcnt vmcnt(8)" ::: "memory"); \
    __builtin_amdgcn_s_barrier(); \
    __builtin_amdgcn_sched_barrier(0); \
    const int slot_ = (kq ^ ((fr >> 1) & 3)) * 8;   /* swizzled 16B slot (ushorts) */ \
    for (int t = 0; t < (NTt); ++t) { \
      const unsigned short* as_ = &Amat[t & 1][0]; \
      const unsigned short* bs_ = &Bmat[t & 1][0]; \
      bf16x8 af_[2][4], bf_[2][4]; \
      _Pragma("unroll") \
      for (int ks_ = 0; ks_ < 2; ++ks_) { \
        _Pragma("unroll") \
        for (int i_ = 0; i_ < 4; ++i_) { \
          af_[ks_][i_] = *(const bf16x8*)(as_ + ks_ * 4096 + (wm + i_ * 16 + fr) * 32 + slot_); \
          bf_[ks_][i_] = *(const bf16x8*)(bs_ + ks_ * 4096 + (wn + i_ * 16 + fr) * 32 + slot_); \
        } } \
      __builtin_amdgcn_s_setprio(1); \
      _Pragma("unroll") \
      for (int i_ = 0; i_ < 4; ++i_) \
        _Pragma("unroll") \
        for (int j_ = 0; j_ < 4; ++j_) \
          acc[i_][j_] = __builtin_amdgcn_mfma_f32_16x16x32_bf16(af_[0][i_], bf_[0][j_], acc[i_][j_], 0, 0, 0); \
      __builtin_amdgcn_s_setprio(0); \
      bar_lds();   /* B1: all waves' ds_reads of this buffer retired */ \
      if (t + 2 < (NTt)) PSTAGE(Amat, Bmat, t & 1, t + 2, Aptr, Bptr, Kk); \
      __builtin_amdgcn_s_setprio(1); \
      _Pragma("unroll") \
      for (int i_ = 0; i_ < 4; ++i_) \
        _Pragma("unroll") \
        for (int j_ = 0; j_ < 4; ++j_) \
          acc[i_][j_] = __builtin_amdgcn_mfma_f32_16x16x32_bf16(af_[1][i_], bf_[1][j_], acc[i_][j_], 0, 0, 0); \
      __builtin_amdgcn_s_setprio(0); \
      __builtin_amdgcn_sched_barrier(0); \
      if (t + 2 < (NTt)) { asm volatile("s_waitcnt vmcnt(8)" ::: "memory"); } \
      else               { asm volatile("s_waitcnt vmcnt(0)" ::: "memory"); } \
      __builtin_amdgcn_s_barrier(); \
      __builtin_amdgcn_sched_barrier(0); \
    } } while (0)

// ---------------- generic pipelined GEMM (used for out-proj) ----------------
__global__ __launch_bounds__(256) void gemm_bt_bf16(
    const unsigned short* __restrict__ A, const unsigned short* __restrict__ BT,
    void* __restrict__ Cout, int M, int N, int K, int act)
{
  __shared__ unsigned short As[2][8192];
  __shared__ unsigned short Bs[2][8192];
  const int tid = threadIdx.x;
  const int bm = blockIdx.y * 128, bn = blockIdx.x * 128;
  const int lane = tid & 63, wave = tid >> 6;
  const int wm = (wave >> 1) * 64, wn = (wave & 1) * 64;
  const int fr = lane & 15, kq = lane >> 4;
  const int NT = K >> 6;

  f32x4 acc[4][4];
#pragma unroll
  for (int i = 0; i < 4; ++i)
#pragma unroll
    for (int j = 0; j < 4; ++j) acc[i][j] = (f32x4){0.f, 0.f, 0.f, 0.f};

  PGEMM_LOOP(As, Bs, A, BT, K, NT);

  if (act == 2) {
    unsigned short* C = (unsigned short*)Cout;
#pragma unroll
    for (int i = 0; i < 4; ++i) {
      int rbase = bm + wm + i * 16 + kq * 4;
#pragma unroll
      for (int r = 0; r < 4; ++r) {
        size_t rowoff = (size_t)(rbase + r) * N + bn + wn + fr;
#pragma unroll
        for (int j = 0; j < 4; ++j) C[rowoff + j * 16] = f2bf(acc[i][j][r]);
      }
    }
  } else {
    float* C = (float*)Cout;
#pragma unroll
    for (int i = 0; i < 4; ++i) {
      int rbase = bm + wm + i * 16 + kq * 4;
#pragma unroll
      for (int r = 0; r < 4; ++r) {
        size_t rowoff = (size_t)(rbase + r) * N + bn + wn + fr;
#pragma unroll
        for (int j = 0; j < 4; ++j) {
          float v = acc[i][j][r];
          if (act == 1) v = silu_f(v);
          C[rowoff + j * 16] = v;
        }
      }
    }
  }
}

// ---------------- fused projection GEMM (pipelined, grouped 1D grid) ----------------
// Segments: [0,1536) q silu | [1536,3072) k silu | [3072,6144) x linear |
// [6144,9216) gate bf16 | [9216,9472) tg silu.
__global__ __launch_bounds__(256) void gemm_fused(
    const unsigned short* __restrict__ A, const unsigned short* __restrict__ BT,
    float* __restrict__ Cq, float* __restrict__ Ck, float* __restrict__ Cx,
    unsigned short* __restrict__ Cg, float* __restrict__ Ct)
{
  __shared__ unsigned short As[2][8192];
  __shared__ unsigned short Bs[2][8192];
  const int tid = threadIdx.x;
  // grouped block mapping (R6)
  const int NPN = NFUSE / 128;           // 74
  const int GROUP = 8;
  const int npig = GROUP * NPN;          // 592
  const int pid = blockIdx.x;
  const int gid = pid / npig;
  const int pm = gid * GROUP + (pid % GROUP);
  const int pn = (pid % npig) / GROUP;
  const int bm = pm * 128, bn = pn * 128;
  const int lane = tid & 63, wave = tid >> 6;
  const int wm = (wave >> 1) * 64, wn = (wave & 1) * 64;
  const int fr = lane & 15, kq = lane >> 4;
  const int NT = DIM >> 6;               // 32

  f32x4 acc[4][4];
#pragma unroll
  for (int i = 0; i < 4; ++i)
#pragma unroll
    for (int j = 0; j < 4; ++j) acc[i][j] = (f32x4){0.f, 0.f, 0.f, 0.f};

  PGEMM_LOOP(As, Bs, A, BT, DIM, NT);

  // segment resolve (block-uniform)
  float* Fd = nullptr; unsigned short* Bd = nullptr;
  int strideN, cb, mode;   // mode: 0=fp32, 1=silu fp32, 2=bf16
  if (bn < 1536)      { Fd = Cq; strideN = 1536; cb = bn;        mode = 1; }
  else if (bn < 3072) { Fd = Ck; strideN = 1536; cb = bn - 1536; mode = 1; }
  else if (bn < 6144) { Fd = Cx; strideN = 3072; cb = bn - 3072; mode = 0; }
  else if (bn < 9216) { Bd = Cg; strideN = 3072; cb = bn - 6144; mode = 2; }
  else                { Fd = Ct; strideN = 256;  cb = bn - 9216; mode = 1; }

  if (mode == 2) {
#pragma unroll
    for (int i = 0; i < 4; ++i) {
      int rbase = bm + wm + i * 16 + kq * 4;
#pragma unroll
      for (int r = 0; r < 4; ++r) {
        size_t rowoff = (size_t)(rbase + r) * strideN + cb + wn + fr;
#pragma unroll
        for (int j = 0; j < 4; ++j) Bd[rowoff + j * 16] = f2bf(acc[i][j][r]);
      }
    }
  } else {
#pragma unroll
    for (int i = 0; i < 4; ++i) {
      int rbase = bm + wm + i * 16 + kq * 4;
#pragma unroll
      for (int r = 0; r < 4; ++r) {
        size_t rowoff = (size_t)(rbase + r) * strideN + cb + wn + fr;
#pragma unroll
        for (int j = 0; j < 4; ++j) {
          float v = acc[i][j][r];
          if (mode == 1) v = silu_f(v);
          Fd[rowoff + j * 16] = v;
        }
      }
    }
  }
}

// ---------------- dyn = tg @ gen_w2 ----------------
__global__ __launch_bounds__(256) void proj_dyn(
    const float* __restrict__ tg, const float* __restrict__ w2, float* __restrict__ dyn)
{
  int t = blockIdx.x, tid = threadIdx.x;
  float g = tg[(size_t)t * 256 + tid];
  float p[4];
#pragma unroll
  for (int j = 0; j < 4; ++j) p[j] = g * w2[tid * 4 + j];
#pragma unroll
  for (int j = 0; j < 4; ++j)
    for (int m = 32; m >= 1; m >>= 1) p[j] += __shfl_xor(p[j], m);
  __shared__ float red[4][4];
  if ((tid & 63) == 0) {
    int w = tid >> 6;
#pragma unroll
    for (int j = 0; j < 4; ++j) red[w][j] = p[j];
  }
  __syncthreads();
  if (tid < 4) dyn[(size_t)t * 4 + tid] = red[0][tid] + red[1][tid] + red[2][tid] + red[3][tid];
}

// ---------------- beta / raw decay log-gate g ----------------
__global__ __launch_bounds__(256) void proj_bg(
    const float* __restrict__ h, const float* __restrict__ Wb, const float* __restrict__ Wa,
    const float* __restrict__ A_log, const float* __restrict__ dt_bias,
    float* __restrict__ beta, float* __restrict__ gout)
{
  int t = blockIdx.x, tid = threadIdx.x;
  float pb[6], pa[6];
#pragma unroll
  for (int j = 0; j < 6; ++j) { pb[j] = 0.f; pa[j] = 0.f; }
  for (int d = tid; d < DIM; d += 256) {
    float hv = h[(size_t)t * DIM + d];
#pragma unroll
    for (int j = 0; j < 6; ++j) {
      pb[j] += hv * Wb[d * 6 + j];
      pa[j] += hv * Wa[d * 6 + j];
    }
  }
#pragma unroll
  for (int j = 0; j < 6; ++j)
    for (int m = 32; m >= 1; m >>= 1) { pb[j] += __shfl_xor(pb[j], m); pa[j] += __shfl_xor(pa[j], m); }
  __shared__ float rb[4][6], ra[4][6];
  if ((tid & 63) == 0) {
    int w = tid >> 6;
#pragma unroll
    for (int j = 0; j < 6; ++j) { rb[w][j] = pb[j]; ra[w][j] = pa[j]; }
  }
  __syncthreads();
  if (tid < 6) {
    int j = tid;
    float sb = rb[0][j] + rb[1][j] + rb[2][j] + rb[3][j];
    float sa = ra[0][j] + ra[1][j] + ra[2][j] + ra[3][j];
    beta[(size_t)t * 6 + j] = 1.f / (1.f + expf(-sb));
    float z = sa + dt_bias[j];
    float sp = (z > 20.f) ? z : log1pf(expf(z));
    gout[(size_t)t * 6 + j] = -expf(A_log[j]) * sp;   // raw log-gate (g < 0)
  }
}

// ---------------- causal dynamic conv + silu (8 timesteps/thread) ----------------
__global__ __launch_bounds__(256) void conv_kernel(
    const float* __restrict__ x, const float* __restrict__ dyn,
    const float* __restrict__ cw, float* __restrict__ v)
{
  int c = blockIdx.x * 256 + threadIdx.x;
  int t0 = blockIdx.y * 8;
  float4 w4 = ((const float4*)cw)[c];
  float xs[11];
#pragma unroll
  for (int i = 0; i < 11; ++i) {
    int t = t0 - 3 + i;
    xs[i] = (t >= 0) ? x[(size_t)t * VD + c] : 0.f;
  }
#pragma unroll
  for (int j = 0; j < 8; ++j) {
    int t = t0 + j;
    float4 dd = ((const float4*)dyn)[t];
    float acc = (w4.x + dd.x) * xs[j]
              + (w4.y + dd.y) * xs[j + 1]
              + (w4.z + dd.z) * xs[j + 2]
              + (w4.w + dd.w) * xs[j + 3];
    v[(size_t)t * VD + c] = silu_f(acc);
  }
}

// ---------------- P1: within-chunk inclusive cumsum of g, gamma = exp(c_end) ----------------
__global__ __launch_bounds__(64) void cumsum_g(
    const float* __restrict__ g, float* __restrict__ c, float* __restrict__ gammas)
{
  int ch = blockIdx.x, h = blockIdx.y;
  int t0 = ch * CK;
  int lane = threadIdx.x;
  float cum = g[(size_t)(t0 + lane) * 6 + h];
  for (int off = 1; off < 64; off <<= 1) {
    float n = __shfl_up(cum, off);
    if (lane >= off) cum += n;
  }
  c[(size_t)h * T_LEN + t0 + lane] = cum;
  if (lane == 63) gammas[h * NCHK + ch] = __expf(cum);
}

// ---------------- fused l2norm + Kbar/Qbar scale ----------------
__global__ __launch_bounds__(384) void l2scale(
    float* __restrict__ q, float* __restrict__ k, const float* __restrict__ c,
    unsigned short* __restrict__ Qb, unsigned short* __restrict__ Kb)
{
  int t = blockIdx.x;
  int h = threadIdx.x >> 6, lane = threadIdx.x & 63;
  size_t off = (size_t)t * KD + h * 256 + lane * 4;
  float4 qv = *(const float4*)(q + off);
  float4 kv = *(const float4*)(k + off);
  float sq = qv.x*qv.x + qv.y*qv.y + qv.z*qv.z + qv.w*qv.w;
  float sk = kv.x*kv.x + kv.y*kv.y + kv.z*kv.z + kv.w*kv.w;
  for (int m = 32; m >= 1; m >>= 1) { sq += __shfl_xor(sq, m); sk += __shfl_xor(sk, m); }
  float rq = rsqrtf(sq + 1e-6f) * 0.0625f;   // fold DK^-0.5
  float rk = rsqrtf(sk + 1e-6f);
  qv.x *= rq; qv.y *= rq; qv.z *= rq; qv.w *= rq;
  kv.x *= rk; kv.y *= rk; kv.z *= rk; kv.w *= rk;
  *(float4*)(q + off) = qv;
  *(float4*)(k + off) = kv;
  float w1 = __expf(c[(size_t)h * T_LEN + t]);
  ushort4 qo, ko;
  qo.x = f2bf(w1 * qv.x); qo.y = f2bf(w1 * qv.y); qo.z = f2bf(w1 * qv.z); qo.w = f2bf(w1 * qv.w);
  ko.x = f2bf(w1 * kv.x); ko.y = f2bf(w1 * kv.y); ko.z = f2bf(w1 * kv.z); ko.w = f2bf(w1 * kv.w);
  *(ushort4*)(Qb + off) = qo;
  *(ushort4*)(Kb + off) = ko;
}

// ---------------- P2b: KhT[h][ch][kk][tt] = exp(c_end - c_t) * k[t][kk]  (bf16) ----------------
__global__ __launch_bounds__(256) void make_khT(
    const float* __restrict__ k, const float* __restrict__ c,
    unsigned short* __restrict__ KhT)
{
  int ch = blockIdx.x, h = blockIdx.y;
  int t0 = ch * CK;
  int tt = threadIdx.x & 63, ks = threadIdx.x >> 6;
  float cend = c[(size_t)h * T_LEN + t0 + 63];
  float w2 = __expf(cend - c[(size_t)h * T_LEN + t0 + tt]);
  size_t obase = ((size_t)(h * NCHK + ch)) * DK * CK;
#pragma unroll 8
  for (int kb2 = 0; kb2 < 64; ++kb2) {
    int kk = ks * 64 + kb2;
    float kv = k[(size_t)(t0 + tt) * KD + h * 256 + kk];
    KhT[obase + (size_t)kk * CK + tt] = f2bf(w2 * kv);
  }
}

// ---------------- P3: per (h,chunk): L, P via MFMA ----------------
__global__ __launch_bounds__(256) void chunk_lp(
    const float* __restrict__ q, const float* __restrict__ k,
    const float* __restrict__ c, const float* __restrict__ beta,
    float* __restrict__ Lg, unsigned short* __restrict__ Pm)
{
  const int ch = blockIdx.x, h = blockIdx.y;
  const int t0 = ch * CK;
  const int tid = threadIdx.x;
  const int w = tid >> 6, lane = tid & 63, fr = lane & 15, kq = lane >> 4;
  __shared__ unsigned short kb[64][264];
  __shared__ unsigned short qb[64][264];
  __shared__ float cs[64], bs[64];
#pragma unroll
  for (int i = 0; i < 16; ++i) {
    int fi = tid + i * 256;
    int r = fi >> 6, d4 = fi & 63;
    float4 kv = *(const float4*)(k + (size_t)(t0 + r) * KD + h * 256 + d4 * 4);
    float4 qv = *(const float4*)(q + (size_t)(t0 + r) * KD + h * 256 + d4 * 4);
    ushort4 k4, q4;
    k4.x = f2bf(kv.x); k4.y = f2bf(kv.y); k4.z = f2bf(kv.z); k4.w = f2bf(kv.w);
    q4.x = f2bf(qv.x); q4.y = f2bf(qv.y); q4.z = f2bf(qv.z); q4.w = f2bf(qv.w);
    *(ushort4*)&kb[r][d4 * 4] = k4;
    *(ushort4*)&qb[r][d4 * 4] = q4;
  }
  if (tid < 64) {
    cs[tid] = c[(size_t)h * T_LEN + t0 + tid];
    bs[tid] = beta[(size_t)(t0 + tid) * 6 + h];
  }
  __syncthreads();

  f32x4 akk[4], aqk[4];
#pragma unroll
  for (int j = 0; j < 4; ++j) { akk[j] = (f32x4){0,0,0,0}; aqk[j] = (f32x4){0,0,0,0}; }
#pragma unroll
  for (int kt = 0; kt < 8; ++kt) {
    bf16x8 ak = *(const bf16x8*)&kb[16 * w + fr][kt * 32 + kq * 8];
    bf16x8 aq = *(const bf16x8*)&qb[16 * w + fr][kt * 32 + kq * 8];
#pragma unroll
    for (int j = 0; j < 4; ++j) {
      bf16x8 b = *(const bf16x8*)&kb[j * 16 + fr][kt * 32 + kq * 8];
      akk[j] = __builtin_amdgcn_mfma_f32_16x16x32_bf16(ak, b, akk[j], 0, 0, 0);
      aqk[j] = __builtin_amdgcn_mfma_f32_16x16x32_bf16(aq, b, aqk[j], 0, 0, 0);
    }
  }
  size_t base = ((size_t)(h * NCHK + ch)) * CK * CK;
#pragma unroll
  for (int j = 0; j < 4; ++j) {
#pragma unroll
    for (int r = 0; r < 4; ++r) {
      int t = 16 * w + kq * 4 + r, col = j * 16 + fr;
      float e = __expf(fminf(cs[t] - cs[col], 0.f));
      Lg[base + t * 64 + col] = (col < t) ? bs[t] * e * akk[j][r] : 0.f;
      Pm[base + t * 64 + col] = f2bf((col <= t) ? e * aqk[j][r] : 0.f);
    }
  }
}

// ---------------- P4: T' = (I+L)^{-1} diag(beta)  (bf16) ----------------
__global__ __launch_bounds__(64) void tri_inv(
    const float* __restrict__ Lg, const float* __restrict__ beta,
    unsigned short* __restrict__ Tm)
{
  const int ch = blockIdx.x, h = blockIdx.y;
  const size_t base = ((size_t)(h * NCHK + ch)) * CK * CK;
  const int j = threadIdx.x;
  __shared__ float Ll[64][65];
  __shared__ float Tl[64][65];
  for (int t = 0; t < 64; ++t) Ll[t][j] = Lg[base + t * 64 + j];
  __syncthreads();
  for (int t = 0; t < 64; ++t) {
    float s;
    if (j > t) s = 0.f;
    else if (j == t) s = 1.f;
    else {
      s = 0.f;
      for (int m = j; m < t; ++m) s -= Ll[t][m] * Tl[m][j];
    }
    Tl[t][j] = s;
  }
  float bj = beta[(size_t)(ch * 64 + j) * 6 + h];
  for (int t = 0; t < 64; ++t) Tm[base + t * 64 + j] = f2bf(Tl[t][j] * bj);
}

// ---------------- chunked gated delta-rule scan (MFMA, 8-wave) — R3 form ----------------
__global__ __launch_bounds__(512, 2) void scan_chunk(
    const unsigned short* __restrict__ Kb,   // [T][KD] Kbar
    const unsigned short* __restrict__ Qb,   // [T][KD] Qbar
    const unsigned short* __restrict__ KhT,  // [H][NCHK][DK][CK]
    const unsigned short* __restrict__ Tm,   // [H][NCHK][CK][CK]
    const unsigned short* __restrict__ Pm,   // [H][NCHK][CK][CK]
    const float* __restrict__ gammas,        // [H][NCHK]
    float* __restrict__ VO)                  // [T][VD]: V in, O out (in place)
{
  const int h = blockIdx.y, sl = blockIdx.x;
  const int tid = threadIdx.x;
  const int w = tid >> 6, lane = tid & 63;
  const int tw = w & 3, kg = w >> 2;
  const int fr = lane & 15, kq = lane >> 4;

  __shared__ unsigned short S0h[16][264];
  __shared__ unsigned short S0l[16][264];
  __shared__ unsigned short XT[16][72];
  __shared__ unsigned short DVT[16][72];
  __shared__ float PY[2][4][16][20];   // partial Y, [kg][tw][fr][kq*4+r]
  __shared__ float PO[2][4][16][20];   // partial O

  f32x4 st[2];
  st[0] = (f32x4){0.f, 0.f, 0.f, 0.f};
  st[1] = (f32x4){0.f, 0.f, 0.f, 0.f};

  const int colg = h * DVh + sl * 16 + fr;
  const size_t hc0 = (size_t)h * NCHK;

  // zero-init S0 staging (cols 0..255 are the ones read)
  {
    int zr = tid >> 5;          // 0..15
    int zc = (tid & 31) * 8;    // 0..248
    ushort4 z; z.x = 0; z.y = 0; z.z = 0; z.w = 0;
    *(ushort4*)&S0h[zr][zc]     = z;
    *(ushort4*)&S0h[zr][zc + 4] = z;
    *(ushort4*)&S0l[zr][zc]     = z;
    *(ushort4*)&S0l[zr][zc + 4] = z;
  }

  bf16x8 kfA[4], kfB[4], qfA[4], qfB[4];
  float vlA[4], vlB[4];

#define PREF(KF, QF, VL, chn) do { \
    const unsigned short* kr_ = Kb + (size_t)((chn) * CK + 16 * tw + fr) * KD + h * 256 + kg * 128 + kq * 8; \
    const unsigned short* qr_ = Qb + (size_t)((chn) * CK + 16 * tw + fr) * KD + h * 256 + kg * 128 + kq * 8; \
    _Pragma("unroll") \
    for (int kt = 0; kt < 4; ++kt) { \
      KF[kt] = *(const bf16x8*)(kr_ + kt * 32); \
      QF[kt] = *(const bf16x8*)(qr_ + kt * 32); } \
    if (kg == 0) { \
      _Pragma("unroll") \
      for (int r = 0; r < 4; ++r) VL[r] = VO[(size_t)((chn) * CK + 16 * tw + kq * 4 + r) * VD + colg]; } \
  } while (0)

#define BODY(chx, KF, QF, VL, KFN, QFN, VLN) do { \
    const int ch_ = (chx); \
    const int t0_ = ch_ * CK; \
    const size_t cb_ = hc0 + ch_; \
    /* tpf: kg0 = T' rows (for DV), kg1 = P rows (for O) */ \
    bf16x8 tpf[2]; \
    { const unsigned short* b_ = (kg == 0 ? Tm : Pm) + (cb_ * CK + 16 * tw + fr) * CK + kq * 8; \
      tpf[0] = *(const bf16x8*)(b_); tpf[1] = *(const bf16x8*)(b_ + 32); } \
    bf16x8 hfr[2][2]; \
    _Pragma("unroll") \
    for (int i = 0; i < 2; ++i) { \
      const unsigned short* hr_ = KhT + (cb_ * DK + 32 * w + 16 * i + fr) * CK + kq * 8; \
      hfr[i][0] = *(const bf16x8*)(hr_); hfr[i][1] = *(const bf16x8*)(hr_ + 32); } \
    const float gam_ = gammas[cb_]; \
    { const int chn_ = (ch_ + 1 < NCHK) ? ch_ + 1 : ch_; PREF(KFN, QFN, VLN, chn_); } \
    /* P1: partial Y/O over this wave's half of DK (4 kt) */ \
    f32x4 yt, ot; \
    { f32x4 yh = (f32x4){0.f,0.f,0.f,0.f}, yl = yh, oh = yh, ol = yh; \
      __builtin_amdgcn_s_setprio(1); \
      _Pragma("unroll") \
      for (int kt = 0; kt < 4; ++kt) { \
        const int ka_ = (kg * 4 + kt) * 32 + kq * 8; \
        bf16x8 bh_ = *(const bf16x8*)&S0h[fr][ka_]; \
        bf16x8 bl_ = *(const bf16x8*)&S0l[fr][ka_]; \
        yh = __builtin_amdgcn_mfma_f32_16x16x32_bf16(KF[kt], bh_, yh, 0, 0, 0); \
        yl = __builtin_amdgcn_mfma_f32_16x16x32_bf16(KF[kt], bl_, yl, 0, 0, 0); \
        oh = __builtin_amdgcn_mfma_f32_16x16x32_bf16(QF[kt], bh_, oh, 0, 0, 0); \
        ol = __builtin_amdgcn_mfma_f32_16x16x32_bf16(QF[kt], bl_, ol, 0, 0, 0); } \
      __builtin_amdgcn_s_setprio(0); \
      yt = yh + yl; ot = oh + ol; } \
    *(f32x4*)&PY[kg][tw][fr][kq * 4] = yt; \
    *(f32x4*)&PO[kg][tw][fr][kq * 4] = ot; \
    bar_lds();   /* B1: partials visible */ \
    if (kg == 0) { \
      f32x4 yo = *(const f32x4*)&PY[1][tw][fr][kq * 4]; \
      ushort4 x4; \
      x4.x = f2bf(VL[0] - (yt[0] + yo[0])); \
      x4.y = f2bf(VL[1] - (yt[1] + yo[1])); \
      x4.z = f2bf(VL[2] - (yt[2] + yo[2])); \
      x4.w = f2bf(VL[3] - (yt[3] + yo[3])); \
      *(ushort4*)&XT[fr][16 * tw + kq * 4] = x4; \
    } else { \
      f32x4 oo = *(const f32x4*)&PO[0][tw][fr][kq * 4]; \
      ot[0] += oo[0]; ot[1] += oo[1]; ot[2] += oo[2]; ot[3] += oo[3]; } \
    bar_lds();   /* B2: XT visible */ \
    /* P2: DV = T' X (kg0 only) */ \
    if (kg == 0) { \
      f32x4 d = (f32x4){0.f,0.f,0.f,0.f}; \
      bf16x8 b0_ = *(const bf16x8*)&XT[fr][kq * 8]; \
      bf16x8 b1_ = *(const bf16x8*)&XT[fr][32 + kq * 8]; \
      d = __builtin_amdgcn_mfma_f32_16x16x32_bf16(tpf[0], b0_, d, 0, 0, 0); \
      d = __builtin_amdgcn_mfma_f32_16x16x32_bf16(tpf[1], b1_, d, 0, 0, 0); \
      ushort4 d4; \
      d4.x = f2bf(d[0]); d4.y = f2bf(d[1]); d4.z = f2bf(d[2]); d4.w = f2bf(d[3]); \
      *(ushort4*)&DVT[fr][16 * tw + kq * 4] = d4; } \
    bar_lds();   /* B3: DVT visible */ \
    /* P3: O-store (kg1), state update + S0 staging (all) */ \
    { bf16x8 dv0_ = *(const bf16x8*)&DVT[fr][kq * 8]; \
      bf16x8 dv1_ = *(const bf16x8*)&DVT[fr][32 + kq * 8]; \
      if (kg == 1) { \
        f32x4 op = (f32x4){0.f,0.f,0.f,0.f}; \
        op = __builtin_amdgcn_mfma_f32_16x16x32_bf16(tpf[0], dv0_, op, 0, 0, 0); \
        op = __builtin_amdgcn_mfma_f32_16x16x32_bf16(tpf[1], dv1_, op, 0, 0, 0); \
        _Pragma("unroll") \
        for (int r = 0; r < 4; ++r) \
          VO[(size_t)(t0_ + 16 * tw + kq * 4 + r) * VD + colg] = ot[r] + op[r]; } \
      __builtin_amdgcn_s_setprio(1); \
      _Pragma("unroll") \
      for (int i = 0; i < 2; ++i) { \
        st[i][0] *= gam_; st[i][1] *= gam_; st[i][2] *= gam_; st[i][3] *= gam_; \
        st[i] = __builtin_amdgcn_mfma_f32_16x16x32_bf16(hfr[i][0], dv0_, st[i], 0, 0, 0); \
        st[i] = __builtin_amdgcn_mfma_f32_16x16x32_bf16(hfr[i][1], dv1_, st[i], 0, 0, 0); \
        ushort4 hi4, lo4; \
        { float s0 = st[i][0], s1 = st[i][1], s2 = st[i][2], s3 = st[i][3]; \
          hi4.x = f2bf(s0); lo4.x = f2bf(s0 - bf2f(hi4.x)); \
          hi4.y = f2bf(s1); lo4.y = f2bf(s1 - bf2f(hi4.y)); \
          hi4.z = f2bf(s2); lo4.z = f2bf(s2 - bf2f(hi4.z)); \
          hi4.w = f2bf(s3); lo4.w = f2bf(s3 - bf2f(hi4.w)); } \
        *(ushort4*)&S0h[fr][32 * w + 16 * i + kq * 4] = hi4; \
        *(ushort4*)&S0l[fr][32 * w + 16 * i + kq * 4] = lo4; } \
      __builtin_amdgcn_s_setprio(0); } \
    bar_lds();   /* B4: S0 visible for next chunk */ \
  } while (0)

  PREF(kfA, qfA, vlA, 0);
  __syncthreads();   // covers the LDS zero-init
  for (int ch = 0; ch < NCHK; ch += 2) {
    BODY(ch,     kfA, qfA, vlA, kfB, qfB, vlB);
    BODY(ch + 1, kfB, qfB, vlB, kfA, qfA, vlA);
  }
#undef BODY
#undef PREF
}

// ---------------- gated RMSNorm ----------------
__global__ __launch_bounds__(256) void norm_gate(
    const float* __restrict__ o, const unsigned short* __restrict__ gate,
    const float* __restrict__ nw, unsigned short* __restrict__ out)
{
  int th = blockIdx.x, tid = threadIdx.x;
  size_t base = (size_t)th * DVh;
  float x0 = o[base + tid], x1 = o[base + 256 + tid];
  float ss = x0 * x0 + x1 * x1;
  for (int m = 32; m >= 1; m >>= 1) ss += __shfl_xor(ss, m);
  __shared__ float red[4];
  if ((tid & 63) == 0) red[tid >> 6] = ss;
  __syncthreads();
  float rms = rsqrtf((red[0] + red[1] + red[2] + red[3]) * (1.f / 512.f) + 1e-5f);
  float g0 = bf2f(gate[base + tid]), g1 = bf2f(gate[base + 256 + tid]);
  out[base + tid]       = f2bf(x0 * rms * nw[tid]       * silu_f(g0));
  out[base + 256 + tid] = f2bf(x1 * rms * nw[tid + 256] * silu_f(g1));
}

extern "C" void kernel_launch(void* const* d_in, const int* in_sizes, int n_in,
                              void* d_out, int out_size, void* d_ws, size_t ws_size,
                              hipStream_t stream)
{
  const float* h       = (const float*)d_in[0];
  const float* Wq      = (const float*)d_in[1];
  const float* Wk      = (const float*)d_in[2];
  const float* Wv      = (const float*)d_in[3];
  const float* Wb      = (const float*)d_in[4];
  const float* Wa      = (const float*)d_in[5];
  const float* Wg      = (const float*)d_in[6];
  const float* Wo      = (const float*)d_in[7];
  const float* A_log   = (const float*)d_in[8];
  const float* dt_bias = (const float*)d_in[9];
  const float* conv_w  = (const float*)d_in[10];
  const float* gen_w1  = (const float*)d_in[11];
  const float* gen_w2  = (const float*)d_in[12];
  const float* norm_w  = (const float*)d_in[13];
  float* out = (float*)d_out;

  const size_t TK = (size_t)T_LEN * KD, TV = (size_t)T_LEN * VD, TD = (size_t)T_LEN * DIM;

  float* ws   = (float*)d_ws;
  float* q    = ws;
  float* k    = q    + TK;
  float* x    = k    + TK;          // h@Wv conv input; region later reused (see aliases)
  float* v    = x    + TV;          // conv out; O written in place by scan
  float* tg   = v    + TV;          // T*256
  float* dyn  = tg   + (size_t)T_LEN * 256;
  float* beta = dyn  + (size_t)T_LEN * 4;
  float* g    = beta + (size_t)T_LEN * 6;
  float* c    = g    + (size_t)T_LEN * 6;       // [H][T]
  float* gam  = c    + (size_t)NH * T_LEN;      // [H][NCHK]
  float* fend = gam  + 512;
  unsigned short* bh      = (unsigned short*)fend;          // T*DIM
  unsigned short* wT      = bh      + TD;                   // DIM*VD (used for Wo only)
  unsigned short* gate_bf = wT      + (size_t)DIM * VD;     // T*VD
  unsigned short* go_bf   = gate_bf + TV;                   // T*VD
  // aliases (lifetime-disjoint):
  unsigned short* Kb_s  = bh;                 // Kbar: bh dead after fused GEMM
  unsigned short* Qb_s  = (unsigned short*)x; // x region free after conv
  unsigned short* KhT_s = Qb_s + TK;
  unsigned short* Tm_s  = KhT_s + TK;         // H*NCHK*DK*CK == T*KD
  unsigned short* Pm_s  = Tm_s + (size_t)NH * NCHK * CK * CK;
  float* Lg = (float*)go_bf;                  // consumed before norm_gate writes go_bf
  // stacked B^T for fused GEMM: [9472][2048] bf16 = 38.8 MB; aliases v region
  // (50.3 MB) — used only before conv_kernel writes v.
  unsigned short* wTall = (unsigned short*)v;

  dim3 blk(256);
  cast_bf16<<<(TD / 4) / 256, blk, 0, stream>>>(h, bh);
  // stack all five projection weights (transposed) into wTall
  tcast<<<dim3(KD / 32, DIM / 32), blk, 0, stream>>>(Wq, wTall + (size_t)0 * DIM, DIM, KD);
  tcast<<<dim3(KD / 32, DIM / 32), blk, 0, stream>>>(Wk, wTall + (size_t)1536 * DIM, DIM, KD);
  tcast<<<dim3(VD / 32, DIM / 32), blk, 0, stream>>>(Wv, wTall + (size_t)3072 * DIM, DIM, VD);
  tcast<<<dim3(VD / 32, DIM / 32), blk, 0, stream>>>(Wg, wTall + (size_t)6144 * DIM, DIM, VD);
  tcast<<<dim3(256 / 32, DIM / 32), blk, 0, stream>>>(gen_w1, wTall + (size_t)9216 * DIM, DIM, 256);
  // one fused GEMM for q | k | x | gate | tg (1D grid, grouped block order)
  gemm_fused<<<dim3((NFUSE / 128) * (T_LEN / 128)), blk, 0, stream>>>(
      bh, wTall, q, k, x, gate_bf, tg);

  proj_bg<<<T_LEN, blk, 0, stream>>>(h, Wb, Wa, A_log, dt_bias, beta, g);
  cumsum_g<<<dim3(NCHK, NH), 64, 0, stream>>>(g, c, gam);
  proj_dyn<<<T_LEN, blk, 0, stream>>>(tg, gen_w2, dyn);
  conv_kernel<<<dim3(VD / 256, T_LEN / 8), blk, 0, stream>>>(x, dyn, conv_w, v);
  l2scale<<<T_LEN, 384, 0, stream>>>(q, k, c, Qb_s, Kb_s);

  make_khT<<<dim3(NCHK, NH), blk, 0, stream>>>(k, c, KhT_s);
  chunk_lp<<<dim3(NCHK, NH), blk, 0, stream>>>(q, k, c, beta, Lg, Pm_s);
  tri_inv<<<dim3(NCHK, NH), 64, 0, stream>>>(Lg, beta, Tm_s);

  scan_chunk<<<dim3(DVh / 16, NH), 512, 0, stream>>>(Kb_s, Qb_s, KhT_s, Tm_s, Pm_s, gam, v);

  norm_gate<<<T_LEN * NH, blk, 0, stream>>>(v, gate_bf, norm_w, go_bf);
  tcast<<<dim3(DIM / 32, VD / 32), blk, 0, stream>>>(Wo, wT, VD, DIM);
  gemm_bt_bf16<<<dim3(DIM / 128, T_LEN / 128), blk, 0, stream>>>(go_bf, wT, out, T_LEN, DIM, VD, 0);
}

// Round 9
// 903.610 us; speedup vs baseline: 1.1783x; 1.0026x over previous
//
#include <hip/hip_runtime.h>
#include <hip/hip_bf16.h>
#include <math.h>

#define T_LEN 4096
#define DIM   2048
#define NH    6
#define DK    256
#define DVh   512
#define KD    1536
#define VD    3072
#define CK    64
#define NCHK  (T_LEN / CK)
#define NFUSE 9472   // 1536(q)+1536(k)+3072(x)+3072(gate)+256(tg) ; 9472 = 37*256

typedef __attribute__((ext_vector_type(8))) short bf16x8;
typedef __attribute__((ext_vector_type(4))) float f32x4;

#define AS1 __attribute__((address_space(1)))
#define AS3 __attribute__((address_space(3)))

__device__ __forceinline__ float silu_f(float v){ return v / (1.f + __expf(-v)); }

__device__ __forceinline__ unsigned short f2bf(float f) {
  unsigned int u = __float_as_uint(f);
  unsigned int r = u + 0x7FFFu + ((u >> 16) & 1u);
  return (unsigned short)(r >> 16);
}
__device__ __forceinline__ float bf2f(unsigned short s) {
  return __uint_as_float(((unsigned int)s) << 16);
}

// LDS-only barrier: drains lgkmcnt but leaves global loads/stores in flight.
__device__ __forceinline__ void bar_lds() {
  __builtin_amdgcn_sched_barrier(0);
  asm volatile("s_waitcnt lgkmcnt(0)" ::: "memory");
  __builtin_amdgcn_s_barrier();
  __builtin_amdgcn_sched_barrier(0);
}

// 8-phase helpers: barrier THEN own-wave lgkm drain (template order), and a
// plain phase-end barrier. sched_barrier(0) fences per rule #18.
__device__ __forceinline__ void phase_pre() {
  __builtin_amdgcn_sched_barrier(0);
  __builtin_amdgcn_s_barrier();
  asm volatile("s_waitcnt lgkmcnt(0)" ::: "memory");
  __builtin_amdgcn_sched_barrier(0);
}
__device__ __forceinline__ void phase_post() {
  __builtin_amdgcn_sched_barrier(0);
  __builtin_amdgcn_s_barrier();
  __builtin_amdgcn_sched_barrier(0);
}

// ---------------- cast fp32 -> bf16 ----------------
__global__ __launch_bounds__(256) void cast_bf16(
    const float* __restrict__ in, unsigned short* __restrict__ out)
{
  int i = blockIdx.x * 256 + threadIdx.x;
  float4 v4 = ((const float4*)in)[i];
  ushort4 o4;
  o4.x = f2bf(v4.x); o4.y = f2bf(v4.y); o4.z = f2bf(v4.z); o4.w = f2bf(v4.w);
  ((ushort4*)out)[i] = o4;
}

// ---------------- transpose + cast: in[R][Cn] fp32 -> out[Cn][R] bf16 ----------------
__global__ __launch_bounds__(256) void tcast(
    const float* __restrict__ in, unsigned short* __restrict__ out, int R, int Cn)
{
  __shared__ float tile[32][33];
  int bx = blockIdx.x * 32;
  int by = blockIdx.y * 32;
  int tx = threadIdx.x & 31, ty = threadIdx.x >> 5;
#pragma unroll
  for (int i = 0; i < 32; i += 8)
    tile[ty + i][tx] = in[(size_t)(by + ty + i) * Cn + bx + tx];
  __syncthreads();
#pragma unroll
  for (int i = 0; i < 32; i += 8)
    out[(size_t)(bx + ty + i) * R + by + tx] = f2bf(tile[tx][ty + i]);
}

// ======== R7/R8 pipelined 128^2 GEMM core (BK=64, dbuf, counted vmcnt, T2 swizzle)
// Kept for the out-projection (N=2048 -> 512 blocks suits 128^2 better than 256^2).
#define PSTAGE(Amat, Bmat, bufi, t_, Aptr, Bptr, Kk) do { \
    int k0_ = (t_) << 6; \
    _Pragma("unroll") \
    for (int i_ = 0; i_ < 4; ++i_) { \
      int c_ = threadIdx.x + 256 * i_; \
      int ks_ = c_ >> 9, row_ = (c_ >> 2) & 127, pc_ = c_ & 3; \
      int pcs_ = pc_ ^ ((row_ >> 1) & 3); \
      int gc_ = k0_ + ks_ * 32 + pcs_ * 8; \
      __builtin_amdgcn_global_load_lds( \
          (const AS1 unsigned int*)(Aptr + (size_t)(bm + row_) * (Kk) + gc_), \
          (AS3 unsigned int*)(&Amat[bufi][0] + c_ * 8), 16, 0, 0); \
      __builtin_amdgcn_global_load_lds( \
          (const AS1 unsigned int*)(Bptr + (size_t)(bn + row_) * (Kk) + gc_), \
          (AS3 unsigned int*)(&Bmat[bufi][0] + c_ * 8), 16, 0, 0); \
    } } while (0)

#define PGEMM_LOOP(Amat, Bmat, Aptr, Bptr, Kk, NTt) do { \
    PSTAGE(Amat, Bmat, 0, 0, Aptr, Bptr, Kk); \
    PSTAGE(Amat, Bmat, 1, 1, Aptr, Bptr, Kk); \
    __builtin_amdgcn_sched_barrier(0); \
    asm volatile("s_waitcnt vmcnt(8)" ::: "memory"); \
    __builtin_amdgcn_s_barrier(); \
    __builtin_amdgcn_sched_barrier(0); \
    const int slot_ = (kq ^ ((fr >> 1) & 3)) * 8; \
    for (int t = 0; t < (NTt); ++t) { \
      const unsigned short* as_ = &Amat[t & 1][0]; \
      const unsigned short* bs_ = &Bmat[t & 1][0]; \
      bf16x8 af_[2][4], bf_[2][4]; \
      _Pragma("unroll") \
      for (int ks_ = 0; ks_ < 2; ++ks_) { \
        _Pragma("unroll") \
        for (int i_ = 0; i_ < 4; ++i_) { \
          af_[ks_][i_] = *(const bf16x8*)(as_ + ks_ * 4096 + (wm + i_ * 16 + fr) * 32 + slot_); \
          bf_[ks_][i_] = *(const bf16x8*)(bs_ + ks_ * 4096 + (wn + i_ * 16 + fr) * 32 + slot_); \
        } } \
      __builtin_amdgcn_s_setprio(1); \
      _Pragma("unroll") \
      for (int i_ = 0; i_ < 4; ++i_) \
        _Pragma("unroll") \
        for (int j_ = 0; j_ < 4; ++j_) \
          acc[i_][j_] = __builtin_amdgcn_mfma_f32_16x16x32_bf16(af_[0][i_], bf_[0][j_], acc[i_][j_], 0, 0, 0); \
      __builtin_amdgcn_s_setprio(0); \
      bar_lds(); \
      if (t + 2 < (NTt)) PSTAGE(Amat, Bmat, t & 1, t + 2, Aptr, Bptr, Kk); \
      __builtin_amdgcn_s_setprio(1); \
      _Pragma("unroll") \
      for (int i_ = 0; i_ < 4; ++i_) \
        _Pragma("unroll") \
        for (int j_ = 0; j_ < 4; ++j_) \
          acc[i_][j_] = __builtin_amdgcn_mfma_f32_16x16x32_bf16(af_[1][i_], bf_[1][j_], acc[i_][j_], 0, 0, 0); \
      __builtin_amdgcn_s_setprio(0); \
      __builtin_amdgcn_sched_barrier(0); \
      if (t + 2 < (NTt)) { asm volatile("s_waitcnt vmcnt(8)" ::: "memory"); } \
      else               { asm volatile("s_waitcnt vmcnt(0)" ::: "memory"); } \
      __builtin_amdgcn_s_barrier(); \
      __builtin_amdgcn_sched_barrier(0); \
    } } while (0)

// ---------------- generic pipelined GEMM (used for out-proj) ----------------
__global__ __launch_bounds__(256) void gemm_bt_bf16(
    const unsigned short* __restrict__ A, const unsigned short* __restrict__ BT,
    void* __restrict__ Cout, int M, int N, int K, int act)
{
  __shared__ unsigned short As[2][8192];
  __shared__ unsigned short Bs[2][8192];
  const int tid = threadIdx.x;
  const int bm = blockIdx.y * 128, bn = blockIdx.x * 128;
  const int lane = tid & 63, wave = tid >> 6;
  const int wm = (wave >> 1) * 64, wn = (wave & 1) * 64;
  const int fr = lane & 15, kq = lane >> 4;
  const int NT = K >> 6;

  f32x4 acc[4][4];
#pragma unroll
  for (int i = 0; i < 4; ++i)
#pragma unroll
    for (int j = 0; j < 4; ++j) acc[i][j] = (f32x4){0.f, 0.f, 0.f, 0.f};

  PGEMM_LOOP(As, Bs, A, BT, K, NT);

  if (act == 2) {
    unsigned short* C = (unsigned short*)Cout;
#pragma unroll
    for (int i = 0; i < 4; ++i) {
      int rbase = bm + wm + i * 16 + kq * 4;
#pragma unroll
      for (int r = 0; r < 4; ++r) {
        size_t rowoff = (size_t)(rbase + r) * N + bn + wn + fr;
#pragma unroll
        for (int j = 0; j < 4; ++j) C[rowoff + j * 16] = f2bf(acc[i][j][r]);
      }
    }
  } else {
    float* C = (float*)Cout;
#pragma unroll
    for (int i = 0; i < 4; ++i) {
      int rbase = bm + wm + i * 16 + kq * 4;
#pragma unroll
      for (int r = 0; r < 4; ++r) {
        size_t rowoff = (size_t)(rbase + r) * N + bn + wn + fr;
#pragma unroll
        for (int j = 0; j < 4; ++j) {
          float v = acc[i][j][r];
          if (act == 1) v = silu_f(v);
          C[rowoff + j * 16] = v;
        }
      }
    }
  }
}

// ======== R9: fused projection GEMM — 256^2 8-phase template (m201 port) ========
// BM=BN=256, BK=64 (2 kslabs of 32), 512 thr = 8 waves (2M x 4N), per-wave
// output 128x64 (acc[8][4]), 64 MFMA/K-tile/wave. LDS 128KB: [dbuf][kslab]
// [256 rows x 32 cols] for A and B. Per K-tile: 4 phases of
// {ds_read subtile + stage 1 half + barrier + lgkm(0) + 16 MFMA + barrier};
// boundary = counted vmcnt(4) (vmcnt(0) only for the last two tiles).
// Staging schedule (derived; each half staged right after the half it
// overwrites dies): ph1: A-ks1(t+1), ph2: B-ks1(t+1), ph3: A-ks0(t+2),
// ph4: B-ks0(t+2). Per-wave vmcnt + barrier => collective retirement.
// Swizzle: 64B LDS rows, same R8 involution (source-preswizzle + read XOR),
// measured zero conflicts.
#define STG2(MatLds, Gptr, rowbase, buf_, ks_, tt_) do { \
    _Pragma("unroll") \
    for (int i_ = 0; i_ < 2; ++i_) { \
      int c_ = tid + 512 * i_; \
      int row_ = c_ >> 2, pc_ = c_ & 3; \
      int gc_ = (tt_) * 64 + (ks_) * 32 + (pc_ ^ ((row_ >> 1) & 3)) * 8; \
      __builtin_amdgcn_global_load_lds( \
          (const AS1 unsigned int*)((Gptr) + (size_t)((rowbase) + row_) * DIM + gc_), \
          (AS3 unsigned int*)(&MatLds[buf_][ks_][0] + c_ * 8), 16, 0, 0); \
    } } while (0)

#define LOAD_AF2(buf_, ks_, mib_) \
    _Pragma("unroll") \
    for (int m_ = 0; m_ < 4; ++m_) \
      af[m_] = *(const bf16x8*)(&As[buf_][ks_][0] + (wr * 128 + ((mib_) + m_) * 16 + fr) * 32 + slot);

#define LOAD_BF2(buf_, ks_) \
    _Pragma("unroll") \
    for (int n_ = 0; n_ < 4; ++n_) \
      bfv[n_] = *(const bf16x8*)(&Bs[buf_][ks_][0] + (wc * 64 + n_ * 16 + fr) * 32 + slot);

#define MFMA16(mib_) do { \
    __builtin_amdgcn_s_setprio(1); \
    _Pragma("unroll") \
    for (int m_ = 0; m_ < 4; ++m_) \
      _Pragma("unroll") \
      for (int n_ = 0; n_ < 4; ++n_) \
        acc[(mib_) + m_][n_] = __builtin_amdgcn_mfma_f32_16x16x32_bf16(af[m_], bfv[n_], acc[(mib_) + m_][n_], 0, 0, 0); \
    __builtin_amdgcn_s_setprio(0); \
    } while (0)

__global__ __launch_bounds__(512, 2) void gemm_fused(
    const unsigned short* __restrict__ A, const unsigned short* __restrict__ BT,
    float* __restrict__ Cq, float* __restrict__ Ck, float* __restrict__ Cx,
    unsigned short* __restrict__ Cg, float* __restrict__ Ct)
{
  __shared__ unsigned short As[2][2][8192];   // [buf][kslab][256*32]
  __shared__ unsigned short Bs[2][2][8192];
  const int tid = threadIdx.x;
  const int pid = blockIdx.x;
  const int pm = pid & 15, pn = pid >> 4;     // M-fastest: 16M x 37N
  const int bm = pm * 256, bn = pn * 256;
  const int lane = tid & 63, w = tid >> 6;
  const int wr = w >> 2, wc = w & 3;
  const int fr = lane & 15, kq = lane >> 4;
  const int NT = DIM / 64;                    // 32
  const int slot = (kq ^ ((fr >> 1) & 3)) * 8;

  // prologue: tile0 (4 halves) + tile1 kslab0 (2 halves) = 12 loads
  STG2(As, A,  bm, 0, 0, 0);  STG2(Bs, BT, bn, 0, 0, 0);
  STG2(As, A,  bm, 0, 1, 0);  STG2(Bs, BT, bn, 0, 1, 0);
  STG2(As, A,  bm, 1, 0, 1);  STG2(Bs, BT, bn, 1, 0, 1);

  f32x4 acc[8][4];
#pragma unroll
  for (int i = 0; i < 8; ++i)
#pragma unroll
    for (int j = 0; j < 4; ++j) acc[i][j] = (f32x4){0.f, 0.f, 0.f, 0.f};

  __builtin_amdgcn_sched_barrier(0);
  asm volatile("s_waitcnt vmcnt(4)" ::: "memory");   // retire tile0's 4 halves
  __builtin_amdgcn_s_barrier();
  __builtin_amdgcn_sched_barrier(0);

  for (int t = 0; t < NT; ++t) {
    const int cur = t & 1, nb = (t + 1) & 1;
    bf16x8 af[4], bfv[4];
    // ph1: kslab0, mi 0-3 (A+B reads); stage A-ks1(t+1)
    LOAD_AF2(cur, 0, 0); LOAD_BF2(cur, 0);
    if (t + 1 < NT) STG2(As, A, bm, nb, 1, t + 1);
    phase_pre(); MFMA16(0); phase_post();
    // ph2: kslab0, mi 4-7 (A reads only, B reused); stage B-ks1(t+1)
    LOAD_AF2(cur, 0, 4);
    if (t + 1 < NT) STG2(Bs, BT, bn, nb, 1, t + 1);
    phase_pre(); MFMA16(4); phase_post();
    // ph3: kslab1, mi 0-3; stage A-ks0(t+2)
    LOAD_AF2(cur, 1, 0); LOAD_BF2(cur, 1);
    if (t + 2 < NT) STG2(As, A, bm, cur, 0, t + 2);
    phase_pre(); MFMA16(0); phase_post();
    // ph4: kslab1, mi 4-7; stage B-ks0(t+2); boundary counted vmcnt
    LOAD_AF2(cur, 1, 4);
    if (t + 2 < NT) STG2(Bs, BT, bn, cur, 0, t + 2);
    phase_pre(); MFMA16(4);
    __builtin_amdgcn_sched_barrier(0);
    if (t + 2 < NT) { asm volatile("s_waitcnt vmcnt(4)" ::: "memory"); }
    else            { asm volatile("s_waitcnt vmcnt(0)" ::: "memory"); }
    __builtin_amdgcn_s_barrier();
    __builtin_amdgcn_sched_barrier(0);
  }

  // segment resolve (block-uniform; all boundaries are multiples of 256)
  float* Fd = nullptr; unsigned short* Bd = nullptr;
  int strideN, cb, mode;   // mode: 0=fp32, 1=silu fp32, 2=bf16
  if (bn < 1536)      { Fd = Cq; strideN = 1536; cb = bn;        mode = 1; }
  else if (bn < 3072) { Fd = Ck; strideN = 1536; cb = bn - 1536; mode = 1; }
  else if (bn < 6144) { Fd = Cx; strideN = 3072; cb = bn - 3072; mode = 0; }
  else if (bn < 9216) { Bd = Cg; strideN = 3072; cb = bn - 6144; mode = 2; }
  else                { Fd = Ct; strideN = 256;  cb = bn - 9216; mode = 1; }

  if (mode == 2) {
#pragma unroll
    for (int mi = 0; mi < 8; ++mi) {
      int rbase = bm + wr * 128 + mi * 16 + kq * 4;
#pragma unroll
      for (int r = 0; r < 4; ++r) {
        size_t rowoff = (size_t)(rbase + r) * strideN + cb + wc * 64 + fr;
#pragma unroll
        for (int nj = 0; nj < 4; ++nj) Bd[rowoff + nj * 16] = f2bf(acc[mi][nj][r]);
      }
    }
  } else {
#pragma unroll
    for (int mi = 0; mi < 8; ++mi) {
      int rbase = bm + wr * 128 + mi * 16 + kq * 4;
#pragma unroll
      for (int r = 0; r < 4; ++r) {
        size_t rowoff = (size_t)(rbase + r) * strideN + cb + wc * 64 + fr;
#pragma unroll
        for (int nj = 0; nj < 4; ++nj) {
          float v = acc[mi][nj][r];
          if (mode == 1) v = silu_f(v);
          Fd[rowoff + nj * 16] = v;
        }
      }
    }
  }
}

// ---------------- dyn = tg @ gen_w2 ----------------
__global__ __launch_bounds__(256) void proj_dyn(
    const float* __restrict__ tg, const float* __restrict__ w2, float* __restrict__ dyn)
{
  int t = blockIdx.x, tid = threadIdx.x;
  float g = tg[(size_t)t * 256 + tid];
  float p[4];
#pragma unroll
  for (int j = 0; j < 4; ++j) p[j] = g * w2[tid * 4 + j];
#pragma unroll
  for (int j = 0; j < 4; ++j)
    for (int m = 32; m >= 1; m >>= 1) p[j] += __shfl_xor(p[j], m);
  __shared__ float red[4][4];
  if ((tid & 63) == 0) {
    int w = tid >> 6;
#pragma unroll
    for (int j = 0; j < 4; ++j) red[w][j] = p[j];
  }
  __syncthreads();
  if (tid < 4) dyn[(size_t)t * 4 + tid] = red[0][tid] + red[1][tid] + red[2][tid] + red[3][tid];
}

// ---------------- beta / raw decay log-gate g ----------------
__global__ __launch_bounds__(256) void proj_bg(
    const float* __restrict__ h, const float* __restrict__ Wb, const float* __restrict__ Wa,
    const float* __restrict__ A_log, const float* __restrict__ dt_bias,
    float* __restrict__ beta, float* __restrict__ gout)
{
  int t = blockIdx.x, tid = threadIdx.x;
  float pb[6], pa[6];
#pragma unroll
  for (int j = 0; j < 6; ++j) { pb[j] = 0.f; pa[j] = 0.f; }
  for (int d = tid; d < DIM; d += 256) {
    float hv = h[(size_t)t * DIM + d];
#pragma unroll
    for (int j = 0; j < 6; ++j) {
      pb[j] += hv * Wb[d * 6 + j];
      pa[j] += hv * Wa[d * 6 + j];
    }
  }
#pragma unroll
  for (int j = 0; j < 6; ++j)
    for (int m = 32; m >= 1; m >>= 1) { pb[j] += __shfl_xor(pb[j], m); pa[j] += __shfl_xor(pa[j], m); }
  __shared__ float rb[4][6], ra[4][6];
  if ((tid & 63) == 0) {
    int w = tid >> 6;
#pragma unroll
    for (int j = 0; j < 6; ++j) { rb[w][j] = pb[j]; ra[w][j] = pa[j]; }
  }
  __syncthreads();
  if (tid < 6) {
    int j = tid;
    float sb = rb[0][j] + rb[1][j] + rb[2][j] + rb[3][j];
    float sa = ra[0][j] + ra[1][j] + ra[2][j] + ra[3][j];
    beta[(size_t)t * 6 + j] = 1.f / (1.f + expf(-sb));
    float z = sa + dt_bias[j];
    float sp = (z > 20.f) ? z : log1pf(expf(z));
    gout[(size_t)t * 6 + j] = -expf(A_log[j]) * sp;   // raw log-gate (g < 0)
  }
}

// ---------------- causal dynamic conv + silu (8 timesteps/thread) ----------------
__global__ __launch_bounds__(256) void conv_kernel(
    const float* __restrict__ x, const float* __restrict__ dyn,
    const float* __restrict__ cw, float* __restrict__ v)
{
  int c = blockIdx.x * 256 + threadIdx.x;
  int t0 = blockIdx.y * 8;
  float4 w4 = ((const float4*)cw)[c];
  float xs[11];
#pragma unroll
  for (int i = 0; i < 11; ++i) {
    int t = t0 - 3 + i;
    xs[i] = (t >= 0) ? x[(size_t)t * VD + c] : 0.f;
  }
#pragma unroll
  for (int j = 0; j < 8; ++j) {
    int t = t0 + j;
    float4 dd = ((const float4*)dyn)[t];
    float acc = (w4.x + dd.x) * xs[j]
              + (w4.y + dd.y) * xs[j + 1]
              + (w4.z + dd.z) * xs[j + 2]
              + (w4.w + dd.w) * xs[j + 3];
    v[(size_t)t * VD + c] = silu_f(acc);
  }
}

// ---------------- P1: within-chunk inclusive cumsum of g, gamma = exp(c_end) ----------------
__global__ __launch_bounds__(64) void cumsum_g(
    const float* __restrict__ g, float* __restrict__ c, float* __restrict__ gammas)
{
  int ch = blockIdx.x, h = blockIdx.y;
  int t0 = ch * CK;
  int lane = threadIdx.x;
  float cum = g[(size_t)(t0 + lane) * 6 + h];
  for (int off = 1; off < 64; off <<= 1) {
    float n = __shfl_up(cum, off);
    if (lane >= off) cum += n;
  }
  c[(size_t)h * T_LEN + t0 + lane] = cum;
  if (lane == 63) gammas[h * NCHK + ch] = __expf(cum);
}

// ---------------- fused l2norm + Kbar/Qbar scale ----------------
__global__ __launch_bounds__(384) void l2scale(
    float* __restrict__ q, float* __restrict__ k, const float* __restrict__ c,
    unsigned short* __restrict__ Qb, unsigned short* __restrict__ Kb)
{
  int t = blockIdx.x;
  int h = threadIdx.x >> 6, lane = threadIdx.x & 63;
  size_t off = (size_t)t * KD + h * 256 + lane * 4;
  float4 qv = *(const float4*)(q + off);
  float4 kv = *(const float4*)(k + off);
  float sq = qv.x*qv.x + qv.y*qv.y + qv.z*qv.z + qv.w*qv.w;
  float sk = kv.x*kv.x + kv.y*kv.y + kv.z*kv.z + kv.w*kv.w;
  for (int m = 32; m >= 1; m >>= 1) { sq += __shfl_xor(sq, m); sk += __shfl_xor(sk, m); }
  float rq = rsqrtf(sq + 1e-6f) * 0.0625f;   // fold DK^-0.5
  float rk = rsqrtf(sk + 1e-6f);
  qv.x *= rq; qv.y *= rq; qv.z *= rq; qv.w *= rq;
  kv.x *= rk; kv.y *= rk; kv.z *= rk; kv.w *= rk;
  *(float4*)(q + off) = qv;
  *(float4*)(k + off) = kv;
  float w1 = __expf(c[(size_t)h * T_LEN + t]);
  ushort4 qo, ko;
  qo.x = f2bf(w1 * qv.x); qo.y = f2bf(w1 * qv.y); qo.z = f2bf(w1 * qv.z); qo.w = f2bf(w1 * qv.w);
  ko.x = f2bf(w1 * kv.x); ko.y = f2bf(w1 * kv.y); ko.z = f2bf(w1 * kv.z); ko.w = f2bf(w1 * kv.w);
  *(ushort4*)(Qb + off) = qo;
  *(ushort4*)(Kb + off) = ko;
}

// ---------------- P2b: KhT[h][ch][kk][tt] = exp(c_end - c_t) * k[t][kk]  (bf16) ----------------
// R9: rewritten with LDS transpose tile. Old form had lanes reading stride-6KB
// (fully uncoalesced). Now: coalesced row loads -> LDS [64][258] (odd dword
// stride => conflict-free transpose read) -> coalesced 128B writes.
__global__ __launch_bounds__(256) void make_khT(
    const float* __restrict__ k, const float* __restrict__ c,
    unsigned short* __restrict__ KhT)
{
  int ch = blockIdx.x, h = blockIdx.y;
  int t0 = ch * CK;
  int tid = threadIdx.x;
  __shared__ unsigned short tile[64][258];
  __shared__ float ws[64];
  if (tid < 64) {
    float cend = c[(size_t)h * T_LEN + t0 + 63];
    ws[tid] = __expf(cend - c[(size_t)h * T_LEN + t0 + tid]);
  }
  __syncthreads();
#pragma unroll 8
  for (int rr = 0; rr < 64; ++rr) {
    float kv = k[(size_t)(t0 + rr) * KD + h * 256 + tid];
    tile[rr][tid] = f2bf(ws[rr] * kv);
  }
  __syncthreads();
  size_t obase = ((size_t)(h * NCHK + ch)) * DK * CK;
  int tt = tid & 63, kr = tid >> 6;
#pragma unroll 8
  for (int kb = 0; kb < 64; ++kb) {
    int kk = kb * 4 + kr;
    KhT[obase + (size_t)kk * CK + tt] = tile[tt][kk];
  }
}

// ---------------- P3: per (h,chunk): L, P via MFMA ----------------
__global__ __launch_bounds__(256) void chunk_lp(
    const float* __restrict__ q, const float* __restrict__ k,
    const float* __restrict__ c, const float* __restrict__ beta,
    float* __restrict__ Lg, unsigned short* __restrict__ Pm)
{
  const int ch = blockIdx.x, h = blockIdx.y;
  const int t0 = ch * CK;
  const int tid = threadIdx.x;
  const int w = tid >> 6, lane = tid & 63, fr = lane & 15, kq = lane >> 4;
  __shared__ unsigned short kb[64][264];
  __shared__ unsigned short qb[64][264];
  __shared__ float cs[64], bs[64];
#pragma unroll
  for (int i = 0; i < 16; ++i) {
    int fi = tid + i * 256;
    int r = fi >> 6, d4 = fi & 63;
    float4 kv = *(const float4*)(k + (size_t)(t0 + r) * KD + h * 256 + d4 * 4);
    float4 qv = *(const float4*)(q + (size_t)(t0 + r) * KD + h * 256 + d4 * 4);
    ushort4 k4, q4;
    k4.x = f2bf(kv.x); k4.y = f2bf(kv.y); k4.z = f2bf(kv.z); k4.w = f2bf(kv.w);
    q4.x = f2bf(qv.x); q4.y = f2bf(qv.y); q4.z = f2bf(qv.z); q4.w = f2bf(qv.w);
    *(ushort4*)&kb[r][d4 * 4] = k4;
    *(ushort4*)&qb[r][d4 * 4] = q4;
  }
  if (tid < 64) {
    cs[tid] = c[(size_t)h * T_LEN + t0 + tid];
    bs[tid] = beta[(size_t)(t0 + tid) * 6 + h];
  }
  __syncthreads();

  f32x4 akk[4], aqk[4];
#pragma unroll
  for (int j = 0; j < 4; ++j) { akk[j] = (f32x4){0,0,0,0}; aqk[j] = (f32x4){0,0,0,0}; }
#pragma unroll
  for (int kt = 0; kt < 8; ++kt) {
    bf16x8 ak = *(const bf16x8*)&kb[16 * w + fr][kt * 32 + kq * 8];
    bf16x8 aq = *(const bf16x8*)&qb[16 * w + fr][kt * 32 + kq * 8];
#pragma unroll
    for (int j = 0; j < 4; ++j) {
      bf16x8 b = *(const bf16x8*)&kb[j * 16 + fr][kt * 32 + kq * 8];
      akk[j] = __builtin_amdgcn_mfma_f32_16x16x32_bf16(ak, b, akk[j], 0, 0, 0);
      aqk[j] = __builtin_amdgcn_mfma_f32_16x16x32_bf16(aq, b, aqk[j], 0, 0, 0);
    }
  }
  size_t base = ((size_t)(h * NCHK + ch)) * CK * CK;
#pragma unroll
  for (int j = 0; j < 4; ++j) {
#pragma unroll
    for (int r = 0; r < 4; ++r) {
      int t = 16 * w + kq * 4 + r, col = j * 16 + fr;
      float e = __expf(fminf(cs[t] - cs[col], 0.f));
      Lg[base + t * 64 + col] = (col < t) ? bs[t] * e * akk[j][r] : 0.f;
      Pm[base + t * 64 + col] = f2bf((col <= t) ? e * aqk[j][r] : 0.f);
    }
  }
}

// ---------------- P4: T' = (I+L)^{-1} diag(beta)  (bf16) ----------------
__global__ __launch_bounds__(64) void tri_inv(
    const float* __restrict__ Lg, const float* __restrict__ beta,
    unsigned short* __restrict__ Tm)
{
  const int ch = blockIdx.x, h = blockIdx.y;
  const size_t base = ((size_t)(h * NCHK + ch)) * CK * CK;
  const int j = threadIdx.x;
  __shared__ float Ll[64][65];
  __shared__ float Tl[64][65];
  for (int t = 0; t < 64; ++t) Ll[t][j] = Lg[base + t * 64 + j];
  __syncthreads();
  for (int t = 0; t < 64; ++t) {
    float s;
    if (j > t) s = 0.f;
    else if (j == t) s = 1.f;
    else {
      s = 0.f;
      for (int m = j; m < t; ++m) s -= Ll[t][m] * Tl[m][j];
    }
    Tl[t][j] = s;
  }
  float bj = beta[(size_t)(ch * 64 + j) * 6 + h];
  for (int t = 0; t < 64; ++t) Tm[base + t * 64 + j] = f2bf(Tl[t][j] * bj);
}

// ---------------- chunked gated delta-rule scan (MFMA, 8-wave) — R3 form ----------------
__global__ __launch_bounds__(512, 2) void scan_chunk(
    const unsigned short* __restrict__ Kb,   // [T][KD] Kbar
    const unsigned short* __restrict__ Qb,   // [T][KD] Qbar
    const unsigned short* __restrict__ KhT,  // [H][NCHK][DK][CK]
    const unsigned short* __restrict__ Tm,   // [H][NCHK][CK][CK]
    const unsigned short* __restrict__ Pm,   // [H][NCHK][CK][CK]
    const float* __restrict__ gammas,        // [H][NCHK]
    float* __restrict__ VO)                  // [T][VD]: V in, O out (in place)
{
  const int h = blockIdx.y, sl = blockIdx.x;
  const int tid = threadIdx.x;
  const int w = tid >> 6, lane = tid & 63;
  const int tw = w & 3, kg = w >> 2;
  const int fr = lane & 15, kq = lane >> 4;

  __shared__ unsigned short S0h[16][264];
  __shared__ unsigned short S0l[16][264];
  __shared__ unsigned short XT[16][72];
  __shared__ unsigned short DVT[16][72];
  __shared__ float PY[2][4][16][20];   // partial Y, [kg][tw][fr][kq*4+r]
  __shared__ float PO[2][4][16][20];   // partial O

  f32x4 st[2];
  st[0] = (f32x4){0.f, 0.f, 0.f, 0.f};
  st[1] = (f32x4){0.f, 0.f, 0.f, 0.f};

  const int colg = h * DVh + sl * 16 + fr;
  const size_t hc0 = (size_t)h * NCHK;

  // zero-init S0 staging (cols 0..255 are the ones read)
  {
    int zr = tid >> 5;          // 0..15
    int zc = (tid & 31) * 8;    // 0..248
    ushort4 z; z.x = 0; z.y = 0; z.z = 0; z.w = 0;
    *(ushort4*)&S0h[zr][zc]     = z;
    *(ushort4*)&S0h[zr][zc + 4] = z;
    *(ushort4*)&S0l[zr][zc]     = z;
    *(ushort4*)&S0l[zr][zc + 4] = z;
  }

  bf16x8 kfA[4], kfB[4], qfA[4], qfB[4];
  float vlA[4], vlB[4];

#define PREF(KF, QF, VL, chn) do { \
    const unsigned short* kr_ = Kb + (size_t)((chn) * CK + 16 * tw + fr) * KD + h * 256 + kg * 128 + kq * 8; \
    const unsigned short* qr_ = Qb + (size_t)((chn) * CK + 16 * tw + fr) * KD + h * 256 + kg * 128 + kq * 8; \
    _Pragma("unroll") \
    for (int kt = 0; kt < 4; ++kt) { \
      KF[kt] = *(const bf16x8*)(kr_ + kt * 32); \
      QF[kt] = *(const bf16x8*)(qr_ + kt * 32); } \
    if (kg == 0) { \
      _Pragma("unroll") \
      for (int r = 0; r < 4; ++r) VL[r] = VO[(size_t)((chn) * CK + 16 * tw + kq * 4 + r) * VD + colg]; } \
  } while (0)

#define BODY(chx, KF, QF, VL, KFN, QFN, VLN) do { \
    const int ch_ = (chx); \
    const int t0_ = ch_ * CK; \
    const size_t cb_ = hc0 + ch_; \
    /* tpf: kg0 = T' rows (for DV), kg1 = P rows (for O) */ \
    bf16x8 tpf[2]; \
    { const unsigned short* b_ = (kg == 0 ? Tm : Pm) + (cb_ * CK + 16 * tw + fr) * CK + kq * 8; \
      tpf[0] = *(const bf16x8*)(b_); tpf[1] = *(const bf16x8*)(b_ + 32); } \
    bf16x8 hfr[2][2]; \
    _Pragma("unroll") \
    for (int i = 0; i < 2; ++i) { \
      const unsigned short* hr_ = KhT + (cb_ * DK + 32 * w + 16 * i + fr) * CK + kq * 8; \
      hfr[i][0] = *(const bf16x8*)(hr_); hfr[i][1] = *(const bf16x8*)(hr_ + 32); } \
    const float gam_ = gammas[cb_]; \
    { const int chn_ = (ch_ + 1 < NCHK) ? ch_ + 1 : ch_; PREF(KFN, QFN, VLN, chn_); } \
    /* P1: partial Y/O over this wave's half of DK (4 kt) */ \
    f32x4 yt, ot; \
    { f32x4 yh = (f32x4){0.f,0.f,0.f,0.f}, yl = yh, oh = yh, ol = yh; \
      __builtin_amdgcn_s_setprio(1); \
      _Pragma("unroll") \
      for (int kt = 0; kt < 4; ++kt) { \
        const int ka_ = (kg * 4 + kt) * 32 + kq * 8; \
        bf16x8 bh_ = *(const bf16x8*)&S0h[fr][ka_]; \
        bf16x8 bl_ = *(const bf16x8*)&S0l[fr][ka_]; \
        yh = __builtin_amdgcn_mfma_f32_16x16x32_bf16(KF[kt], bh_, yh, 0, 0, 0); \
        yl = __builtin_amdgcn_mfma_f32_16x16x32_bf16(KF[kt], bl_, yl, 0, 0, 0); \
        oh = __builtin_amdgcn_mfma_f32_16x16x32_bf16(QF[kt], bh_, oh, 0, 0, 0); \
        ol = __builtin_amdgcn_mfma_f32_16x16x32_bf16(QF[kt], bl_, ol, 0, 0, 0); } \
      __builtin_amdgcn_s_setprio(0); \
      yt = yh + yl; ot = oh + ol; } \
    *(f32x4*)&PY[kg][tw][fr][kq * 4] = yt; \
    *(f32x4*)&PO[kg][tw][fr][kq * 4] = ot; \
    bar_lds();   /* B1: partials visible */ \
    if (kg == 0) { \
      f32x4 yo = *(const f32x4*)&PY[1][tw][fr][kq * 4]; \
      ushort4 x4; \
      x4.x = f2bf(VL[0] - (yt[0] + yo[0])); \
      x4.y = f2bf(VL[1] - (yt[1] + yo[1])); \
      x4.z = f2bf(VL[2] - (yt[2] + yo[2])); \
      x4.w = f2bf(VL[3] - (yt[3] + yo[3])); \
      *(ushort4*)&XT[fr][16 * tw + kq * 4] = x4; \
    } else { \
      f32x4 oo = *(const f32x4*)&PO[0][tw][fr][kq * 4]; \
      ot[0] += oo[0]; ot[1] += oo[1]; ot[2] += oo[2]; ot[3] += oo[3]; } \
    bar_lds();   /* B2: XT visible */ \
    /* P2: DV = T' X (kg0 only) */ \
    if (kg == 0) { \
      f32x4 d = (f32x4){0.f,0.f,0.f,0.f}; \
      bf16x8 b0_ = *(const bf16x8*)&XT[fr][kq * 8]; \
      bf16x8 b1_ = *(const bf16x8*)&XT[fr][32 + kq * 8]; \
      d = __builtin_amdgcn_mfma_f32_16x16x32_bf16(tpf[0], b0_, d, 0, 0, 0); \
      d = __builtin_amdgcn_mfma_f32_16x16x32_bf16(tpf[1], b1_, d, 0, 0, 0); \
      ushort4 d4; \
      d4.x = f2bf(d[0]); d4.y = f2bf(d[1]); d4.z = f2bf(d[2]); d4.w = f2bf(d[3]); \
      *(ushort4*)&DVT[fr][16 * tw + kq * 4] = d4; } \
    bar_lds();   /* B3: DVT visible */ \
    /* P3: O-store (kg1), state update + S0 staging (all) */ \
    { bf16x8 dv0_ = *(const bf16x8*)&DVT[fr][kq * 8]; \
      bf16x8 dv1_ = *(const bf16x8*)&DVT[fr][32 + kq * 8]; \
      if (kg == 1) { \
        f32x4 op = (f32x4){0.f,0.f,0.f,0.f}; \
        op = __builtin_amdgcn_mfma_f32_16x16x32_bf16(tpf[0], dv0_, op, 0, 0, 0); \
        op = __builtin_amdgcn_mfma_f32_16x16x32_bf16(tpf[1], dv1_, op, 0, 0, 0); \
        _Pragma("unroll") \
        for (int r = 0; r < 4; ++r) \
          VO[(size_t)(t0_ + 16 * tw + kq * 4 + r) * VD + colg] = ot[r] + op[r]; } \
      __builtin_amdgcn_s_setprio(1); \
      _Pragma("unroll") \
      for (int i = 0; i < 2; ++i) { \
        st[i][0] *= gam_; st[i][1] *= gam_; st[i][2] *= gam_; st[i][3] *= gam_; \
        st[i] = __builtin_amdgcn_mfma_f32_16x16x32_bf16(hfr[i][0], dv0_, st[i], 0, 0, 0); \
        st[i] = __builtin_amdgcn_mfma_f32_16x16x32_bf16(hfr[i][1], dv1_, st[i], 0, 0, 0); \
        ushort4 hi4, lo4; \
        { float s0 = st[i][0], s1 = st[i][1], s2 = st[i][2], s3 = st[i][3]; \
          hi4.x = f2bf(s0); lo4.x = f2bf(s0 - bf2f(hi4.x)); \
          hi4.y = f2bf(s1); lo4.y = f2bf(s1 - bf2f(hi4.y)); \
          hi4.z = f2bf(s2); lo4.z = f2bf(s2 - bf2f(hi4.z)); \
          hi4.w = f2bf(s3); lo4.w = f2bf(s3 - bf2f(hi4.w)); } \
        *(ushort4*)&S0h[fr][32 * w + 16 * i + kq * 4] = hi4; \
        *(ushort4*)&S0l[fr][32 * w + 16 * i + kq * 4] = lo4; } \
      __builtin_amdgcn_s_setprio(0); } \
    bar_lds();   /* B4: S0 visible for next chunk */ \
  } while (0)

  PREF(kfA, qfA, vlA, 0);
  __syncthreads();   // covers the LDS zero-init
  for (int ch = 0; ch < NCHK; ch += 2) {
    BODY(ch,     kfA, qfA, vlA, kfB, qfB, vlB);
    BODY(ch + 1, kfB, qfB, vlB, kfA, qfA, vlA);
  }
#undef BODY
#undef PREF
}

// ---------------- gated RMSNorm ----------------
__global__ __launch_bounds__(256) void norm_gate(
    const float* __restrict__ o, const unsigned short* __restrict__ gate,
    const float* __restrict__ nw, unsigned short* __restrict__ out)
{
  int th = blockIdx.x, tid = threadIdx.x;
  size_t base = (size_t)th * DVh;
  float x0 = o[base + tid], x1 = o[base + 256 + tid];
  float ss = x0 * x0 + x1 * x1;
  for (int m = 32; m >= 1; m >>= 1) ss += __shfl_xor(ss, m);
  __shared__ float red[4];
  if ((tid & 63) == 0) red[tid >> 6] = ss;
  __syncthreads();
  float rms = rsqrtf((red[0] + red[1] + red[2] + red[3]) * (1.f / 512.f) + 1e-5f);
  float g0 = bf2f(gate[base + tid]), g1 = bf2f(gate[base + 256 + tid]);
  out[base + tid]       = f2bf(x0 * rms * nw[tid]       * silu_f(g0));
  out[base + 256 + tid] = f2bf(x1 * rms * nw[tid + 256] * silu_f(g1));
}

extern "C" void kernel_launch(void* const* d_in, const int* in_sizes, int n_in,
                              void* d_out, int out_size, void* d_ws, size_t ws_size,
                              hipStream_t stream)
{
  const float* h       = (const float*)d_in[0];
  const float* Wq      = (const float*)d_in[1];
  const float* Wk      = (const float*)d_in[2];
  const float* Wv      = (const float*)d_in[3];
  const float* Wb      = (const float*)d_in[4];
  const float* Wa      = (const float*)d_in[5];
  const float* Wg      = (const float*)d_in[6];
  const float* Wo      = (const float*)d_in[7];
  const float* A_log   = (const float*)d_in[8];
  const float* dt_bias = (const float*)d_in[9];
  const float* conv_w  = (const float*)d_in[10];
  const float* gen_w1  = (const float*)d_in[11];
  const float* gen_w2  = (const float*)d_in[12];
  const float* norm_w  = (const float*)d_in[13];
  float* out = (float*)d_out;

  const size_t TK = (size_t)T_LEN * KD, TV = (size_t)T_LEN * VD, TD = (size_t)T_LEN * DIM;

  float* ws   = (float*)d_ws;
  float* q    = ws;
  float* k    = q    + TK;
  float* x    = k    + TK;          // h@Wv conv input; region later reused (see aliases)
  float* v    = x    + TV;          // conv out; O written in place by scan
  float* tg   = v    + TV;          // T*256
  float* dyn  = tg   + (size_t)T_LEN * 256;
  float* beta = dyn  + (size_t)T_LEN * 4;
  float* g    = beta + (size_t)T_LEN * 6;
  float* c    = g    + (size_t)T_LEN * 6;       // [H][T]
  float* gam  = c    + (size_t)NH * T_LEN;      // [H][NCHK]
  float* fend = gam  + 512;
  unsigned short* bh      = (unsigned short*)fend;          // T*DIM
  unsigned short* wT      = bh      + TD;                   // DIM*VD (used for Wo only)
  unsigned short* gate_bf = wT      + (size_t)DIM * VD;     // T*VD
  unsigned short* go_bf   = gate_bf + TV;                   // T*VD
  // aliases (lifetime-disjoint):
  unsigned short* Kb_s  = bh;                 // Kbar: bh dead after fused GEMM
  unsigned short* Qb_s  = (unsigned short*)x; // x region free after conv
  unsigned short* KhT_s = Qb_s + TK;
  unsigned short* Tm_s  = KhT_s + TK;         // H*NCHK*DK*CK == T*KD
  unsigned short* Pm_s  = Tm_s + (size_t)NH * NCHK * CK * CK;
  float* Lg = (float*)go_bf;                  // consumed before norm_gate writes go_bf
  // stacked B^T for fused GEMM: [9472][2048] bf16 = 38.8 MB; aliases v region
  // (50.3 MB) — used only before conv_kernel writes v.
  unsigned short* wTall = (unsigned short*)v;

  dim3 blk(256);
  cast_bf16<<<(TD / 4) / 256, blk, 0, stream>>>(h, bh);
  // stack all five projection weights (transposed) into wTall
  tcast<<<dim3(KD / 32, DIM / 32), blk, 0, stream>>>(Wq, wTall + (size_t)0 * DIM, DIM, KD);
  tcast<<<dim3(KD / 32, DIM / 32), blk, 0, stream>>>(Wk, wTall + (size_t)1536 * DIM, DIM, KD);
  tcast<<<dim3(VD / 32, DIM / 32), blk, 0, stream>>>(Wv, wTall + (size_t)3072 * DIM, DIM, VD);
  tcast<<<dim3(VD / 32, DIM / 32), blk, 0, stream>>>(Wg, wTall + (size_t)6144 * DIM, DIM, VD);
  tcast<<<dim3(256 / 32, DIM / 32), blk, 0, stream>>>(gen_w1, wTall + (size_t)9216 * DIM, DIM, 256);
  // one fused GEMM for q | k | x | gate | tg (256^2 8-phase, 16M x 37N blocks)
  gemm_fused<<<dim3((T_LEN / 256) * (NFUSE / 256)), 512, 0, stream>>>(
      bh, wTall, q, k, x, gate_bf, tg);

  proj_bg<<<T_LEN, blk, 0, stream>>>(h, Wb, Wa, A_log, dt_bias, beta, g);
  cumsum_g<<<dim3(NCHK, NH), 64, 0, stream>>>(g, c, gam);
  proj_dyn<<<T_LEN, blk, 0, stream>>>(tg, gen_w2, dyn);
  conv_kernel<<<dim3(VD / 256, T_LEN / 8), blk, 0, stream>>>(x, dyn, conv_w, v);
  l2scale<<<T_LEN, 384, 0, stream>>>(q, k, c, Qb_s, Kb_s);

  make_khT<<<dim3(NCHK, NH), blk, 0, stream>>>(k, c, KhT_s);
  chunk_lp<<<dim3(NCHK, NH), blk, 0, stream>>>(q, k, c, beta, Lg, Pm_s);
  tri_inv<<<dim3(NCHK, NH), 64, 0, stream>>>(Lg, beta, Tm_s);

  scan_chunk<<<dim3(DVh / 16, NH), 512, 0, stream>>>(Kb_s, Qb_s, KhT_s, Tm_s, Pm_s, gam, v);

  norm_gate<<<T_LEN * NH, blk, 0, stream>>>(v, gate_bf, norm_w, go_bf);
  tcast<<<dim3(DIM / 32, VD / 32), blk, 0, stream>>>(Wo, wT, VD, DIM);
  gemm_bt_bf16<<<dim3(DIM / 128, T_LEN / 128), blk, 0, stream>>>(go_bf, wT, out, T_LEN, DIM, VD, 0);
}

// Round 10
// 881.984 us; speedup vs baseline: 1.2072x; 1.0245x over previous
//
#include <hip/hip_runtime.h>
#include <hip/hip_bf16.h>
#include <math.h>

#define T_LEN 4096
#define DIM   2048
#define NH    6
#define DK    256
#define DVh   512
#define KD    1536
#define VD    3072
#define CK    64
#define NCHK  (T_LEN / CK)
#define NFUSE 9472   // 1536(q)+1536(k)+3072(x)+3072(gate)+256(tg)

typedef __attribute__((ext_vector_type(8))) short bf16x8;
typedef __attribute__((ext_vector_type(4))) float f32x4;

#define AS1 __attribute__((address_space(1)))
#define AS3 __attribute__((address_space(3)))

__device__ __forceinline__ float silu_f(float v){ return v / (1.f + __expf(-v)); }

__device__ __forceinline__ unsigned short f2bf(float f) {
  unsigned int u = __float_as_uint(f);
  unsigned int r = u + 0x7FFFu + ((u >> 16) & 1u);
  return (unsigned short)(r >> 16);
}
__device__ __forceinline__ float bf2f(unsigned short s) {
  return __uint_as_float(((unsigned int)s) << 16);
}

// LDS-only barrier: drains lgkmcnt but leaves global loads/stores in flight.
__device__ __forceinline__ void bar_lds() {
  __builtin_amdgcn_sched_barrier(0);
  asm volatile("s_waitcnt lgkmcnt(0)" ::: "memory");
  __builtin_amdgcn_s_barrier();
  __builtin_amdgcn_sched_barrier(0);
}

// ---------------- cast fp32 -> bf16 ----------------
__global__ __launch_bounds__(256) void cast_bf16(
    const float* __restrict__ in, unsigned short* __restrict__ out)
{
  int i = blockIdx.x * 256 + threadIdx.x;
  float4 v4 = ((const float4*)in)[i];
  ushort4 o4;
  o4.x = f2bf(v4.x); o4.y = f2bf(v4.y); o4.z = f2bf(v4.z); o4.w = f2bf(v4.w);
  ((ushort4*)out)[i] = o4;
}

// ---------------- R10: ALL weight transposes in ONE launch ----------------
// Segments (block-id ranges, compile-time): Wq | Wk | Wv | Wg | gen_w1 -> wTall
// slices; Wo -> wT. Same 32x32 LDS transpose tile as the old tcast. Removes 5
// launch gaps + small-grid ramp; Wo moved early (wT untouched until out-GEMM).
__global__ __launch_bounds__(256) void tcast_all(
    const float* __restrict__ Wq, const float* __restrict__ Wk,
    const float* __restrict__ Wv, const float* __restrict__ Wg,
    const float* __restrict__ g1, const float* __restrict__ Wo,
    unsigned short* __restrict__ wTall, unsigned short* __restrict__ wT)
{
  int id = blockIdx.x;
  const float* in; unsigned short* out; int R, Cn, nbx;
  if (id < 3072)       { in = Wq; out = wTall;                          R = 2048; Cn = 1536; nbx = 48; }
  else if (id < 6144)  { in = Wk; out = wTall + (size_t)1536 * 2048;    R = 2048; Cn = 1536; nbx = 48; id -= 3072; }
  else if (id < 12288) { in = Wv; out = wTall + (size_t)3072 * 2048;    R = 2048; Cn = 3072; nbx = 96; id -= 6144; }
  else if (id < 18432) { in = Wg; out = wTall + (size_t)6144 * 2048;    R = 2048; Cn = 3072; nbx = 96; id -= 12288; }
  else if (id < 18944) { in = g1; out = wTall + (size_t)9216 * 2048;    R = 2048; Cn = 256;  nbx = 8;  id -= 18432; }
  else                 { in = Wo; out = wT;                             R = 3072; Cn = 2048; nbx = 64; id -= 18944; }
  int bx = (id % nbx) * 32, by = (id / nbx) * 32;
  __shared__ float tile[32][33];
  int tx = threadIdx.x & 31, ty = threadIdx.x >> 5;
#pragma unroll
  for (int i = 0; i < 32; i += 8)
    tile[ty + i][tx] = in[(size_t)(by + ty + i) * Cn + bx + tx];
  __syncthreads();
#pragma unroll
  for (int i = 0; i < 32; i += 8)
    out[(size_t)(bx + ty + i) * R + by + tx] = f2bf(tile[tx][ty + i]);
}

// ======== R7/R8 pipelined 128^2 GEMM core (BK=64, dbuf, counted vmcnt, T2 swizzle)
// Measured: MfmaUtil 29, bank-conflict 0, 237 us on the fused projection.
#define PSTAGE(Amat, Bmat, bufi, t_, Aptr, Bptr, Kk) do { \
    int k0_ = (t_) << 6; \
    _Pragma("unroll") \
    for (int i_ = 0; i_ < 4; ++i_) { \
      int c_ = threadIdx.x + 256 * i_; \
      int ks_ = c_ >> 9, row_ = (c_ >> 2) & 127, pc_ = c_ & 3; \
      int pcs_ = pc_ ^ ((row_ >> 1) & 3); \
      int gc_ = k0_ + ks_ * 32 + pcs_ * 8; \
      __builtin_amdgcn_global_load_lds( \
          (const AS1 unsigned int*)(Aptr + (size_t)(bm + row_) * (Kk) + gc_), \
          (AS3 unsigned int*)(&Amat[bufi][0] + c_ * 8), 16, 0, 0); \
      __builtin_amdgcn_global_load_lds( \
          (const AS1 unsigned int*)(Bptr + (size_t)(bn + row_) * (Kk) + gc_), \
          (AS3 unsigned int*)(&Bmat[bufi][0] + c_ * 8), 16, 0, 0); \
    } } while (0)

#define PGEMM_LOOP(Amat, Bmat, Aptr, Bptr, Kk, NTt) do { \
    PSTAGE(Amat, Bmat, 0, 0, Aptr, Bptr, Kk); \
    PSTAGE(Amat, Bmat, 1, 1, Aptr, Bptr, Kk); \
    __builtin_amdgcn_sched_barrier(0); \
    asm volatile("s_waitcnt vmcnt(8)" ::: "memory"); \
    __builtin_amdgcn_s_barrier(); \
    __builtin_amdgcn_sched_barrier(0); \
    const int slot_ = (kq ^ ((fr >> 1) & 3)) * 8; \
    for (int t = 0; t < (NTt); ++t) { \
      const unsigned short* as_ = &Amat[t & 1][0]; \
      const unsigned short* bs_ = &Bmat[t & 1][0]; \
      bf16x8 af_[2][4], bf_[2][4]; \
      _Pragma("unroll") \
      for (int ks_ = 0; ks_ < 2; ++ks_) { \
        _Pragma("unroll") \
        for (int i_ = 0; i_ < 4; ++i_) { \
          af_[ks_][i_] = *(const bf16x8*)(as_ + ks_ * 4096 + (wm + i_ * 16 + fr) * 32 + slot_); \
          bf_[ks_][i_] = *(const bf16x8*)(bs_ + ks_ * 4096 + (wn + i_ * 16 + fr) * 32 + slot_); \
        } } \
      __builtin_amdgcn_s_setprio(1); \
      _Pragma("unroll") \
      for (int i_ = 0; i_ < 4; ++i_) \
        _Pragma("unroll") \
        for (int j_ = 0; j_ < 4; ++j_) \
          acc[i_][j_] = __builtin_amdgcn_mfma_f32_16x16x32_bf16(af_[0][i_], bf_[0][j_], acc[i_][j_], 0, 0, 0); \
      __builtin_amdgcn_s_setprio(0); \
      bar_lds(); \
      if (t + 2 < (NTt)) PSTAGE(Amat, Bmat, t & 1, t + 2, Aptr, Bptr, Kk); \
      __builtin_amdgcn_s_setprio(1); \
      _Pragma("unroll") \
      for (int i_ = 0; i_ < 4; ++i_) \
        _Pragma("unroll") \
        for (int j_ = 0; j_ < 4; ++j_) \
          acc[i_][j_] = __builtin_amdgcn_mfma_f32_16x16x32_bf16(af_[1][i_], bf_[1][j_], acc[i_][j_], 0, 0, 0); \
      __builtin_amdgcn_s_setprio(0); \
      __builtin_amdgcn_sched_barrier(0); \
      if (t + 2 < (NTt)) { asm volatile("s_waitcnt vmcnt(8)" ::: "memory"); } \
      else               { asm volatile("s_waitcnt vmcnt(0)" ::: "memory"); } \
      __builtin_amdgcn_s_barrier(); \
      __builtin_amdgcn_sched_barrier(0); \
    } } while (0)

// ---------------- generic pipelined GEMM (used for out-proj) ----------------
__global__ __launch_bounds__(256) void gemm_bt_bf16(
    const unsigned short* __restrict__ A, const unsigned short* __restrict__ BT,
    void* __restrict__ Cout, int M, int N, int K, int act)
{
  __shared__ unsigned short As[2][8192];
  __shared__ unsigned short Bs[2][8192];
  const int tid = threadIdx.x;
  const int bm = blockIdx.y * 128, bn = blockIdx.x * 128;
  const int lane = tid & 63, wave = tid >> 6;
  const int wm = (wave >> 1) * 64, wn = (wave & 1) * 64;
  const int fr = lane & 15, kq = lane >> 4;
  const int NT = K >> 6;

  f32x4 acc[4][4];
#pragma unroll
  for (int i = 0; i < 4; ++i)
#pragma unroll
    for (int j = 0; j < 4; ++j) acc[i][j] = (f32x4){0.f, 0.f, 0.f, 0.f};

  PGEMM_LOOP(As, Bs, A, BT, K, NT);

  if (act == 2) {
    unsigned short* C = (unsigned short*)Cout;
#pragma unroll
    for (int i = 0; i < 4; ++i) {
      int rbase = bm + wm + i * 16 + kq * 4;
#pragma unroll
      for (int r = 0; r < 4; ++r) {
        size_t rowoff = (size_t)(rbase + r) * N + bn + wn + fr;
#pragma unroll
        for (int j = 0; j < 4; ++j) C[rowoff + j * 16] = f2bf(acc[i][j][r]);
      }
    }
  } else {
    float* C = (float*)Cout;
#pragma unroll
    for (int i = 0; i < 4; ++i) {
      int rbase = bm + wm + i * 16 + kq * 4;
#pragma unroll
      for (int r = 0; r < 4; ++r) {
        size_t rowoff = (size_t)(rbase + r) * N + bn + wn + fr;
#pragma unroll
        for (int j = 0; j < 4; ++j) {
          float v = acc[i][j][r];
          if (act == 1) v = silu_f(v);
          C[rowoff + j * 16] = v;
        }
      }
    }
  }
}

// ---------------- fused projection GEMM (R8 form: pipelined, grouped 1D grid) ----------------
// Segments: [0,1536) q silu | [1536,3072) k silu | [3072,6144) x linear |
// [6144,9216) gate bf16 | [9216,9472) tg silu.
__global__ __launch_bounds__(256) void gemm_fused(
    const unsigned short* __restrict__ A, const unsigned short* __restrict__ BT,
    float* __restrict__ Cq, float* __restrict__ Ck, float* __restrict__ Cx,
    unsigned short* __restrict__ Cg, float* __restrict__ Ct)
{
  __shared__ unsigned short As[2][8192];
  __shared__ unsigned short Bs[2][8192];
  const int tid = threadIdx.x;
  // grouped block mapping (R6)
  const int NPN = NFUSE / 128;           // 74
  const int GROUP = 8;
  const int npig = GROUP * NPN;          // 592
  const int pid = blockIdx.x;
  const int gid = pid / npig;
  const int pm = gid * GROUP + (pid % GROUP);
  const int pn = (pid % npig) / GROUP;
  const int bm = pm * 128, bn = pn * 128;
  const int lane = tid & 63, wave = tid >> 6;
  const int wm = (wave >> 1) * 64, wn = (wave & 1) * 64;
  const int fr = lane & 15, kq = lane >> 4;
  const int NT = DIM >> 6;               // 32

  f32x4 acc[4][4];
#pragma unroll
  for (int i = 0; i < 4; ++i)
#pragma unroll
    for (int j = 0; j < 4; ++j) acc[i][j] = (f32x4){0.f, 0.f, 0.f, 0.f};

  PGEMM_LOOP(As, Bs, A, BT, DIM, NT);

  // segment resolve (block-uniform)
  float* Fd = nullptr; unsigned short* Bd = nullptr;
  int strideN, cb, mode;   // mode: 0=fp32, 1=silu fp32, 2=bf16
  if (bn < 1536)      { Fd = Cq; strideN = 1536; cb = bn;        mode = 1; }
  else if (bn < 3072) { Fd = Ck; strideN = 1536; cb = bn - 1536; mode = 1; }
  else if (bn < 6144) { Fd = Cx; strideN = 3072; cb = bn - 3072; mode = 0; }
  else if (bn < 9216) { Bd = Cg; strideN = 3072; cb = bn - 6144; mode = 2; }
  else                { Fd = Ct; strideN = 256;  cb = bn - 9216; mode = 1; }

  if (mode == 2) {
#pragma unroll
    for (int i = 0; i < 4; ++i) {
      int rbase = bm + wm + i * 16 + kq * 4;
#pragma unroll
      for (int r = 0; r < 4; ++r) {
        size_t rowoff = (size_t)(rbase + r) * strideN + cb + wn + fr;
#pragma unroll
        for (int j = 0; j < 4; ++j) Bd[rowoff + j * 16] = f2bf(acc[i][j][r]);
      }
    }
  } else {
#pragma unroll
    for (int i = 0; i < 4; ++i) {
      int rbase = bm + wm + i * 16 + kq * 4;
#pragma unroll
      for (int r = 0; r < 4; ++r) {
        size_t rowoff = (size_t)(rbase + r) * strideN + cb + wn + fr;
#pragma unroll
        for (int j = 0; j < 4; ++j) {
          float v = acc[i][j][r];
          if (mode == 1) v = silu_f(v);
          Fd[rowoff + j * 16] = v;
        }
      }
    }
  }
}

// ---------------- dyn = tg @ gen_w2 ----------------
__global__ __launch_bounds__(256) void proj_dyn(
    const float* __restrict__ tg, const float* __restrict__ w2, float* __restrict__ dyn)
{
  int t = blockIdx.x, tid = threadIdx.x;
  float g = tg[(size_t)t * 256 + tid];
  float p[4];
#pragma unroll
  for (int j = 0; j < 4; ++j) p[j] = g * w2[tid * 4 + j];
#pragma unroll
  for (int j = 0; j < 4; ++j)
    for (int m = 32; m >= 1; m >>= 1) p[j] += __shfl_xor(p[j], m);
  __shared__ float red[4][4];
  if ((tid & 63) == 0) {
    int w = tid >> 6;
#pragma unroll
    for (int j = 0; j < 4; ++j) red[w][j] = p[j];
  }
  __syncthreads();
  if (tid < 4) dyn[(size_t)t * 4 + tid] = red[0][tid] + red[1][tid] + red[2][tid] + red[3][tid];
}

// ---------------- beta / raw decay log-gate g ----------------
__global__ __launch_bounds__(256) void proj_bg(
    const float* __restrict__ h, const float* __restrict__ Wb, const float* __restrict__ Wa,
    const float* __restrict__ A_log, const float* __restrict__ dt_bias,
    float* __restrict__ beta, float* __restrict__ gout)
{
  int t = blockIdx.x, tid = threadIdx.x;
  float pb[6], pa[6];
#pragma unroll
  for (int j = 0; j < 6; ++j) { pb[j] = 0.f; pa[j] = 0.f; }
  for (int d = tid; d < DIM; d += 256) {
    float hv = h[(size_t)t * DIM + d];
#pragma unroll
    for (int j = 0; j < 6; ++j) {
      pb[j] += hv * Wb[d * 6 + j];
      pa[j] += hv * Wa[d * 6 + j];
    }
  }
#pragma unroll
  for (int j = 0; j < 6; ++j)
    for (int m = 32; m >= 1; m >>= 1) { pb[j] += __shfl_xor(pb[j], m); pa[j] += __shfl_xor(pa[j], m); }
  __shared__ float rb[4][6], ra[4][6];
  if ((tid & 63) == 0) {
    int w = tid >> 6;
#pragma unroll
    for (int j = 0; j < 6; ++j) { rb[w][j] = pb[j]; ra[w][j] = pa[j]; }
  }
  __syncthreads();
  if (tid < 6) {
    int j = tid;
    float sb = rb[0][j] + rb[1][j] + rb[2][j] + rb[3][j];
    float sa = ra[0][j] + ra[1][j] + ra[2][j] + ra[3][j];
    beta[(size_t)t * 6 + j] = 1.f / (1.f + expf(-sb));
    float z = sa + dt_bias[j];
    float sp = (z > 20.f) ? z : log1pf(expf(z));
    gout[(size_t)t * 6 + j] = -expf(A_log[j]) * sp;   // raw log-gate (g < 0)
  }
}

// ---------------- causal dynamic conv + silu (8 timesteps/thread) ----------------
__global__ __launch_bounds__(256) void conv_kernel(
    const float* __restrict__ x, const float* __restrict__ dyn,
    const float* __restrict__ cw, float* __restrict__ v)
{
  int c = blockIdx.x * 256 + threadIdx.x;
  int t0 = blockIdx.y * 8;
  float4 w4 = ((const float4*)cw)[c];
  float xs[11];
#pragma unroll
  for (int i = 0; i < 11; ++i) {
    int t = t0 - 3 + i;
    xs[i] = (t >= 0) ? x[(size_t)t * VD + c] : 0.f;
  }
#pragma unroll
  for (int j = 0; j < 8; ++j) {
    int t = t0 + j;
    float4 dd = ((const float4*)dyn)[t];
    float acc = (w4.x + dd.x) * xs[j]
              + (w4.y + dd.y) * xs[j + 1]
              + (w4.z + dd.z) * xs[j + 2]
              + (w4.w + dd.w) * xs[j + 3];
    v[(size_t)t * VD + c] = silu_f(acc);
  }
}

// ---------------- P1: within-chunk inclusive cumsum of g, gamma = exp(c_end) ----------------
__global__ __launch_bounds__(64) void cumsum_g(
    const float* __restrict__ g, float* __restrict__ c, float* __restrict__ gammas)
{
  int ch = blockIdx.x, h = blockIdx.y;
  int t0 = ch * CK;
  int lane = threadIdx.x;
  float cum = g[(size_t)(t0 + lane) * 6 + h];
  for (int off = 1; off < 64; off <<= 1) {
    float n = __shfl_up(cum, off);
    if (lane >= off) cum += n;
  }
  c[(size_t)h * T_LEN + t0 + lane] = cum;
  if (lane == 63) gammas[h * NCHK + ch] = __expf(cum);
}

// ---------------- fused l2norm + Kbar/Qbar scale ----------------
__global__ __launch_bounds__(384) void l2scale(
    float* __restrict__ q, float* __restrict__ k, const float* __restrict__ c,
    unsigned short* __restrict__ Qb, unsigned short* __restrict__ Kb)
{
  int t = blockIdx.x;
  int h = threadIdx.x >> 6, lane = threadIdx.x & 63;
  size_t off = (size_t)t * KD + h * 256 + lane * 4;
  float4 qv = *(const float4*)(q + off);
  float4 kv = *(const float4*)(k + off);
  float sq = qv.x*qv.x + qv.y*qv.y + qv.z*qv.z + qv.w*qv.w;
  float sk = kv.x*kv.x + kv.y*kv.y + kv.z*kv.z + kv.w*kv.w;
  for (int m = 32; m >= 1; m >>= 1) { sq += __shfl_xor(sq, m); sk += __shfl_xor(sk, m); }
  float rq = rsqrtf(sq + 1e-6f) * 0.0625f;   // fold DK^-0.5
  float rk = rsqrtf(sk + 1e-6f);
  qv.x *= rq; qv.y *= rq; qv.z *= rq; qv.w *= rq;
  kv.x *= rk; kv.y *= rk; kv.z *= rk; kv.w *= rk;
  *(float4*)(q + off) = qv;
  *(float4*)(k + off) = kv;
  float w1 = __expf(c[(size_t)h * T_LEN + t]);
  ushort4 qo, ko;
  qo.x = f2bf(w1 * qv.x); qo.y = f2bf(w1 * qv.y); qo.z = f2bf(w1 * qv.z); qo.w = f2bf(w1 * qv.w);
  ko.x = f2bf(w1 * kv.x); ko.y = f2bf(w1 * kv.y); ko.z = f2bf(w1 * kv.z); ko.w = f2bf(w1 * kv.w);
  *(ushort4*)(Qb + off) = qo;
  *(ushort4*)(Kb + off) = ko;
}

// ---------------- P2b: KhT[h][ch][kk][tt] = exp(c_end - c_t) * k[t][kk]  (bf16) ----------------
// LDS-transpose form (R9): coalesced loads -> [64][258] tile -> coalesced writes.
__global__ __launch_bounds__(256) void make_khT(
    const float* __restrict__ k, const float* __restrict__ c,
    unsigned short* __restrict__ KhT)
{
  int ch = blockIdx.x, h = blockIdx.y;
  int t0 = ch * CK;
  int tid = threadIdx.x;
  __shared__ unsigned short tile[64][258];
  __shared__ float ws[64];
  if (tid < 64) {
    float cend = c[(size_t)h * T_LEN + t0 + 63];
    ws[tid] = __expf(cend - c[(size_t)h * T_LEN + t0 + tid]);
  }
  __syncthreads();
#pragma unroll 8
  for (int rr = 0; rr < 64; ++rr) {
    float kv = k[(size_t)(t0 + rr) * KD + h * 256 + tid];
    tile[rr][tid] = f2bf(ws[rr] * kv);
  }
  __syncthreads();
  size_t obase = ((size_t)(h * NCHK + ch)) * DK * CK;
  int tt = tid & 63, kr = tid >> 6;
#pragma unroll 8
  for (int kb = 0; kb < 64; ++kb) {
    int kk = kb * 4 + kr;
    KhT[obase + (size_t)kk * CK + tt] = tile[tt][kk];
  }
}

// ---------------- P3: per (h,chunk): L, P via MFMA ----------------
__global__ __launch_bounds__(256) void chunk_lp(
    const float* __restrict__ q, const float* __restrict__ k,
    const float* __restrict__ c, const float* __restrict__ beta,
    float* __restrict__ Lg, unsigned short* __restrict__ Pm)
{
  const int ch = blockIdx.x, h = blockIdx.y;
  const int t0 = ch * CK;
  const int tid = threadIdx.x;
  const int w = tid >> 6, lane = tid & 63, fr = lane & 15, kq = lane >> 4;
  __shared__ unsigned short kb[64][264];
  __shared__ unsigned short qb[64][264];
  __shared__ float cs[64], bs[64];
#pragma unroll
  for (int i = 0; i < 16; ++i) {
    int fi = tid + i * 256;
    int r = fi >> 6, d4 = fi & 63;
    float4 kv = *(const float4*)(k + (size_t)(t0 + r) * KD + h * 256 + d4 * 4);
    float4 qv = *(const float4*)(q + (size_t)(t0 + r) * KD + h * 256 + d4 * 4);
    ushort4 k4, q4;
    k4.x = f2bf(kv.x); k4.y = f2bf(kv.y); k4.z = f2bf(kv.z); k4.w = f2bf(kv.w);
    q4.x = f2bf(qv.x); q4.y = f2bf(qv.y); q4.z = f2bf(qv.z); q4.w = f2bf(qv.w);
    *(ushort4*)&kb[r][d4 * 4] = k4;
    *(ushort4*)&qb[r][d4 * 4] = q4;
  }
  if (tid < 64) {
    cs[tid] = c[(size_t)h * T_LEN + t0 + tid];
    bs[tid] = beta[(size_t)(t0 + tid) * 6 + h];
  }
  __syncthreads();

  f32x4 akk[4], aqk[4];
#pragma unroll
  for (int j = 0; j < 4; ++j) { akk[j] = (f32x4){0,0,0,0}; aqk[j] = (f32x4){0,0,0,0}; }
#pragma unroll
  for (int kt = 0; kt < 8; ++kt) {
    bf16x8 ak = *(const bf16x8*)&kb[16 * w + fr][kt * 32 + kq * 8];
    bf16x8 aq = *(const bf16x8*)&qb[16 * w + fr][kt * 32 + kq * 8];
#pragma unroll
    for (int j = 0; j < 4; ++j) {
      bf16x8 b = *(const bf16x8*)&kb[j * 16 + fr][kt * 32 + kq * 8];
      akk[j] = __builtin_amdgcn_mfma_f32_16x16x32_bf16(ak, b, akk[j], 0, 0, 0);
      aqk[j] = __builtin_amdgcn_mfma_f32_16x16x32_bf16(aq, b, aqk[j], 0, 0, 0);
    }
  }
  size_t base = ((size_t)(h * NCHK + ch)) * CK * CK;
#pragma unroll
  for (int j = 0; j < 4; ++j) {
#pragma unroll
    for (int r = 0; r < 4; ++r) {
      int t = 16 * w + kq * 4 + r, col = j * 16 + fr;
      float e = __expf(fminf(cs[t] - cs[col], 0.f));
      Lg[base + t * 64 + col] = (col < t) ? bs[t] * e * akk[j][r] : 0.f;
      Pm[base + t * 64 + col] = f2bf((col <= t) ? e * aqk[j][r] : 0.f);
    }
  }
}

// ---------------- P4: T' = (I+L)^{-1} diag(beta)  (bf16) ----------------
__global__ __launch_bounds__(64) void tri_inv(
    const float* __restrict__ Lg, const float* __restrict__ beta,
    unsigned short* __restrict__ Tm)
{
  const int ch = blockIdx.x, h = blockIdx.y;
  const size_t base = ((size_t)(h * NCHK + ch)) * CK * CK;
  const int j = threadIdx.x;
  __shared__ float Ll[64][65];
  __shared__ float Tl[64][65];
  for (int t = 0; t < 64; ++t) Ll[t][j] = Lg[base + t * 64 + j];
  __syncthreads();
  for (int t = 0; t < 64; ++t) {
    float s;
    if (j > t) s = 0.f;
    else if (j == t) s = 1.f;
    else {
      s = 0.f;
      for (int m = j; m < t; ++m) s -= Ll[t][m] * Tl[m][j];
    }
    Tl[t][j] = s;
  }
  float bj = beta[(size_t)(ch * 64 + j) * 6 + h];
  for (int t = 0; t < 64; ++t) Tm[base + t * 64 + j] = f2bf(Tl[t][j] * bj);
}

// ---------------- chunked gated delta-rule scan (MFMA, 8-wave) — R3 form ----------------
__global__ __launch_bounds__(512, 2) void scan_chunk(
    const unsigned short* __restrict__ Kb,   // [T][KD] Kbar
    const unsigned short* __restrict__ Qb,   // [T][KD] Qbar
    const unsigned short* __restrict__ KhT,  // [H][NCHK][DK][CK]
    const unsigned short* __restrict__ Tm,   // [H][NCHK][CK][CK]
    const unsigned short* __restrict__ Pm,   // [H][NCHK][CK][CK]
    const float* __restrict__ gammas,        // [H][NCHK]
    float* __restrict__ VO)                  // [T][VD]: V in, O out (in place)
{
  const int h = blockIdx.y, sl = blockIdx.x;
  const int tid = threadIdx.x;
  const int w = tid >> 6, lane = tid & 63;
  const int tw = w & 3, kg = w >> 2;
  const int fr = lane & 15, kq = lane >> 4;

  __shared__ unsigned short S0h[16][264];
  __shared__ unsigned short S0l[16][264];
  __shared__ unsigned short XT[16][72];
  __shared__ unsigned short DVT[16][72];
  __shared__ float PY[2][4][16][20];   // partial Y, [kg][tw][fr][kq*4+r]
  __shared__ float PO[2][4][16][20];   // partial O

  f32x4 st[2];
  st[0] = (f32x4){0.f, 0.f, 0.f, 0.f};
  st[1] = (f32x4){0.f, 0.f, 0.f, 0.f};

  const int colg = h * DVh + sl * 16 + fr;
  const size_t hc0 = (size_t)h * NCHK;

  // zero-init S0 staging (cols 0..255 are the ones read)
  {
    int zr = tid >> 5;          // 0..15
    int zc = (tid & 31) * 8;    // 0..248
    ushort4 z; z.x = 0; z.y = 0; z.z = 0; z.w = 0;
    *(ushort4*)&S0h[zr][zc]     = z;
    *(ushort4*)&S0h[zr][zc + 4] = z;
    *(ushort4*)&S0l[zr][zc]     = z;
    *(ushort4*)&S0l[zr][zc + 4] = z;
  }

  bf16x8 kfA[4], kfB[4], qfA[4], qfB[4];
  float vlA[4], vlB[4];

#define PREF(KF, QF, VL, chn) do { \
    const unsigned short* kr_ = Kb + (size_t)((chn) * CK + 16 * tw + fr) * KD + h * 256 + kg * 128 + kq * 8; \
    const unsigned short* qr_ = Qb + (size_t)((chn) * CK + 16 * tw + fr) * KD + h * 256 + kg * 128 + kq * 8; \
    _Pragma("unroll") \
    for (int kt = 0; kt < 4; ++kt) { \
      KF[kt] = *(const bf16x8*)(kr_ + kt * 32); \
      QF[kt] = *(const bf16x8*)(qr_ + kt * 32); } \
    if (kg == 0) { \
      _Pragma("unroll") \
      for (int r = 0; r < 4; ++r) VL[r] = VO[(size_t)((chn) * CK + 16 * tw + kq * 4 + r) * VD + colg]; } \
  } while (0)

#define BODY(chx, KF, QF, VL, KFN, QFN, VLN) do { \
    const int ch_ = (chx); \
    const int t0_ = ch_ * CK; \
    const size_t cb_ = hc0 + ch_; \
    /* tpf: kg0 = T' rows (for DV), kg1 = P rows (for O) */ \
    bf16x8 tpf[2]; \
    { const unsigned short* b_ = (kg == 0 ? Tm : Pm) + (cb_ * CK + 16 * tw + fr) * CK + kq * 8; \
      tpf[0] = *(const bf16x8*)(b_); tpf[1] = *(const bf16x8*)(b_ + 32); } \
    bf16x8 hfr[2][2]; \
    _Pragma("unroll") \
    for (int i = 0; i < 2; ++i) { \
      const unsigned short* hr_ = KhT + (cb_ * DK + 32 * w + 16 * i + fr) * CK + kq * 8; \
      hfr[i][0] = *(const bf16x8*)(hr_); hfr[i][1] = *(const bf16x8*)(hr_ + 32); } \
    const float gam_ = gammas[cb_]; \
    { const int chn_ = (ch_ + 1 < NCHK) ? ch_ + 1 : ch_; PREF(KFN, QFN, VLN, chn_); } \
    /* P1: partial Y/O over this wave's half of DK (4 kt) */ \
    f32x4 yt, ot; \
    { f32x4 yh = (f32x4){0.f,0.f,0.f,0.f}, yl = yh, oh = yh, ol = yh; \
      __builtin_amdgcn_s_setprio(1); \
      _Pragma("unroll") \
      for (int kt = 0; kt < 4; ++kt) { \
        const int ka_ = (kg * 4 + kt) * 32 + kq * 8; \
        bf16x8 bh_ = *(const bf16x8*)&S0h[fr][ka_]; \
        bf16x8 bl_ = *(const bf16x8*)&S0l[fr][ka_]; \
        yh = __builtin_amdgcn_mfma_f32_16x16x32_bf16(KF[kt], bh_, yh, 0, 0, 0); \
        yl = __builtin_amdgcn_mfma_f32_16x16x32_bf16(KF[kt], bl_, yl, 0, 0, 0); \
        oh = __builtin_amdgcn_mfma_f32_16x16x32_bf16(QF[kt], bh_, oh, 0, 0, 0); \
        ol = __builtin_amdgcn_mfma_f32_16x16x32_bf16(QF[kt], bl_, ol, 0, 0, 0); } \
      __builtin_amdgcn_s_setprio(0); \
      yt = yh + yl; ot = oh + ol; } \
    *(f32x4*)&PY[kg][tw][fr][kq * 4] = yt; \
    *(f32x4*)&PO[kg][tw][fr][kq * 4] = ot; \
    bar_lds();   /* B1: partials visible */ \
    if (kg == 0) { \
      f32x4 yo = *(const f32x4*)&PY[1][tw][fr][kq * 4]; \
      ushort4 x4; \
      x4.x = f2bf(VL[0] - (yt[0] + yo[0])); \
      x4.y = f2bf(VL[1] - (yt[1] + yo[1])); \
      x4.z = f2bf(VL[2] - (yt[2] + yo[2])); \
      x4.w = f2bf(VL[3] - (yt[3] + yo[3])); \
      *(ushort4*)&XT[fr][16 * tw + kq * 4] = x4; \
    } else { \
      f32x4 oo = *(const f32x4*)&PO[0][tw][fr][kq * 4]; \
      ot[0] += oo[0]; ot[1] += oo[1]; ot[2] += oo[2]; ot[3] += oo[3]; } \
    bar_lds();   /* B2: XT visible */ \
    /* P2: DV = T' X (kg0 only) */ \
    if (kg == 0) { \
      f32x4 d = (f32x4){0.f,0.f,0.f,0.f}; \
      bf16x8 b0_ = *(const bf16x8*)&XT[fr][kq * 8]; \
      bf16x8 b1_ = *(const bf16x8*)&XT[fr][32 + kq * 8]; \
      d = __builtin_amdgcn_mfma_f32_16x16x32_bf16(tpf[0], b0_, d, 0, 0, 0); \
      d = __builtin_amdgcn_mfma_f32_16x16x32_bf16(tpf[1], b1_, d, 0, 0, 0); \
      ushort4 d4; \
      d4.x = f2bf(d[0]); d4.y = f2bf(d[1]); d4.z = f2bf(d[2]); d4.w = f2bf(d[3]); \
      *(ushort4*)&DVT[fr][16 * tw + kq * 4] = d4; } \
    bar_lds();   /* B3: DVT visible */ \
    /* P3: O-store (kg1), state update + S0 staging (all) */ \
    { bf16x8 dv0_ = *(const bf16x8*)&DVT[fr][kq * 8]; \
      bf16x8 dv1_ = *(const bf16x8*)&DVT[fr][32 + kq * 8]; \
      if (kg == 1) { \
        f32x4 op = (f32x4){0.f,0.f,0.f,0.f}; \
        op = __builtin_amdgcn_mfma_f32_16x16x32_bf16(tpf[0], dv0_, op, 0, 0, 0); \
        op = __builtin_amdgcn_mfma_f32_16x16x32_bf16(tpf[1], dv1_, op, 0, 0, 0); \
        _Pragma("unroll") \
        for (int r = 0; r < 4; ++r) \
          VO[(size_t)(t0_ + 16 * tw + kq * 4 + r) * VD + colg] = ot[r] + op[r]; } \
      __builtin_amdgcn_s_setprio(1); \
      _Pragma("unroll") \
      for (int i = 0; i < 2; ++i) { \
        st[i][0] *= gam_; st[i][1] *= gam_; st[i][2] *= gam_; st[i][3] *= gam_; \
        st[i] = __builtin_amdgcn_mfma_f32_16x16x32_bf16(hfr[i][0], dv0_, st[i], 0, 0, 0); \
        st[i] = __builtin_amdgcn_mfma_f32_16x16x32_bf16(hfr[i][1], dv1_, st[i], 0, 0, 0); \
        ushort4 hi4, lo4; \
        { float s0 = st[i][0], s1 = st[i][1], s2 = st[i][2], s3 = st[i][3]; \
          hi4.x = f2bf(s0); lo4.x = f2bf(s0 - bf2f(hi4.x)); \
          hi4.y = f2bf(s1); lo4.y = f2bf(s1 - bf2f(hi4.y)); \
          hi4.z = f2bf(s2); lo4.z = f2bf(s2 - bf2f(hi4.z)); \
          hi4.w = f2bf(s3); lo4.w = f2bf(s3 - bf2f(hi4.w)); } \
        *(ushort4*)&S0h[fr][32 * w + 16 * i + kq * 4] = hi4; \
        *(ushort4*)&S0l[fr][32 * w + 16 * i + kq * 4] = lo4; } \
      __builtin_amdgcn_s_setprio(0); } \
    bar_lds();   /* B4: S0 visible for next chunk */ \
  } while (0)

  PREF(kfA, qfA, vlA, 0);
  __syncthreads();   // covers the LDS zero-init
  for (int ch = 0; ch < NCHK; ch += 2) {
    BODY(ch,     kfA, qfA, vlA, kfB, qfB, vlB);
    BODY(ch + 1, kfB, qfB, vlB, kfA, qfA, vlA);
  }
#undef BODY
#undef PREF
}

// ---------------- gated RMSNorm ----------------
__global__ __launch_bounds__(256) void norm_gate(
    const float* __restrict__ o, const unsigned short* __restrict__ gate,
    const float* __restrict__ nw, unsigned short* __restrict__ out)
{
  int th = blockIdx.x, tid = threadIdx.x;
  size_t base = (size_t)th * DVh;
  float x0 = o[base + tid], x1 = o[base + 256 + tid];
  float ss = x0 * x0 + x1 * x1;
  for (int m = 32; m >= 1; m >>= 1) ss += __shfl_xor(ss, m);
  __shared__ float red[4];
  if ((tid & 63) == 0) red[tid >> 6] = ss;
  __syncthreads();
  float rms = rsqrtf((red[0] + red[1] + red[2] + red[3]) * (1.f / 512.f) + 1e-5f);
  float g0 = bf2f(gate[base + tid]), g1 = bf2f(gate[base + 256 + tid]);
  out[base + tid]       = f2bf(x0 * rms * nw[tid]       * silu_f(g0));
  out[base + 256 + tid] = f2bf(x1 * rms * nw[tid + 256] * silu_f(g1));
}

extern "C" void kernel_launch(void* const* d_in, const int* in_sizes, int n_in,
                              void* d_out, int out_size, void* d_ws, size_t ws_size,
                              hipStream_t stream)
{
  const float* h       = (const float*)d_in[0];
  const float* Wq      = (const float*)d_in[1];
  const float* Wk      = (const float*)d_in[2];
  const float* Wv      = (const float*)d_in[3];
  const float* Wb      = (const float*)d_in[4];
  const float* Wa      = (const float*)d_in[5];
  const float* Wg      = (const float*)d_in[6];
  const float* Wo      = (const float*)d_in[7];
  const float* A_log   = (const float*)d_in[8];
  const float* dt_bias = (const float*)d_in[9];
  const float* conv_w  = (const float*)d_in[10];
  const float* gen_w1  = (const float*)d_in[11];
  const float* gen_w2  = (const float*)d_in[12];
  const float* norm_w  = (const float*)d_in[13];
  float* out = (float*)d_out;

  const size_t TK = (size_t)T_LEN * KD, TV = (size_t)T_LEN * VD, TD = (size_t)T_LEN * DIM;

  float* ws   = (float*)d_ws;
  float* q    = ws;
  float* k    = q    + TK;
  float* x    = k    + TK;          // h@Wv conv input; region later reused (see aliases)
  float* v    = x    + TV;          // conv out; O written in place by scan
  float* tg   = v    + TV;          // T*256
  float* dyn  = tg   + (size_t)T_LEN * 256;
  float* beta = dyn  + (size_t)T_LEN * 4;
  float* g    = beta + (size_t)T_LEN * 6;
  float* c    = g    + (size_t)T_LEN * 6;       // [H][T]
  float* gam  = c    + (size_t)NH * T_LEN;      // [H][NCHK]
  float* fend = gam  + 512;
  unsigned short* bh      = (unsigned short*)fend;          // T*DIM
  unsigned short* wT      = bh      + TD;                   // DIM*VD (used for Wo only)
  unsigned short* gate_bf = wT      + (size_t)DIM * VD;     // T*VD
  unsigned short* go_bf   = gate_bf + TV;                   // T*VD
  // aliases (lifetime-disjoint):
  unsigned short* Kb_s  = bh;                 // Kbar: bh dead after fused GEMM
  unsigned short* Qb_s  = (unsigned short*)x; // x region free after conv
  unsigned short* KhT_s = Qb_s + TK;
  unsigned short* Tm_s  = KhT_s + TK;         // H*NCHK*DK*CK == T*KD
  unsigned short* Pm_s  = Tm_s + (size_t)NH * NCHK * CK * CK;
  float* Lg = (float*)go_bf;                  // consumed before norm_gate writes go_bf
  // stacked B^T for fused GEMM: [9472][2048] bf16 = 38.8 MB; aliases v region
  // (50.3 MB) — used only before conv_kernel writes v.
  unsigned short* wTall = (unsigned short*)v;

  dim3 blk(256);
  cast_bf16<<<(TD / 4) / 256, blk, 0, stream>>>(h, bh);
  // ALL weight transposes (5 stacked projections + Wo) in one launch
  tcast_all<<<25088, blk, 0, stream>>>(Wq, Wk, Wv, Wg, gen_w1, Wo, wTall, wT);
  // one fused GEMM for q | k | x | gate | tg (1D grid, grouped block order)
  gemm_fused<<<dim3((NFUSE / 128) * (T_LEN / 128)), blk, 0, stream>>>(
      bh, wTall, q, k, x, gate_bf, tg);

  proj_bg<<<T_LEN, blk, 0, stream>>>(h, Wb, Wa, A_log, dt_bias, beta, g);
  cumsum_g<<<dim3(NCHK, NH), 64, 0, stream>>>(g, c, gam);
  proj_dyn<<<T_LEN, blk, 0, stream>>>(tg, gen_w2, dyn);
  conv_kernel<<<dim3(VD / 256, T_LEN / 8), blk, 0, stream>>>(x, dyn, conv_w, v);
  l2scale<<<T_LEN, 384, 0, stream>>>(q, k, c, Qb_s, Kb_s);

  make_khT<<<dim3(NCHK, NH), blk, 0, stream>>>(k, c, KhT_s);
  chunk_lp<<<dim3(NCHK, NH), blk, 0, stream>>>(q, k, c, beta, Lg, Pm_s);
  tri_inv<<<dim3(NCHK, NH), 64, 0, stream>>>(Lg, beta, Tm_s);

  scan_chunk<<<dim3(DVh / 16, NH), 512, 0, stream>>>(Kb_s, Qb_s, KhT_s, Tm_s, Pm_s, gam, v);

  norm_gate<<<T_LEN * NH, blk, 0, stream>>>(v, gate_bf, norm_w, go_bf);
  gemm_bt_bf16<<<dim3(DIM / 128, T_LEN / 128), blk, 0, stream>>>(go_bf, wT, out, T_LEN, DIM, VD, 0);
}